// Round 2
// baseline (3656.641 us; speedup 1.0000x reference)
//
#include <hip/hip_runtime.h>
#include <stdint.h>
#include <stddef.h>

typedef unsigned long long u64;
typedef unsigned int u32;

#define NBATCH 8
#define NPTS   8192
#define SG     2048
#define KS     32
#define NGRP   (NBATCH*SG)      // 16384
#define MROWS  (NGRP*KS)        // 524288

// ---- ALL scratch in module-static device globals: immune to ws_size ----
__device__ float4 g_p4[NBATCH*NPTS];          // 1 MiB  {x,y,z,|p|^2}
__device__ float  g_cx[NGRP], g_cy[NGRP], g_cz[NGRP];
__device__ int    g_ball[(size_t)NGRP*KS];    // 2 MiB
__device__ double g_stats[3*128*256];         // 768 KiB
__device__ float  g_A[256], g_Bv[256];        // BN scale/shift: L0 @0, L1 @64, L2 @128
__device__ float  g_mmax[(size_t)NGRP*128];   // 8 MiB
__device__ float  g_mmin[(size_t)NGRP*128];   // 8 MiB
__device__ float  g_y0[(size_t)MROWS*64];     // 134 MiB raw L0 output
__device__ float  g_y1[(size_t)MROWS*64];     // 134 MiB raw L1 output

// ---------------- K_zero ----------------
__global__ __launch_bounds__(256) void k_zero(){
  int idx = blockIdx.x*256 + threadIdx.x;
  if (idx < 3*128*256) g_stats[idx] = 0.0;
}

// ---------------- K_pre ----------------
__global__ __launch_bounds__(256) void k_pre(const float* __restrict__ xyz){
#pragma clang fp contract(off)
  int idx = blockIdx.x*256 + threadIdx.x;
  if (idx >= NBATCH*NPTS) return;
  float x = xyz[idx*3+0];
  float y = xyz[idx*3+1];
  float z = xyz[idx*3+2];
  float xx = x*x; float yy = y*y; float zz = z*z;
  float s2 = (xx + yy) + zz;
  g_p4[idx] = make_float4(x,y,z,s2);
}

// ---------------- K_fps ----------------
// ROUND 2 CHANGE: rocprof showed the RA spills against an ~88-VGPR budget
// regardless of source form (r0: arrays, r1: named scalars — both VGPR=88,
// FETCH 562MB of spill traffic). Fix by FITTING under 88 by construction:
//   * dist[] running-min moved to LDS  dls[16][512] (32 KiB, point-major:
//     lane t -> addr t*4 + i*2048, 2-way bank aliasing = free)
//   * 512 threads x 16 pts/thread: xyz register state 96 -> 48 floats
// Distance math is op-for-op identical to the passing version (contract
// off, (a0+a1)+a2, fminf). Key = (dist_bits<<32)|(8191-gi) picks a unique
// global winner independent of thread partitioning; ascending local i ==
// ascending gi (gi = i*512+t), so centroid sequence is bit-identical.

#define NT  512
#define PPT 16

#define FOR16(M) M(0) M(1) M(2) M(3) M(4) M(5) M(6) M(7) \
                 M(8) M(9) M(10) M(11) M(12) M(13) M(14) M(15)

#define DECLP(i) float px##i, py##i, pz##i;

#define LOADP(i) { float4 p_ = g_p4[base + (i)*NT + t]; \
                   px##i = p_.x; py##i = p_.y; pz##i = p_.z; \
                   dls[i][t] = 1e10f; }

#define UPD(i) { float dx = px##i - fc.x; \
                 float dy = py##i - fc.y; \
                 float dz = pz##i - fc.z; \
                 float a0 = dx*dx; float a1 = dy*dy; float a2 = dz*dz; \
                 float d  = (a0 + a1) + a2; \
                 float nd = fminf(dls[i][t], d); \
                 dls[i][t] = nd; \
                 if (nd > bv){ bv = nd; bi = (i); } }

__global__ __launch_bounds__(NT, 1) void k_fps(const int* __restrict__ start, float* __restrict__ out_xyz){
  const int b = blockIdx.x;
  const int t = threadIdx.x;
  const int base = b*NPTS;
  __shared__ u64 wk[2][8];
  __shared__ float dls[PPT][NT];   // 32 KiB running min-dist

  FOR16(DECLP)
  FOR16(LOADP)

  int far = start[b];
  float4 fc = g_p4[base+far];
  if (t==0){
    g_cx[b*SG]=fc.x; g_cy[b*SG]=fc.y; g_cz[b*SG]=fc.z;
    size_t o = (size_t)(b*SG)*3;
    out_xyz[o+0]=fc.x; out_xyz[o+1]=fc.y; out_xyz[o+2]=fc.z;
  }
  const int lane = t & 63, w = t >> 6;   // w in 0..7
  for (int it=1; it<SG; ++it){
    float bv = -1.0f; int bi = 0;
    {
#pragma clang fp contract(off)
      FOR16(UPD)
    }
    int gi = bi*NT + t;
    u64 key = ((u64)__float_as_uint(bv) << 32) | (u32)(NPTS-1 - gi);
#pragma unroll
    for (int off=32; off>=1; off>>=1){
      u64 k2 = __shfl_down(key, off);
      if (k2 > key) key = k2;
    }
    const int pb = it & 1;
    if (lane==0) wk[pb][w] = key;
    __syncthreads();
    u64 k0 = wk[pb][0], k1 = wk[pb][1], k2 = wk[pb][2], k3 = wk[pb][3];
    u64 k4 = wk[pb][4], k5 = wk[pb][5], k6 = wk[pb][6], k7 = wk[pb][7];
    u64 ka = (k0 > k1) ? k0 : k1;
    u64 kb = (k2 > k3) ? k2 : k3;
    u64 kc = (k4 > k5) ? k4 : k5;
    u64 kd = (k6 > k7) ? k6 : k7;
    u64 ke = (ka > kb) ? ka : kb;
    u64 kf = (kc > kd) ? kc : kd;
    u64 km = (ke > kf) ? ke : kf;
    far = NPTS-1 - (int)(km & 0xffffffffu);
    fc = g_p4[base+far];
    if (t==0){
      g_cx[b*SG+it]=fc.x; g_cy[b*SG+it]=fc.y; g_cz[b*SG+it]=fc.z;
      size_t o = (size_t)(b*SG+it)*3;
      out_xyz[o+0]=fc.x; out_xyz[o+1]=fc.y; out_xyz[o+2]=fc.z;
    }
  }
}

// ---------------- K_ball: expansion form, FMA-ascending dot (PASSED r7, do not touch) ----------------
__global__ __launch_bounds__(256) void k_ball(){
  const int g = blockIdx.x*4 + (threadIdx.x>>6);
  const int lane = threadIdx.x & 63;
  const int b = g >> 11;
  const float4* pb4 = g_p4 + b*NPTS;
  float cxv = g_cx[g], cyv = g_cy[g], czv = g_cz[g];
  float s1;
  {
#pragma clang fp contract(off)
    float a = cxv*cxv; float bb = cyv*cyv; float cc = czv*czv;
    s1 = (a + bb) + cc;
  }
  const float R2 = 0.04f;
  int filled = 0, firstn = -1;
  for (int n0=0; n0<NPTS && filled<KS; n0+=64){
    float4 p = pb4[n0+lane];
    float sq;
    {
#pragma clang fp contract(off)
      float dt = cxv*p.x;
      dt = fmaf(cyv, p.y, dt);
      dt = fmaf(czv, p.z, dt);
      float ss = s1 + p.w;
      sq = ss - 2.0f*dt;
    }
    bool mem = !(sq > R2);
    u64 mk = __ballot(mem);
    if (firstn < 0 && mk) firstn = n0 + (__ffsll((unsigned long long)mk) - 1);
    int pos = filled + (int)__popcll(mk & ((1ull<<lane)-1ull));
    if (mem && pos < KS) g_ball[(size_t)g*KS + pos] = n0 + lane;
    filled += (int)__popcll(mk);
  }
  for (int s = filled + lane; s < KS; s += 64) g_ball[(size_t)g*KS+s] = firstn;
}

// ---------------- K_mlpA: gather + L0 -> Y0 (raw f32) + stats0 ----------------
__global__ __launch_bounds__(256) void k_mlpA(
    const float* __restrict__ points,
    const float* __restrict__ W0, const float* __restrict__ B0v){
  double* stats = g_stats;
  const int g = blockIdx.x, tid = threadIdx.x;
  const int b = g >> 11;
  __shared__ __align__(16) float xt[32][68];
  __shared__ __align__(16) float w0s[68][64];
  __shared__ float wsum[4][64], wsq[4][64];

  for (int i = tid; i < 67*64; i += 256) w0s[i>>6][i&63] = W0[i];
  if (tid < 64) w0s[67][tid] = 0.f;

  if (tid < 32){
    int n = g_ball[(size_t)g*KS + tid];
    float4 p = g_p4[b*NPTS + n];
    xt[tid][0] = p.x - g_cx[g];
    xt[tid][1] = p.y - g_cy[g];
    xt[tid][2] = p.z - g_cz[g];
    xt[tid][67] = 0.f;
  }
  {
    int k = tid >> 3, j = tid & 7;
    int n = g_ball[(size_t)g*KS + k];
    const float4* pr = (const float4*)(points + ((size_t)(b*NPTS + n))*64);
    float4 v0 = pr[j*2], v1 = pr[j*2+1];
    int c0 = 3 + j*8;
    xt[k][c0+0]=v0.x; xt[k][c0+1]=v0.y; xt[k][c0+2]=v0.z; xt[k][c0+3]=v0.w;
    xt[k][c0+4]=v1.x; xt[k][c0+5]=v1.y; xt[k][c0+6]=v1.z; xt[k][c0+7]=v1.w;
  }
  __syncthreads();

  const int k0 = (tid >> 4) * 2;
  const int d0 = (tid & 15) * 4;
  const int lane = tid & 63, w = tid >> 6;

  float acc0[4] = {0.f,0.f,0.f,0.f};
  float acc1[4] = {0.f,0.f,0.f,0.f};
#pragma unroll
  for (int cq = 0; cq < 17; ++cq){
    const int c = cq*4;
    float xa[4], xb[4], r0[4], r1[4], r2[4], r3[4];
    *(float4*)xa = *(const float4*)&xt[k0][c];
    *(float4*)xb = *(const float4*)&xt[k0+1][c];
    *(float4*)r0 = *(const float4*)&w0s[c+0][d0];
    *(float4*)r1 = *(const float4*)&w0s[c+1][d0];
    *(float4*)r2 = *(const float4*)&w0s[c+2][d0];
    *(float4*)r3 = *(const float4*)&w0s[c+3][d0];
#pragma unroll
    for (int j=0;j<4;j++){
      acc0[j] = fmaf(xa[0], r0[j], acc0[j]);
      acc0[j] = fmaf(xa[1], r1[j], acc0[j]);
      acc0[j] = fmaf(xa[2], r2[j], acc0[j]);
      acc0[j] = fmaf(xa[3], r3[j], acc0[j]);
      acc1[j] = fmaf(xb[0], r0[j], acc1[j]);
      acc1[j] = fmaf(xb[1], r1[j], acc1[j]);
      acc1[j] = fmaf(xb[2], r2[j], acc1[j]);
      acc1[j] = fmaf(xb[3], r3[j], acc1[j]);
    }
  }
#pragma unroll
  for (int j=0;j<4;j++){ float bv = B0v[d0+j]; acc0[j] += bv; acc1[j] += bv; }

  // store raw Y0
  {
    size_t r0 = ((size_t)g*KS + k0)*64 + d0;
    *(float4*)&g_y0[r0]      = *(float4*)acc0;
    *(float4*)&g_y0[r0 + 64] = *(float4*)acc1;
  }

  float s[4], q[4];
#pragma unroll
  for (int j=0;j<4;j++){ s[j] = acc0[j]+acc1[j]; q[j] = acc0[j]*acc0[j] + acc1[j]*acc1[j]; }
#pragma unroll
  for (int j=0;j<4;j++){
    s[j] += __shfl_down(s[j],32); s[j] += __shfl_down(s[j],16);
    q[j] += __shfl_down(q[j],32); q[j] += __shfl_down(q[j],16);
  }
  if (lane < 16){
#pragma unroll
    for (int j=0;j<4;j++){ wsum[w][lane*4+j] = s[j]; wsq[w][lane*4+j] = q[j]; }
  }
  __syncthreads();
  if (tid < 64){
    float S = wsum[0][tid]+wsum[1][tid]+wsum[2][tid]+wsum[3][tid];
    float Q = wsq[0][tid]+wsq[1][tid]+wsq[2][tid]+wsq[3][tid];
    int bucket = g & 127;
    atomicAdd(&stats[(size_t)bucket*256 + tid], (double)S);
    atomicAdd(&stats[(size_t)bucket*256 + 128 + tid], (double)Q);
  }
}

// ---------------- K_mlpB: Y0 + BN0/ReLU -> L1 -> Y1 (raw) + stats1 ----------------
__global__ __launch_bounds__(256) void k_mlpB(
    const float* __restrict__ W1, const float* __restrict__ B1v){
  double* stats = g_stats + (size_t)1*128*256;
  const int g = blockIdx.x, tid = threadIdx.x;
  __shared__ __align__(16) float xn[32][68];
  __shared__ __align__(16) float w1s[64][64];
  __shared__ float wsum[4][64], wsq[4][64];

  for (int i = tid; i < 64*64; i += 256) w1s[i>>6][i&63] = W1[i];
  {
    int k = tid >> 3, j = tid & 7;
    const float4* pr = (const float4*)(g_y0 + ((size_t)g*KS + k)*64);
    float4 v0 = pr[j*2], v1 = pr[j*2+1];
    int c0 = j*8;
    xn[k][c0+0] = fmaxf(fmaf(v0.x, g_A[c0+0], g_Bv[c0+0]), 0.f);
    xn[k][c0+1] = fmaxf(fmaf(v0.y, g_A[c0+1], g_Bv[c0+1]), 0.f);
    xn[k][c0+2] = fmaxf(fmaf(v0.z, g_A[c0+2], g_Bv[c0+2]), 0.f);
    xn[k][c0+3] = fmaxf(fmaf(v0.w, g_A[c0+3], g_Bv[c0+3]), 0.f);
    xn[k][c0+4] = fmaxf(fmaf(v1.x, g_A[c0+4], g_Bv[c0+4]), 0.f);
    xn[k][c0+5] = fmaxf(fmaf(v1.y, g_A[c0+5], g_Bv[c0+5]), 0.f);
    xn[k][c0+6] = fmaxf(fmaf(v1.z, g_A[c0+6], g_Bv[c0+6]), 0.f);
    xn[k][c0+7] = fmaxf(fmaf(v1.w, g_A[c0+7], g_Bv[c0+7]), 0.f);
  }
  __syncthreads();

  const int k0 = (tid >> 4) * 2;
  const int d0 = (tid & 15) * 4;
  const int lane = tid & 63, w = tid >> 6;

  float bc0[4] = {0.f,0.f,0.f,0.f};
  float bc1[4] = {0.f,0.f,0.f,0.f};
#pragma unroll
  for (int cq = 0; cq < 16; ++cq){
    const int c = cq*4;
    float xa[4], xb[4], r0[4], r1[4], r2[4], r3[4];
    *(float4*)xa = *(const float4*)&xn[k0][c];
    *(float4*)xb = *(const float4*)&xn[k0+1][c];
    *(float4*)r0 = *(const float4*)&w1s[c+0][d0];
    *(float4*)r1 = *(const float4*)&w1s[c+1][d0];
    *(float4*)r2 = *(const float4*)&w1s[c+2][d0];
    *(float4*)r3 = *(const float4*)&w1s[c+3][d0];
#pragma unroll
    for (int j=0;j<4;j++){
      bc0[j] = fmaf(xa[0], r0[j], bc0[j]);
      bc0[j] = fmaf(xa[1], r1[j], bc0[j]);
      bc0[j] = fmaf(xa[2], r2[j], bc0[j]);
      bc0[j] = fmaf(xa[3], r3[j], bc0[j]);
      bc1[j] = fmaf(xb[0], r0[j], bc1[j]);
      bc1[j] = fmaf(xb[1], r1[j], bc1[j]);
      bc1[j] = fmaf(xb[2], r2[j], bc1[j]);
      bc1[j] = fmaf(xb[3], r3[j], bc1[j]);
    }
  }
#pragma unroll
  for (int j=0;j<4;j++){ float bv = B1v[d0+j]; bc0[j] += bv; bc1[j] += bv; }

  {
    size_t r0 = ((size_t)g*KS + k0)*64 + d0;
    *(float4*)&g_y1[r0]      = *(float4*)bc0;
    *(float4*)&g_y1[r0 + 64] = *(float4*)bc1;
  }

  float s[4], q[4];
#pragma unroll
  for (int j=0;j<4;j++){ s[j] = bc0[j]+bc1[j]; q[j] = bc0[j]*bc0[j] + bc1[j]*bc1[j]; }
#pragma unroll
  for (int j=0;j<4;j++){
    s[j] += __shfl_down(s[j],32); s[j] += __shfl_down(s[j],16);
    q[j] += __shfl_down(q[j],32); q[j] += __shfl_down(q[j],16);
  }
  if (lane < 16){
#pragma unroll
    for (int j=0;j<4;j++){ wsum[w][lane*4+j] = s[j]; wsq[w][lane*4+j] = q[j]; }
  }
  __syncthreads();
  if (tid < 64){
    float S = wsum[0][tid]+wsum[1][tid]+wsum[2][tid]+wsum[3][tid];
    float Q = wsq[0][tid]+wsq[1][tid]+wsq[2][tid]+wsq[3][tid];
    int bucket = g & 127;
    atomicAdd(&stats[(size_t)bucket*256 + tid], (double)S);
    atomicAdd(&stats[(size_t)bucket*256 + 128 + tid], (double)Q);
  }
}

// ---------------- K_mlpC: Y1 + BN1/ReLU -> L2 -> stats2 + max/min ----------------
__global__ __launch_bounds__(256) void k_mlpC(
    const float* __restrict__ W2, const float* __restrict__ B2v){
  double* stats = g_stats + (size_t)2*128*256;
  const int g = blockIdx.x, tid = threadIdx.x;
  __shared__ __align__(16) float xt[32][68];
  __shared__ __align__(16) float w2s[64][128];
  __shared__ float wsum[4][128], wsq[4][128];
  __shared__ float wmx[4][128], wmn[4][128];

  for (int i = tid; i < 64*128; i += 256) w2s[i>>7][i&127] = W2[i];
  {
    int k = tid >> 3, j = tid & 7;
    const float4* pr = (const float4*)(g_y1 + ((size_t)g*KS + k)*64);
    float4 v0 = pr[j*2], v1 = pr[j*2+1];
    int c0 = j*8;
    xt[k][c0+0] = fmaxf(fmaf(v0.x, g_A[64+c0+0], g_Bv[64+c0+0]), 0.f);
    xt[k][c0+1] = fmaxf(fmaf(v0.y, g_A[64+c0+1], g_Bv[64+c0+1]), 0.f);
    xt[k][c0+2] = fmaxf(fmaf(v0.z, g_A[64+c0+2], g_Bv[64+c0+2]), 0.f);
    xt[k][c0+3] = fmaxf(fmaf(v0.w, g_A[64+c0+3], g_Bv[64+c0+3]), 0.f);
    xt[k][c0+4] = fmaxf(fmaf(v1.x, g_A[64+c0+4], g_Bv[64+c0+4]), 0.f);
    xt[k][c0+5] = fmaxf(fmaf(v1.y, g_A[64+c0+5], g_Bv[64+c0+5]), 0.f);
    xt[k][c0+6] = fmaxf(fmaf(v1.z, g_A[64+c0+6], g_Bv[64+c0+6]), 0.f);
    xt[k][c0+7] = fmaxf(fmaf(v1.w, g_A[64+c0+7], g_Bv[64+c0+7]), 0.f);
  }
  __syncthreads();

  const int k0 = (tid >> 4) * 2;
  const int e0 = (tid & 15) * 8;
  const int lane = tid & 63, w = tid >> 6;

  float c0a[8] = {0.f,0.f,0.f,0.f,0.f,0.f,0.f,0.f};
  float c1a[8] = {0.f,0.f,0.f,0.f,0.f,0.f,0.f,0.f};
#pragma unroll
  for (int cq = 0; cq < 16; ++cq){
    const int c = cq*4;
    float xa[4], xb[4], r0[8], r1[8], r2[8], r3[8];
    *(float4*)xa = *(const float4*)&xt[k0][c];
    *(float4*)xb = *(const float4*)&xt[k0+1][c];
    *(float4*)&r0[0] = *(const float4*)&w2s[c+0][e0]; *(float4*)&r0[4] = *(const float4*)&w2s[c+0][e0+4];
    *(float4*)&r1[0] = *(const float4*)&w2s[c+1][e0]; *(float4*)&r1[4] = *(const float4*)&w2s[c+1][e0+4];
    *(float4*)&r2[0] = *(const float4*)&w2s[c+2][e0]; *(float4*)&r2[4] = *(const float4*)&w2s[c+2][e0+4];
    *(float4*)&r3[0] = *(const float4*)&w2s[c+3][e0]; *(float4*)&r3[4] = *(const float4*)&w2s[c+3][e0+4];
#pragma unroll
    for (int j=0;j<8;j++){
      c0a[j] = fmaf(xa[0], r0[j], c0a[j]);
      c0a[j] = fmaf(xa[1], r1[j], c0a[j]);
      c0a[j] = fmaf(xa[2], r2[j], c0a[j]);
      c0a[j] = fmaf(xa[3], r3[j], c0a[j]);
      c1a[j] = fmaf(xb[0], r0[j], c1a[j]);
      c1a[j] = fmaf(xb[1], r1[j], c1a[j]);
      c1a[j] = fmaf(xb[2], r2[j], c1a[j]);
      c1a[j] = fmaf(xb[3], r3[j], c1a[j]);
    }
  }
#pragma unroll
  for (int j=0;j<8;j++){ float bv = B2v[e0+j]; c0a[j] += bv; c1a[j] += bv; }

  float s[8], q[8], mx[8], mn[8];
#pragma unroll
  for (int j=0;j<8;j++){
    s[j] = c0a[j]+c1a[j]; q[j] = c0a[j]*c0a[j] + c1a[j]*c1a[j];
    mx[j] = fmaxf(c0a[j], c1a[j]); mn[j] = fminf(c0a[j], c1a[j]);
  }
#pragma unroll
  for (int j=0;j<8;j++){
    s[j] += __shfl_down(s[j],32); s[j] += __shfl_down(s[j],16);
    q[j] += __shfl_down(q[j],32); q[j] += __shfl_down(q[j],16);
    mx[j] = fmaxf(mx[j], __shfl_xor(mx[j],16)); mx[j] = fmaxf(mx[j], __shfl_xor(mx[j],32));
    mn[j] = fminf(mn[j], __shfl_xor(mn[j],16)); mn[j] = fminf(mn[j], __shfl_xor(mn[j],32));
  }
  if (lane < 16){
#pragma unroll
    for (int j=0;j<8;j++){
      wsum[w][lane*8+j] = s[j]; wsq[w][lane*8+j] = q[j];
      wmx[w][lane*8+j] = mx[j]; wmn[w][lane*8+j] = mn[j];
    }
  }
  __syncthreads();
  if (tid < 128){
    float S = wsum[0][tid]+wsum[1][tid]+wsum[2][tid]+wsum[3][tid];
    float Q = wsq[0][tid]+wsq[1][tid]+wsq[2][tid]+wsq[3][tid];
    float MX = fmaxf(fmaxf(wmx[0][tid],wmx[1][tid]), fmaxf(wmx[2][tid],wmx[3][tid]));
    float MN = fminf(fminf(wmn[0][tid],wmn[1][tid]), fminf(wmn[2][tid],wmn[3][tid]));
    g_mmax[(size_t)g*128 + tid] = MX;
    g_mmin[(size_t)g*128 + tid] = MN;
    int bucket = g & 127;
    atomicAdd(&stats[(size_t)bucket*256 + tid], (double)S);
    atomicAdd(&stats[(size_t)bucket*256 + 128 + tid], (double)Q);
  }
}

// ---------------- K_stats ----------------
__global__ void k_stats(int stage, const float* __restrict__ gamma,
                        const float* __restrict__ beta, int aoff, int cout){
  int c = threadIdx.x;
  if (c >= cout) return;
  const double* stats = g_stats + (size_t)stage*128*256;
  double S=0.0, Q=0.0;
  for (int k=0;k<128;k++){ S += stats[(size_t)k*256 + c]; Q += stats[(size_t)k*256 + 128 + c]; }
  const double M = (double)MROWS;
  double mean = S / M;
  double var  = Q / M - mean*mean;
  double inv  = 1.0 / sqrt(var + 1e-5);
  double a    = (double)gamma[c] * inv;
  g_A[aoff+c]  = (float)a;
  g_Bv[aoff+c] = (float)((double)beta[c] - mean * a);
}

// ---------------- K_final ----------------
__global__ __launch_bounds__(256) void k_final(float* __restrict__ outp){
  int idx = blockIdx.x*256 + threadIdx.x;
  int d = idx & 127;
  float a = g_A[128+d], b = g_Bv[128+d];
  float y = (a >= 0.f) ? g_mmax[idx] : g_mmin[idx];
  float v = fmaf(y, a, b);
  outp[idx] = fmaxf(v, 0.f);
}

extern "C" void kernel_launch(void* const* d_in, const int* in_sizes, int n_in,
                              void* d_out, int out_size, void* d_ws, size_t ws_size,
                              hipStream_t stream) {
  (void)in_sizes; (void)n_in; (void)out_size; (void)d_ws; (void)ws_size;
  const float* xyz    = (const float*)d_in[0];
  const float* points = (const float*)d_in[1];
  const int*   start  = (const int*)d_in[2];
  const float* W0 = (const float*)d_in[3];  const float* b0 = (const float*)d_in[4];
  const float* g0 = (const float*)d_in[5];  const float* be0= (const float*)d_in[6];
  const float* W1 = (const float*)d_in[7];  const float* b1 = (const float*)d_in[8];
  const float* g1 = (const float*)d_in[9];  const float* be1= (const float*)d_in[10];
  const float* W2 = (const float*)d_in[11]; const float* b2 = (const float*)d_in[12];
  const float* g2 = (const float*)d_in[13]; const float* be2= (const float*)d_in[14];

  float* out_xyz = (float*)d_out;
  float* out_pts = (float*)d_out + (size_t)NBATCH*SG*3;

  k_zero <<<384, 256, 0, stream>>>();
  k_pre  <<<256, 256, 0, stream>>>(xyz);
  k_fps  <<<NBATCH, NT, 0, stream>>>(start, out_xyz);
  k_ball <<<4096, 256, 0, stream>>>();

  k_mlpA<<<NGRP, 256, 0, stream>>>(points, W0, b0);
  k_stats<<<1, 128, 0, stream>>>(0, g0, be0, 0, 64);
  k_mlpB<<<NGRP, 256, 0, stream>>>(W1, b1);
  k_stats<<<1, 128, 0, stream>>>(1, g1, be1, 64, 64);
  k_mlpC<<<NGRP, 256, 0, stream>>>(W2, b2);
  k_stats<<<1, 128, 0, stream>>>(2, g2, be2, 128, 128);
  k_final<<<8192, 256, 0, stream>>>(out_pts);
}

// Round 3
// 3242.563 us; speedup vs baseline: 1.1277x; 1.1277x over previous
//
#include <hip/hip_runtime.h>
#include <stdint.h>
#include <stddef.h>

typedef unsigned long long u64;
typedef unsigned int u32;

#define NBATCH 8
#define NPTS   8192
#define SG     2048
#define KS     32
#define NGRP   (NBATCH*SG)      // 16384
#define MROWS  (NGRP*KS)        // 524288

// ---- ALL scratch in module-static device globals: immune to ws_size ----
__device__ float4 g_p4[NBATCH*NPTS];          // 1 MiB  {x,y,z,|p|^2}
__device__ float  g_cx[NGRP], g_cy[NGRP], g_cz[NGRP];
__device__ int    g_ball[(size_t)NGRP*KS];    // 2 MiB
__device__ double g_stats[3*128*256];         // 768 KiB
__device__ float  g_A[256], g_Bv[256];        // BN scale/shift: L0 @0, L1 @64, L2 @128
__device__ float  g_mmax[(size_t)NGRP*128];   // 8 MiB
__device__ float  g_mmin[(size_t)NGRP*128];   // 8 MiB
__device__ float  g_y0[(size_t)MROWS*64];     // 134 MiB raw L0 output
__device__ float  g_y1[(size_t)MROWS*64];     // 134 MiB raw L1 output

// ---------------- K_zero ----------------
__global__ __launch_bounds__(256) void k_zero(){
  int idx = blockIdx.x*256 + threadIdx.x;
  if (idx < 3*128*256) g_stats[idx] = 0.0;
}

// ---------------- K_pre ----------------
__global__ __launch_bounds__(256) void k_pre(const float* __restrict__ xyz){
#pragma clang fp contract(off)
  int idx = blockIdx.x*256 + threadIdx.x;
  if (idx >= NBATCH*NPTS) return;
  float x = xyz[idx*3+0];
  float y = xyz[idx*3+1];
  float z = xyz[idx*3+2];
  float xx = x*x; float yy = y*y; float zz = z*z;
  float s2 = (xx + yy) + zz;
  g_p4[idx] = make_float4(x,y,z,s2);
}

// ---------------- K_fps ----------------
// ROUND 3: evidence so far —
//   r0/r1 (256thr x 32ppt, regs): VGPR=88 => RA spilled ~60 of 128 state
//     floats to scratch; 2573us.
//   r2   (512thr x 16ppt, dist in LDS): VGPR=52, no spill, but 256 DS
//     wave-instrs/iter on ONE CU's DS pipe => DS-throughput-bound; 3054us.
//   FETCH/WRITE counters never moved across all three => they are
//     pipeline-aggregated attribution artifacts; ignore them.
// FIX: 1024 threads x 8 pts/thread, ALL state in registers.
//   State = 24 xyz + 8 dist + temps ~= 50 VGPR: fits under even a 64-VGPR
//   budget, so no spill is possible by construction. No DS dist traffic.
//   4 waves/SIMD give TLP to hide shuffle + fc-load latency.
// Math identical bits: contract(off), (a0+a1)+a2, fminf chain.
// Key=(dist_bits<<32)|(8191-gi) -> unique global (max-dist, min-index)
// winner, independent of partitioning. gi = i*1024+t: ascending local i ==
// ascending gi per thread, preserving the local-argmax tie-break.

#define NT  1024
#define PPT 8

#define FOR8(M) M(0) M(1) M(2) M(3) M(4) M(5) M(6) M(7)

#define DECLP(i) float px##i, py##i, pz##i, dd##i;

#define LOADP(i) { float4 p_ = g_p4[base + (i)*NT + t]; \
                   px##i = p_.x; py##i = p_.y; pz##i = p_.z; dd##i = 1e10f; }

#define UPD(i) { float dx = px##i - fc.x; \
                 float dy = py##i - fc.y; \
                 float dz = pz##i - fc.z; \
                 float a0 = dx*dx; float a1 = dy*dy; float a2 = dz*dz; \
                 float d  = (a0 + a1) + a2; \
                 float nd = fminf(dd##i, d); \
                 dd##i = nd; \
                 if (nd > bv){ bv = nd; bi = (i); } }

__global__ __launch_bounds__(NT, 1) void k_fps(const int* __restrict__ start, float* __restrict__ out_xyz){
  const int b = blockIdx.x;
  const int t = threadIdx.x;
  const int base = b*NPTS;
  __shared__ u64 wk[2][16];

  FOR8(DECLP)
  FOR8(LOADP)

  int far = start[b];
  float4 fc = g_p4[base+far];
  if (t==0){
    g_cx[b*SG]=fc.x; g_cy[b*SG]=fc.y; g_cz[b*SG]=fc.z;
    size_t o = (size_t)(b*SG)*3;
    out_xyz[o+0]=fc.x; out_xyz[o+1]=fc.y; out_xyz[o+2]=fc.z;
  }
  const int lane = t & 63, w = t >> 6;   // w in 0..15
  for (int it=1; it<SG; ++it){
    float bv = -1.0f; int bi = 0;
    {
#pragma clang fp contract(off)
      FOR8(UPD)
    }
    int gi = bi*NT + t;
    u64 key = ((u64)__float_as_uint(bv) << 32) | (u32)(NPTS-1 - gi);
#pragma unroll
    for (int off=32; off>=1; off>>=1){
      u64 k2 = __shfl_down(key, off);
      if (k2 > key) key = k2;
    }
    const int pb = it & 1;
    if (lane==0) wk[pb][w] = key;
    __syncthreads();
    u64 km = wk[pb][0];
#pragma unroll
    for (int j=1;j<16;j++){ u64 kj = wk[pb][j]; if (kj > km) km = kj; }
    far = NPTS-1 - (int)(km & 0xffffffffu);
    fc = g_p4[base+far];
    if (t==0){
      g_cx[b*SG+it]=fc.x; g_cy[b*SG+it]=fc.y; g_cz[b*SG+it]=fc.z;
      size_t o = (size_t)(b*SG+it)*3;
      out_xyz[o+0]=fc.x; out_xyz[o+1]=fc.y; out_xyz[o+2]=fc.z;
    }
  }
}

// ---------------- K_ball: expansion form, FMA-ascending dot (PASSED r7, do not touch) ----------------
__global__ __launch_bounds__(256) void k_ball(){
  const int g = blockIdx.x*4 + (threadIdx.x>>6);
  const int lane = threadIdx.x & 63;
  const int b = g >> 11;
  const float4* pb4 = g_p4 + b*NPTS;
  float cxv = g_cx[g], cyv = g_cy[g], czv = g_cz[g];
  float s1;
  {
#pragma clang fp contract(off)
    float a = cxv*cxv; float bb = cyv*cyv; float cc = czv*czv;
    s1 = (a + bb) + cc;
  }
  const float R2 = 0.04f;
  int filled = 0, firstn = -1;
  for (int n0=0; n0<NPTS && filled<KS; n0+=64){
    float4 p = pb4[n0+lane];
    float sq;
    {
#pragma clang fp contract(off)
      float dt = cxv*p.x;
      dt = fmaf(cyv, p.y, dt);
      dt = fmaf(czv, p.z, dt);
      float ss = s1 + p.w;
      sq = ss - 2.0f*dt;
    }
    bool mem = !(sq > R2);
    u64 mk = __ballot(mem);
    if (firstn < 0 && mk) firstn = n0 + (__ffsll((unsigned long long)mk) - 1);
    int pos = filled + (int)__popcll(mk & ((1ull<<lane)-1ull));
    if (mem && pos < KS) g_ball[(size_t)g*KS + pos] = n0 + lane;
    filled += (int)__popcll(mk);
  }
  for (int s = filled + lane; s < KS; s += 64) g_ball[(size_t)g*KS+s] = firstn;
}

// ---------------- K_mlpA: gather + L0 -> Y0 (raw f32) + stats0 ----------------
__global__ __launch_bounds__(256) void k_mlpA(
    const float* __restrict__ points,
    const float* __restrict__ W0, const float* __restrict__ B0v){
  double* stats = g_stats;
  const int g = blockIdx.x, tid = threadIdx.x;
  const int b = g >> 11;
  __shared__ __align__(16) float xt[32][68];
  __shared__ __align__(16) float w0s[68][64];
  __shared__ float wsum[4][64], wsq[4][64];

  for (int i = tid; i < 67*64; i += 256) w0s[i>>6][i&63] = W0[i];
  if (tid < 64) w0s[67][tid] = 0.f;

  if (tid < 32){
    int n = g_ball[(size_t)g*KS + tid];
    float4 p = g_p4[b*NPTS + n];
    xt[tid][0] = p.x - g_cx[g];
    xt[tid][1] = p.y - g_cy[g];
    xt[tid][2] = p.z - g_cz[g];
    xt[tid][67] = 0.f;
  }
  {
    int k = tid >> 3, j = tid & 7;
    int n = g_ball[(size_t)g*KS + k];
    const float4* pr = (const float4*)(points + ((size_t)(b*NPTS + n))*64);
    float4 v0 = pr[j*2], v1 = pr[j*2+1];
    int c0 = 3 + j*8;
    xt[k][c0+0]=v0.x; xt[k][c0+1]=v0.y; xt[k][c0+2]=v0.z; xt[k][c0+3]=v0.w;
    xt[k][c0+4]=v1.x; xt[k][c0+5]=v1.y; xt[k][c0+6]=v1.z; xt[k][c0+7]=v1.w;
  }
  __syncthreads();

  const int k0 = (tid >> 4) * 2;
  const int d0 = (tid & 15) * 4;
  const int lane = tid & 63, w = tid >> 6;

  float acc0[4] = {0.f,0.f,0.f,0.f};
  float acc1[4] = {0.f,0.f,0.f,0.f};
#pragma unroll
  for (int cq = 0; cq < 17; ++cq){
    const int c = cq*4;
    float xa[4], xb[4], r0[4], r1[4], r2[4], r3[4];
    *(float4*)xa = *(const float4*)&xt[k0][c];
    *(float4*)xb = *(const float4*)&xt[k0+1][c];
    *(float4*)r0 = *(const float4*)&w0s[c+0][d0];
    *(float4*)r1 = *(const float4*)&w0s[c+1][d0];
    *(float4*)r2 = *(const float4*)&w0s[c+2][d0];
    *(float4*)r3 = *(const float4*)&w0s[c+3][d0];
#pragma unroll
    for (int j=0;j<4;j++){
      acc0[j] = fmaf(xa[0], r0[j], acc0[j]);
      acc0[j] = fmaf(xa[1], r1[j], acc0[j]);
      acc0[j] = fmaf(xa[2], r2[j], acc0[j]);
      acc0[j] = fmaf(xa[3], r3[j], acc0[j]);
      acc1[j] = fmaf(xb[0], r0[j], acc1[j]);
      acc1[j] = fmaf(xb[1], r1[j], acc1[j]);
      acc1[j] = fmaf(xb[2], r2[j], acc1[j]);
      acc1[j] = fmaf(xb[3], r3[j], acc1[j]);
    }
  }
#pragma unroll
  for (int j=0;j<4;j++){ float bv = B0v[d0+j]; acc0[j] += bv; acc1[j] += bv; }

  // store raw Y0
  {
    size_t r0 = ((size_t)g*KS + k0)*64 + d0;
    *(float4*)&g_y0[r0]      = *(float4*)acc0;
    *(float4*)&g_y0[r0 + 64] = *(float4*)acc1;
  }

  float s[4], q[4];
#pragma unroll
  for (int j=0;j<4;j++){ s[j] = acc0[j]+acc1[j]; q[j] = acc0[j]*acc0[j] + acc1[j]*acc1[j]; }
#pragma unroll
  for (int j=0;j<4;j++){
    s[j] += __shfl_down(s[j],32); s[j] += __shfl_down(s[j],16);
    q[j] += __shfl_down(q[j],32); q[j] += __shfl_down(q[j],16);
  }
  if (lane < 16){
#pragma unroll
    for (int j=0;j<4;j++){ wsum[w][lane*4+j] = s[j]; wsq[w][lane*4+j] = q[j]; }
  }
  __syncthreads();
  if (tid < 64){
    float S = wsum[0][tid]+wsum[1][tid]+wsum[2][tid]+wsum[3][tid];
    float Q = wsq[0][tid]+wsq[1][tid]+wsq[2][tid]+wsq[3][tid];
    int bucket = g & 127;
    atomicAdd(&stats[(size_t)bucket*256 + tid], (double)S);
    atomicAdd(&stats[(size_t)bucket*256 + 128 + tid], (double)Q);
  }
}

// ---------------- K_mlpB: Y0 + BN0/ReLU -> L1 -> Y1 (raw) + stats1 ----------------
__global__ __launch_bounds__(256) void k_mlpB(
    const float* __restrict__ W1, const float* __restrict__ B1v){
  double* stats = g_stats + (size_t)1*128*256;
  const int g = blockIdx.x, tid = threadIdx.x;
  __shared__ __align__(16) float xn[32][68];
  __shared__ __align__(16) float w1s[64][64];
  __shared__ float wsum[4][64], wsq[4][64];

  for (int i = tid; i < 64*64; i += 256) w1s[i>>6][i&63] = W1[i];
  {
    int k = tid >> 3, j = tid & 7;
    const float4* pr = (const float4*)(g_y0 + ((size_t)g*KS + k)*64);
    float4 v0 = pr[j*2], v1 = pr[j*2+1];
    int c0 = j*8;
    xn[k][c0+0] = fmaxf(fmaf(v0.x, g_A[c0+0], g_Bv[c0+0]), 0.f);
    xn[k][c0+1] = fmaxf(fmaf(v0.y, g_A[c0+1], g_Bv[c0+1]), 0.f);
    xn[k][c0+2] = fmaxf(fmaf(v0.z, g_A[c0+2], g_Bv[c0+2]), 0.f);
    xn[k][c0+3] = fmaxf(fmaf(v0.w, g_A[c0+3], g_Bv[c0+3]), 0.f);
    xn[k][c0+4] = fmaxf(fmaf(v1.x, g_A[c0+4], g_Bv[c0+4]), 0.f);
    xn[k][c0+5] = fmaxf(fmaf(v1.y, g_A[c0+5], g_Bv[c0+5]), 0.f);
    xn[k][c0+6] = fmaxf(fmaf(v1.z, g_A[c0+6], g_Bv[c0+6]), 0.f);
    xn[k][c0+7] = fmaxf(fmaf(v1.w, g_A[c0+7], g_Bv[c0+7]), 0.f);
  }
  __syncthreads();

  const int k0 = (tid >> 4) * 2;
  const int d0 = (tid & 15) * 4;
  const int lane = tid & 63, w = tid >> 6;

  float bc0[4] = {0.f,0.f,0.f,0.f};
  float bc1[4] = {0.f,0.f,0.f,0.f};
#pragma unroll
  for (int cq = 0; cq < 16; ++cq){
    const int c = cq*4;
    float xa[4], xb[4], r0[4], r1[4], r2[4], r3[4];
    *(float4*)xa = *(const float4*)&xn[k0][c];
    *(float4*)xb = *(const float4*)&xn[k0+1][c];
    *(float4*)r0 = *(const float4*)&w1s[c+0][d0];
    *(float4*)r1 = *(const float4*)&w1s[c+1][d0];
    *(float4*)r2 = *(const float4*)&w1s[c+2][d0];
    *(float4*)r3 = *(const float4*)&w1s[c+3][d0];
#pragma unroll
    for (int j=0;j<4;j++){
      bc0[j] = fmaf(xa[0], r0[j], bc0[j]);
      bc0[j] = fmaf(xa[1], r1[j], bc0[j]);
      bc0[j] = fmaf(xa[2], r2[j], bc0[j]);
      bc0[j] = fmaf(xa[3], r3[j], bc0[j]);
      bc1[j] = fmaf(xb[0], r0[j], bc1[j]);
      bc1[j] = fmaf(xb[1], r1[j], bc1[j]);
      bc1[j] = fmaf(xb[2], r2[j], bc1[j]);
      bc1[j] = fmaf(xb[3], r3[j], bc1[j]);
    }
  }
#pragma unroll
  for (int j=0;j<4;j++){ float bv = B1v[d0+j]; bc0[j] += bv; bc1[j] += bv; }

  {
    size_t r0 = ((size_t)g*KS + k0)*64 + d0;
    *(float4*)&g_y1[r0]      = *(float4*)bc0;
    *(float4*)&g_y1[r0 + 64] = *(float4*)bc1;
  }

  float s[4], q[4];
#pragma unroll
  for (int j=0;j<4;j++){ s[j] = bc0[j]+bc1[j]; q[j] = bc0[j]*bc0[j] + bc1[j]*bc1[j]; }
#pragma unroll
  for (int j=0;j<4;j++){
    s[j] += __shfl_down(s[j],32); s[j] += __shfl_down(s[j],16);
    q[j] += __shfl_down(q[j],32); q[j] += __shfl_down(q[j],16);
  }
  if (lane < 16){
#pragma unroll
    for (int j=0;j<4;j++){ wsum[w][lane*4+j] = s[j]; wsq[w][lane*4+j] = q[j]; }
  }
  __syncthreads();
  if (tid < 64){
    float S = wsum[0][tid]+wsum[1][tid]+wsum[2][tid]+wsum[3][tid];
    float Q = wsq[0][tid]+wsq[1][tid]+wsq[2][tid]+wsq[3][tid];
    int bucket = g & 127;
    atomicAdd(&stats[(size_t)bucket*256 + tid], (double)S);
    atomicAdd(&stats[(size_t)bucket*256 + 128 + tid], (double)Q);
  }
}

// ---------------- K_mlpC: Y1 + BN1/ReLU -> L2 -> stats2 + max/min ----------------
__global__ __launch_bounds__(256) void k_mlpC(
    const float* __restrict__ W2, const float* __restrict__ B2v){
  double* stats = g_stats + (size_t)2*128*256;
  const int g = blockIdx.x, tid = threadIdx.x;
  __shared__ __align__(16) float xt[32][68];
  __shared__ __align__(16) float w2s[64][128];
  __shared__ float wsum[4][128], wsq[4][128];
  __shared__ float wmx[4][128], wmn[4][128];

  for (int i = tid; i < 64*128; i += 256) w2s[i>>7][i&127] = W2[i];
  {
    int k = tid >> 3, j = tid & 7;
    const float4* pr = (const float4*)(g_y1 + ((size_t)g*KS + k)*64);
    float4 v0 = pr[j*2], v1 = pr[j*2+1];
    int c0 = j*8;
    xt[k][c0+0] = fmaxf(fmaf(v0.x, g_A[64+c0+0], g_Bv[64+c0+0]), 0.f);
    xt[k][c0+1] = fmaxf(fmaf(v0.y, g_A[64+c0+1], g_Bv[64+c0+1]), 0.f);
    xt[k][c0+2] = fmaxf(fmaf(v0.z, g_A[64+c0+2], g_Bv[64+c0+2]), 0.f);
    xt[k][c0+3] = fmaxf(fmaf(v0.w, g_A[64+c0+3], g_Bv[64+c0+3]), 0.f);
    xt[k][c0+4] = fmaxf(fmaf(v1.x, g_A[64+c0+4], g_Bv[64+c0+4]), 0.f);
    xt[k][c0+5] = fmaxf(fmaf(v1.y, g_A[64+c0+5], g_Bv[64+c0+5]), 0.f);
    xt[k][c0+6] = fmaxf(fmaf(v1.z, g_A[64+c0+6], g_Bv[64+c0+6]), 0.f);
    xt[k][c0+7] = fmaxf(fmaf(v1.w, g_A[64+c0+7], g_Bv[64+c0+7]), 0.f);
  }
  __syncthreads();

  const int k0 = (tid >> 4) * 2;
  const int e0 = (tid & 15) * 8;
  const int lane = tid & 63, w = tid >> 6;

  float c0a[8] = {0.f,0.f,0.f,0.f,0.f,0.f,0.f,0.f};
  float c1a[8] = {0.f,0.f,0.f,0.f,0.f,0.f,0.f,0.f};
#pragma unroll
  for (int cq = 0; cq < 16; ++cq){
    const int c = cq*4;
    float xa[4], xb[4], r0[8], r1[8], r2[8], r3[8];
    *(float4*)xa = *(const float4*)&xt[k0][c];
    *(float4*)xb = *(const float4*)&xt[k0+1][c];
    *(float4*)&r0[0] = *(const float4*)&w2s[c+0][e0]; *(float4*)&r0[4] = *(const float4*)&w2s[c+0][e0+4];
    *(float4*)&r1[0] = *(const float4*)&w2s[c+1][e0]; *(float4*)&r1[4] = *(const float4*)&w2s[c+1][e0+4];
    *(float4*)&r2[0] = *(const float4*)&w2s[c+2][e0]; *(float4*)&r2[4] = *(const float4*)&w2s[c+2][e0+4];
    *(float4*)&r3[0] = *(const float4*)&w2s[c+3][e0]; *(float4*)&r3[4] = *(const float4*)&w2s[c+3][e0+4];
#pragma unroll
    for (int j=0;j<8;j++){
      c0a[j] = fmaf(xa[0], r0[j], c0a[j]);
      c0a[j] = fmaf(xa[1], r1[j], c0a[j]);
      c0a[j] = fmaf(xa[2], r2[j], c0a[j]);
      c0a[j] = fmaf(xa[3], r3[j], c0a[j]);
      c1a[j] = fmaf(xb[0], r0[j], c1a[j]);
      c1a[j] = fmaf(xb[1], r1[j], c1a[j]);
      c1a[j] = fmaf(xb[2], r2[j], c1a[j]);
      c1a[j] = fmaf(xb[3], r3[j], c1a[j]);
    }
  }
#pragma unroll
  for (int j=0;j<8;j++){ float bv = B2v[e0+j]; c0a[j] += bv; c1a[j] += bv; }

  float s[8], q[8], mx[8], mn[8];
#pragma unroll
  for (int j=0;j<8;j++){
    s[j] = c0a[j]+c1a[j]; q[j] = c0a[j]*c0a[j] + c1a[j]*c1a[j];
    mx[j] = fmaxf(c0a[j], c1a[j]); mn[j] = fminf(c0a[j], c1a[j]);
  }
#pragma unroll
  for (int j=0;j<8;j++){
    s[j] += __shfl_down(s[j],32); s[j] += __shfl_down(s[j],16);
    q[j] += __shfl_down(q[j],32); q[j] += __shfl_down(q[j],16);
    mx[j] = fmaxf(mx[j], __shfl_xor(mx[j],16)); mx[j] = fmaxf(mx[j], __shfl_xor(mx[j],32));
    mn[j] = fminf(mn[j], __shfl_xor(mn[j],16)); mn[j] = fminf(mn[j], __shfl_xor(mn[j],32));
  }
  if (lane < 16){
#pragma unroll
    for (int j=0;j<8;j++){
      wsum[w][lane*8+j] = s[j]; wsq[w][lane*8+j] = q[j];
      wmx[w][lane*8+j] = mx[j]; wmn[w][lane*8+j] = mn[j];
    }
  }
  __syncthreads();
  if (tid < 128){
    float S = wsum[0][tid]+wsum[1][tid]+wsum[2][tid]+wsum[3][tid];
    float Q = wsq[0][tid]+wsq[1][tid]+wsq[2][tid]+wsq[3][tid];
    float MX = fmaxf(fmaxf(wmx[0][tid],wmx[1][tid]), fmaxf(wmx[2][tid],wmx[3][tid]));
    float MN = fminf(fminf(wmn[0][tid],wmn[1][tid]), fminf(wmn[2][tid],wmn[3][tid]));
    g_mmax[(size_t)g*128 + tid] = MX;
    g_mmin[(size_t)g*128 + tid] = MN;
    int bucket = g & 127;
    atomicAdd(&stats[(size_t)bucket*256 + tid], (double)S);
    atomicAdd(&stats[(size_t)bucket*256 + 128 + tid], (double)Q);
  }
}

// ---------------- K_stats ----------------
__global__ void k_stats(int stage, const float* __restrict__ gamma,
                        const float* __restrict__ beta, int aoff, int cout){
  int c = threadIdx.x;
  if (c >= cout) return;
  const double* stats = g_stats + (size_t)stage*128*256;
  double S=0.0, Q=0.0;
  for (int k=0;k<128;k++){ S += stats[(size_t)k*256 + c]; Q += stats[(size_t)k*256 + 128 + c]; }
  const double M = (double)MROWS;
  double mean = S / M;
  double var  = Q / M - mean*mean;
  double inv  = 1.0 / sqrt(var + 1e-5);
  double a    = (double)gamma[c] * inv;
  g_A[aoff+c]  = (float)a;
  g_Bv[aoff+c] = (float)((double)beta[c] - mean * a);
}

// ---------------- K_final ----------------
__global__ __launch_bounds__(256) void k_final(float* __restrict__ outp){
  int idx = blockIdx.x*256 + threadIdx.x;
  int d = idx & 127;
  float a = g_A[128+d], b = g_Bv[128+d];
  float y = (a >= 0.f) ? g_mmax[idx] : g_mmin[idx];
  float v = fmaf(y, a, b);
  outp[idx] = fmaxf(v, 0.f);
}

extern "C" void kernel_launch(void* const* d_in, const int* in_sizes, int n_in,
                              void* d_out, int out_size, void* d_ws, size_t ws_size,
                              hipStream_t stream) {
  (void)in_sizes; (void)n_in; (void)out_size; (void)d_ws; (void)ws_size;
  const float* xyz    = (const float*)d_in[0];
  const float* points = (const float*)d_in[1];
  const int*   start  = (const int*)d_in[2];
  const float* W0 = (const float*)d_in[3];  const float* b0 = (const float*)d_in[4];
  const float* g0 = (const float*)d_in[5];  const float* be0= (const float*)d_in[6];
  const float* W1 = (const float*)d_in[7];  const float* b1 = (const float*)d_in[8];
  const float* g1 = (const float*)d_in[9];  const float* be1= (const float*)d_in[10];
  const float* W2 = (const float*)d_in[11]; const float* b2 = (const float*)d_in[12];
  const float* g2 = (const float*)d_in[13]; const float* be2= (const float*)d_in[14];

  float* out_xyz = (float*)d_out;
  float* out_pts = (float*)d_out + (size_t)NBATCH*SG*3;

  k_zero <<<384, 256, 0, stream>>>();
  k_pre  <<<256, 256, 0, stream>>>(xyz);
  k_fps  <<<NBATCH, NT, 0, stream>>>(start, out_xyz);
  k_ball <<<4096, 256, 0, stream>>>();

  k_mlpA<<<NGRP, 256, 0, stream>>>(points, W0, b0);
  k_stats<<<1, 128, 0, stream>>>(0, g0, be0, 0, 64);
  k_mlpB<<<NGRP, 256, 0, stream>>>(W1, b1);
  k_stats<<<1, 128, 0, stream>>>(1, g1, be1, 64, 64);
  k_mlpC<<<NGRP, 256, 0, stream>>>(W2, b2);
  k_stats<<<1, 128, 0, stream>>>(2, g2, be2, 128, 128);
  k_final<<<8192, 256, 0, stream>>>(out_pts);
}

// Round 4
// 3053.636 us; speedup vs baseline: 1.1975x; 1.0619x over previous
//
#include <hip/hip_runtime.h>
#include <stdint.h>
#include <stddef.h>

typedef unsigned long long u64;
typedef unsigned int u32;

#define NBATCH 8
#define NPTS   8192
#define SG     2048
#define KS     32
#define NGRP   (NBATCH*SG)      // 16384
#define MROWS  (NGRP*KS)        // 524288

// ---- ALL scratch in module-static device globals: immune to ws_size ----
__device__ float4 g_p4[NBATCH*NPTS];          // 1 MiB  {x,y,z,|p|^2}
__device__ float  g_cx[NGRP], g_cy[NGRP], g_cz[NGRP];
__device__ int    g_ball[(size_t)NGRP*KS];    // 2 MiB
__device__ double g_stats[3*128*256];         // 768 KiB
__device__ float  g_A[256], g_Bv[256];        // BN scale/shift: L0 @0, L1 @64, L2 @128
__device__ float  g_mmax[(size_t)NGRP*128];   // 8 MiB
__device__ float  g_mmin[(size_t)NGRP*128];   // 8 MiB
__device__ float  g_y0[(size_t)MROWS*64];     // 134 MiB raw L0 output
__device__ float  g_y1[(size_t)MROWS*64];     // 134 MiB raw L1 output

// ---------------- K_zero ----------------
__global__ __launch_bounds__(256) void k_zero(){
  int idx = blockIdx.x*256 + threadIdx.x;
  if (idx < 3*128*256) g_stats[idx] = 0.0;
}

// ---------------- K_pre ----------------
__global__ __launch_bounds__(256) void k_pre(const float* __restrict__ xyz){
#pragma clang fp contract(off)
  int idx = blockIdx.x*256 + threadIdx.x;
  if (idx >= NBATCH*NPTS) return;
  float x = xyz[idx*3+0];
  float y = xyz[idx*3+1];
  float z = xyz[idx*3+2];
  float xx = x*x; float yy = y*y; float zz = z*z;
  float s2 = (xx + yy) + zz;
  g_p4[idx] = make_float4(x,y,z,s2);
}

// ---------------- K_fps ----------------
// Evidence trail:
//   r0/r1 (256thr, regs, VGPR=88 spilling): 2573us.
//   r2   (512thr, dist in LDS): DS-throughput-bound, 3054us.
//   r3   (1024thr x 8ppt, all-reg, VGPR=40, NO spill): 2634us — barely
//        better than the SPILLING r0. => spill was never the dominant
//        term. VALUBusy x32 ~= 83%: ~2560 busy cyc/iter vs ~700 cyc of
//        distance math. The reduce machinery dominates:
//        6-step u64 shfl (12 ds_bpermute/wave) + ALL 1024 threads
//        redundantly reading 16 partials (256 ds_read_b64) + 15-cmp u64
//        tree per thread => ~450 DS wave-ops/iter ~ 2700cyc on 1 DS pipe.
// r4 FIX: de-duplicate the reduce.
//   * per-wave: only 2 xor-shuffle steps (32,16) -> lanes 0..15 hold the
//     16 disjoint {l, l^16, l^32, l^48} group maxes; write 16 partials.
//   * wave 0 alone reduces all 256 partials (4 reads/lane + 3 cmps +
//     6-step xor reduce) and publishes the winning key to kfin.
//   * barrier2; everyone reads kfin (broadcast), decodes far, loads fc.
//   DS ops/iter ~450 -> ~115. Exactness: u64 max is associative +
//   commutative and keys are unique ((dist_bits<<32)|(8191-gi)), so any
//   tree shape gives the identical (max dist, min index) winner ->
//   centroid sequence bit-identical. Two barriers/iter make the
//   single-buffered kfin provably race-free (each read precedes the next
//   write via barrier1 of it+1).
// Distance math unchanged bits: contract(off), (a0+a1)+a2, fminf chain;
// gi = i*1024+t keeps ascending local i == ascending gi per thread.

#define NT  1024
#define PPT 8

#define FOR8(M) M(0) M(1) M(2) M(3) M(4) M(5) M(6) M(7)

#define DECLP(i) float px##i, py##i, pz##i, dd##i;

#define LOADP(i) { float4 p_ = g_p4[base + (i)*NT + t]; \
                   px##i = p_.x; py##i = p_.y; pz##i = p_.z; dd##i = 1e10f; }

#define UPD(i) { float dx = px##i - fc.x; \
                 float dy = py##i - fc.y; \
                 float dz = pz##i - fc.z; \
                 float a0 = dx*dx; float a1 = dy*dy; float a2 = dz*dz; \
                 float d  = (a0 + a1) + a2; \
                 float nd = fminf(dd##i, d); \
                 dd##i = nd; \
                 if (nd > bv){ bv = nd; bi = (i); } }

__global__ __launch_bounds__(NT, 1) void k_fps(const int* __restrict__ start, float* __restrict__ out_xyz){
  const int b = blockIdx.x;
  const int t = threadIdx.x;
  const int base = b*NPTS;
  __shared__ u64 wk[256];    // 16 waves x 16 group-max partials
  __shared__ u64 kfin;       // winning key

  FOR8(DECLP)
  FOR8(LOADP)

  int far = start[b];
  float4 fc = g_p4[base+far];
  if (t==0){
    g_cx[b*SG]=fc.x; g_cy[b*SG]=fc.y; g_cz[b*SG]=fc.z;
    size_t o = (size_t)(b*SG)*3;
    out_xyz[o+0]=fc.x; out_xyz[o+1]=fc.y; out_xyz[o+2]=fc.z;
  }
  const int lane = t & 63, w = t >> 6;   // w in 0..15
  for (int it=1; it<SG; ++it){
    float bv = -1.0f; int bi = 0;
    {
#pragma clang fp contract(off)
      FOR8(UPD)
    }
    int gi = bi*NT + t;
    u64 key = ((u64)__float_as_uint(bv) << 32) | (u32)(NPTS-1 - gi);
    // 2-step xor butterfly: lane l -> max over {l, l^16, l^32, l^48}
    { u64 k2 = __shfl_xor(key, 32); if (k2 > key) key = k2; }
    { u64 k2 = __shfl_xor(key, 16); if (k2 > key) key = k2; }
    if (lane < 16) wk[w*16 + lane] = key;
    __syncthreads();
    if (w == 0){
      u64 ka = wk[lane], kb = wk[lane+64], kc = wk[lane+128], kd = wk[lane+192];
      u64 ke = (ka > kb) ? ka : kb;
      u64 kf = (kc > kd) ? kc : kd;
      u64 km = (ke > kf) ? ke : kf;
#pragma unroll
      for (int off=32; off>=1; off>>=1){
        u64 k2 = __shfl_xor(km, off);
        if (k2 > km) km = k2;
      }
      if (lane == 0) kfin = km;
    }
    __syncthreads();
    u64 km = kfin;
    far = NPTS-1 - (int)(km & 0xffffffffu);
    fc = g_p4[base+far];
    if (t==0){
      g_cx[b*SG+it]=fc.x; g_cy[b*SG+it]=fc.y; g_cz[b*SG+it]=fc.z;
      size_t o = (size_t)(b*SG+it)*3;
      out_xyz[o+0]=fc.x; out_xyz[o+1]=fc.y; out_xyz[o+2]=fc.z;
    }
  }
}

// ---------------- K_ball: expansion form, FMA-ascending dot (PASSED r7, do not touch) ----------------
__global__ __launch_bounds__(256) void k_ball(){
  const int g = blockIdx.x*4 + (threadIdx.x>>6);
  const int lane = threadIdx.x & 63;
  const int b = g >> 11;
  const float4* pb4 = g_p4 + b*NPTS;
  float cxv = g_cx[g], cyv = g_cy[g], czv = g_cz[g];
  float s1;
  {
#pragma clang fp contract(off)
    float a = cxv*cxv; float bb = cyv*cyv; float cc = czv*czv;
    s1 = (a + bb) + cc;
  }
  const float R2 = 0.04f;
  int filled = 0, firstn = -1;
  for (int n0=0; n0<NPTS && filled<KS; n0+=64){
    float4 p = pb4[n0+lane];
    float sq;
    {
#pragma clang fp contract(off)
      float dt = cxv*p.x;
      dt = fmaf(cyv, p.y, dt);
      dt = fmaf(czv, p.z, dt);
      float ss = s1 + p.w;
      sq = ss - 2.0f*dt;
    }
    bool mem = !(sq > R2);
    u64 mk = __ballot(mem);
    if (firstn < 0 && mk) firstn = n0 + (__ffsll((unsigned long long)mk) - 1);
    int pos = filled + (int)__popcll(mk & ((1ull<<lane)-1ull));
    if (mem && pos < KS) g_ball[(size_t)g*KS + pos] = n0 + lane;
    filled += (int)__popcll(mk);
  }
  for (int s = filled + lane; s < KS; s += 64) g_ball[(size_t)g*KS+s] = firstn;
}

// ---------------- K_mlpA: gather + L0 -> Y0 (raw f32) + stats0 ----------------
__global__ __launch_bounds__(256) void k_mlpA(
    const float* __restrict__ points,
    const float* __restrict__ W0, const float* __restrict__ B0v){
  double* stats = g_stats;
  const int g = blockIdx.x, tid = threadIdx.x;
  const int b = g >> 11;
  __shared__ __align__(16) float xt[32][68];
  __shared__ __align__(16) float w0s[68][64];
  __shared__ float wsum[4][64], wsq[4][64];

  for (int i = tid; i < 67*64; i += 256) w0s[i>>6][i&63] = W0[i];
  if (tid < 64) w0s[67][tid] = 0.f;

  if (tid < 32){
    int n = g_ball[(size_t)g*KS + tid];
    float4 p = g_p4[b*NPTS + n];
    xt[tid][0] = p.x - g_cx[g];
    xt[tid][1] = p.y - g_cy[g];
    xt[tid][2] = p.z - g_cz[g];
    xt[tid][67] = 0.f;
  }
  {
    int k = tid >> 3, j = tid & 7;
    int n = g_ball[(size_t)g*KS + k];
    const float4* pr = (const float4*)(points + ((size_t)(b*NPTS + n))*64);
    float4 v0 = pr[j*2], v1 = pr[j*2+1];
    int c0 = 3 + j*8;
    xt[k][c0+0]=v0.x; xt[k][c0+1]=v0.y; xt[k][c0+2]=v0.z; xt[k][c0+3]=v0.w;
    xt[k][c0+4]=v1.x; xt[k][c0+5]=v1.y; xt[k][c0+6]=v1.z; xt[k][c0+7]=v1.w;
  }
  __syncthreads();

  const int k0 = (tid >> 4) * 2;
  const int d0 = (tid & 15) * 4;
  const int lane = tid & 63, w = tid >> 6;

  float acc0[4] = {0.f,0.f,0.f,0.f};
  float acc1[4] = {0.f,0.f,0.f,0.f};
#pragma unroll
  for (int cq = 0; cq < 17; ++cq){
    const int c = cq*4;
    float xa[4], xb[4], r0[4], r1[4], r2[4], r3[4];
    *(float4*)xa = *(const float4*)&xt[k0][c];
    *(float4*)xb = *(const float4*)&xt[k0+1][c];
    *(float4*)r0 = *(const float4*)&w0s[c+0][d0];
    *(float4*)r1 = *(const float4*)&w0s[c+1][d0];
    *(float4*)r2 = *(const float4*)&w0s[c+2][d0];
    *(float4*)r3 = *(const float4*)&w0s[c+3][d0];
#pragma unroll
    for (int j=0;j<4;j++){
      acc0[j] = fmaf(xa[0], r0[j], acc0[j]);
      acc0[j] = fmaf(xa[1], r1[j], acc0[j]);
      acc0[j] = fmaf(xa[2], r2[j], acc0[j]);
      acc0[j] = fmaf(xa[3], r3[j], acc0[j]);
      acc1[j] = fmaf(xb[0], r0[j], acc1[j]);
      acc1[j] = fmaf(xb[1], r1[j], acc1[j]);
      acc1[j] = fmaf(xb[2], r2[j], acc1[j]);
      acc1[j] = fmaf(xb[3], r3[j], acc1[j]);
    }
  }
#pragma unroll
  for (int j=0;j<4;j++){ float bv = B0v[d0+j]; acc0[j] += bv; acc1[j] += bv; }

  // store raw Y0
  {
    size_t r0 = ((size_t)g*KS + k0)*64 + d0;
    *(float4*)&g_y0[r0]      = *(float4*)acc0;
    *(float4*)&g_y0[r0 + 64] = *(float4*)acc1;
  }

  float s[4], q[4];
#pragma unroll
  for (int j=0;j<4;j++){ s[j] = acc0[j]+acc1[j]; q[j] = acc0[j]*acc0[j] + acc1[j]*acc1[j]; }
#pragma unroll
  for (int j=0;j<4;j++){
    s[j] += __shfl_down(s[j],32); s[j] += __shfl_down(s[j],16);
    q[j] += __shfl_down(q[j],32); q[j] += __shfl_down(q[j],16);
  }
  if (lane < 16){
#pragma unroll
    for (int j=0;j<4;j++){ wsum[w][lane*4+j] = s[j]; wsq[w][lane*4+j] = q[j]; }
  }
  __syncthreads();
  if (tid < 64){
    float S = wsum[0][tid]+wsum[1][tid]+wsum[2][tid]+wsum[3][tid];
    float Q = wsq[0][tid]+wsq[1][tid]+wsq[2][tid]+wsq[3][tid];
    int bucket = g & 127;
    atomicAdd(&stats[(size_t)bucket*256 + tid], (double)S);
    atomicAdd(&stats[(size_t)bucket*256 + 128 + tid], (double)Q);
  }
}

// ---------------- K_mlpB: Y0 + BN0/ReLU -> L1 -> Y1 (raw) + stats1 ----------------
__global__ __launch_bounds__(256) void k_mlpB(
    const float* __restrict__ W1, const float* __restrict__ B1v){
  double* stats = g_stats + (size_t)1*128*256;
  const int g = blockIdx.x, tid = threadIdx.x;
  __shared__ __align__(16) float xn[32][68];
  __shared__ __align__(16) float w1s[64][64];
  __shared__ float wsum[4][64], wsq[4][64];

  for (int i = tid; i < 64*64; i += 256) w1s[i>>6][i&63] = W1[i];
  {
    int k = tid >> 3, j = tid & 7;
    const float4* pr = (const float4*)(g_y0 + ((size_t)g*KS + k)*64);
    float4 v0 = pr[j*2], v1 = pr[j*2+1];
    int c0 = j*8;
    xn[k][c0+0] = fmaxf(fmaf(v0.x, g_A[c0+0], g_Bv[c0+0]), 0.f);
    xn[k][c0+1] = fmaxf(fmaf(v0.y, g_A[c0+1], g_Bv[c0+1]), 0.f);
    xn[k][c0+2] = fmaxf(fmaf(v0.z, g_A[c0+2], g_Bv[c0+2]), 0.f);
    xn[k][c0+3] = fmaxf(fmaf(v0.w, g_A[c0+3], g_Bv[c0+3]), 0.f);
    xn[k][c0+4] = fmaxf(fmaf(v1.x, g_A[c0+4], g_Bv[c0+4]), 0.f);
    xn[k][c0+5] = fmaxf(fmaf(v1.y, g_A[c0+5], g_Bv[c0+5]), 0.f);
    xn[k][c0+6] = fmaxf(fmaf(v1.z, g_A[c0+6], g_Bv[c0+6]), 0.f);
    xn[k][c0+7] = fmaxf(fmaf(v1.w, g_A[c0+7], g_Bv[c0+7]), 0.f);
  }
  __syncthreads();

  const int k0 = (tid >> 4) * 2;
  const int d0 = (tid & 15) * 4;
  const int lane = tid & 63, w = tid >> 6;

  float bc0[4] = {0.f,0.f,0.f,0.f};
  float bc1[4] = {0.f,0.f,0.f,0.f};
#pragma unroll
  for (int cq = 0; cq < 16; ++cq){
    const int c = cq*4;
    float xa[4], xb[4], r0[4], r1[4], r2[4], r3[4];
    *(float4*)xa = *(const float4*)&xn[k0][c];
    *(float4*)xb = *(const float4*)&xn[k0+1][c];
    *(float4*)r0 = *(const float4*)&w1s[c+0][d0];
    *(float4*)r1 = *(const float4*)&w1s[c+1][d0];
    *(float4*)r2 = *(const float4*)&w1s[c+2][d0];
    *(float4*)r3 = *(const float4*)&w1s[c+3][d0];
#pragma unroll
    for (int j=0;j<4;j++){
      bc0[j] = fmaf(xa[0], r0[j], bc0[j]);
      bc0[j] = fmaf(xa[1], r1[j], bc0[j]);
      bc0[j] = fmaf(xa[2], r2[j], bc0[j]);
      bc0[j] = fmaf(xa[3], r3[j], bc0[j]);
      bc1[j] = fmaf(xb[0], r0[j], bc1[j]);
      bc1[j] = fmaf(xb[1], r1[j], bc1[j]);
      bc1[j] = fmaf(xb[2], r2[j], bc1[j]);
      bc1[j] = fmaf(xb[3], r3[j], bc1[j]);
    }
  }
#pragma unroll
  for (int j=0;j<4;j++){ float bv = B1v[d0+j]; bc0[j] += bv; bc1[j] += bv; }

  {
    size_t r0 = ((size_t)g*KS + k0)*64 + d0;
    *(float4*)&g_y1[r0]      = *(float4*)bc0;
    *(float4*)&g_y1[r0 + 64] = *(float4*)bc1;
  }

  float s[4], q[4];
#pragma unroll
  for (int j=0;j<4;j++){ s[j] = bc0[j]+bc1[j]; q[j] = bc0[j]*bc0[j] + bc1[j]*bc1[j]; }
#pragma unroll
  for (int j=0;j<4;j++){
    s[j] += __shfl_down(s[j],32); s[j] += __shfl_down(s[j],16);
    q[j] += __shfl_down(q[j],32); q[j] += __shfl_down(q[j],16);
  }
  if (lane < 16){
#pragma unroll
    for (int j=0;j<4;j++){ wsum[w][lane*4+j] = s[j]; wsq[w][lane*4+j] = q[j]; }
  }
  __syncthreads();
  if (tid < 64){
    float S = wsum[0][tid]+wsum[1][tid]+wsum[2][tid]+wsum[3][tid];
    float Q = wsq[0][tid]+wsq[1][tid]+wsq[2][tid]+wsq[3][tid];
    int bucket = g & 127;
    atomicAdd(&stats[(size_t)bucket*256 + tid], (double)S);
    atomicAdd(&stats[(size_t)bucket*256 + 128 + tid], (double)Q);
  }
}

// ---------------- K_mlpC: Y1 + BN1/ReLU -> L2 -> stats2 + max/min ----------------
__global__ __launch_bounds__(256) void k_mlpC(
    const float* __restrict__ W2, const float* __restrict__ B2v){
  double* stats = g_stats + (size_t)2*128*256;
  const int g = blockIdx.x, tid = threadIdx.x;
  __shared__ __align__(16) float xt[32][68];
  __shared__ __align__(16) float w2s[64][128];
  __shared__ float wsum[4][128], wsq[4][128];
  __shared__ float wmx[4][128], wmn[4][128];

  for (int i = tid; i < 64*128; i += 256) w2s[i>>7][i&127] = W2[i];
  {
    int k = tid >> 3, j = tid & 7;
    const float4* pr = (const float4*)(g_y1 + ((size_t)g*KS + k)*64);
    float4 v0 = pr[j*2], v1 = pr[j*2+1];
    int c0 = j*8;
    xt[k][c0+0] = fmaxf(fmaf(v0.x, g_A[64+c0+0], g_Bv[64+c0+0]), 0.f);
    xt[k][c0+1] = fmaxf(fmaf(v0.y, g_A[64+c0+1], g_Bv[64+c0+1]), 0.f);
    xt[k][c0+2] = fmaxf(fmaf(v0.z, g_A[64+c0+2], g_Bv[64+c0+2]), 0.f);
    xt[k][c0+3] = fmaxf(fmaf(v0.w, g_A[64+c0+3], g_Bv[64+c0+3]), 0.f);
    xt[k][c0+4] = fmaxf(fmaf(v1.x, g_A[64+c0+4], g_Bv[64+c0+4]), 0.f);
    xt[k][c0+5] = fmaxf(fmaf(v1.y, g_A[64+c0+5], g_Bv[64+c0+5]), 0.f);
    xt[k][c0+6] = fmaxf(fmaf(v1.z, g_A[64+c0+6], g_Bv[64+c0+6]), 0.f);
    xt[k][c0+7] = fmaxf(fmaf(v1.w, g_A[64+c0+7], g_Bv[64+c0+7]), 0.f);
  }
  __syncthreads();

  const int k0 = (tid >> 4) * 2;
  const int e0 = (tid & 15) * 8;
  const int lane = tid & 63, w = tid >> 6;

  float c0a[8] = {0.f,0.f,0.f,0.f,0.f,0.f,0.f,0.f};
  float c1a[8] = {0.f,0.f,0.f,0.f,0.f,0.f,0.f,0.f};
#pragma unroll
  for (int cq = 0; cq < 16; ++cq){
    const int c = cq*4;
    float xa[4], xb[4], r0[8], r1[8], r2[8], r3[8];
    *(float4*)xa = *(const float4*)&xt[k0][c];
    *(float4*)xb = *(const float4*)&xt[k0+1][c];
    *(float4*)&r0[0] = *(const float4*)&w2s[c+0][e0]; *(float4*)&r0[4] = *(const float4*)&w2s[c+0][e0+4];
    *(float4*)&r1[0] = *(const float4*)&w2s[c+1][e0]; *(float4*)&r1[4] = *(const float4*)&w2s[c+1][e0+4];
    *(float4*)&r2[0] = *(const float4*)&w2s[c+2][e0]; *(float4*)&r2[4] = *(const float4*)&w2s[c+2][e0+4];
    *(float4*)&r3[0] = *(const float4*)&w2s[c+3][e0]; *(float4*)&r3[4] = *(const float4*)&w2s[c+3][e0+4];
#pragma unroll
    for (int j=0;j<8;j++){
      c0a[j] = fmaf(xa[0], r0[j], c0a[j]);
      c0a[j] = fmaf(xa[1], r1[j], c0a[j]);
      c0a[j] = fmaf(xa[2], r2[j], c0a[j]);
      c0a[j] = fmaf(xa[3], r3[j], c0a[j]);
      c1a[j] = fmaf(xb[0], r0[j], c1a[j]);
      c1a[j] = fmaf(xb[1], r1[j], c1a[j]);
      c1a[j] = fmaf(xb[2], r2[j], c1a[j]);
      c1a[j] = fmaf(xb[3], r3[j], c1a[j]);
    }
  }
#pragma unroll
  for (int j=0;j<8;j++){ float bv = B2v[e0+j]; c0a[j] += bv; c1a[j] += bv; }

  float s[8], q[8], mx[8], mn[8];
#pragma unroll
  for (int j=0;j<8;j++){
    s[j] = c0a[j]+c1a[j]; q[j] = c0a[j]*c0a[j] + c1a[j]*c1a[j];
    mx[j] = fmaxf(c0a[j], c1a[j]); mn[j] = fminf(c0a[j], c1a[j]);
  }
#pragma unroll
  for (int j=0;j<8;j++){
    s[j] += __shfl_down(s[j],32); s[j] += __shfl_down(s[j],16);
    q[j] += __shfl_down(q[j],32); q[j] += __shfl_down(q[j],16);
    mx[j] = fmaxf(mx[j], __shfl_xor(mx[j],16)); mx[j] = fmaxf(mx[j], __shfl_xor(mx[j],32));
    mn[j] = fminf(mn[j], __shfl_xor(mn[j],16)); mn[j] = fminf(mn[j], __shfl_xor(mn[j],32));
  }
  if (lane < 16){
#pragma unroll
    for (int j=0;j<8;j++){
      wsum[w][lane*8+j] = s[j]; wsq[w][lane*8+j] = q[j];
      wmx[w][lane*8+j] = mx[j]; wmn[w][lane*8+j] = mn[j];
    }
  }
  __syncthreads();
  if (tid < 128){
    float S = wsum[0][tid]+wsum[1][tid]+wsum[2][tid]+wsum[3][tid];
    float Q = wsq[0][tid]+wsq[1][tid]+wsq[2][tid]+wsq[3][tid];
    float MX = fmaxf(fmaxf(wmx[0][tid],wmx[1][tid]), fmaxf(wmx[2][tid],wmx[3][tid]));
    float MN = fminf(fminf(wmn[0][tid],wmn[1][tid]), fminf(wmn[2][tid],wmn[3][tid]));
    g_mmax[(size_t)g*128 + tid] = MX;
    g_mmin[(size_t)g*128 + tid] = MN;
    int bucket = g & 127;
    atomicAdd(&stats[(size_t)bucket*256 + tid], (double)S);
    atomicAdd(&stats[(size_t)bucket*256 + 128 + tid], (double)Q);
  }
}

// ---------------- K_stats ----------------
__global__ void k_stats(int stage, const float* __restrict__ gamma,
                        const float* __restrict__ beta, int aoff, int cout){
  int c = threadIdx.x;
  if (c >= cout) return;
  const double* stats = g_stats + (size_t)stage*128*256;
  double S=0.0, Q=0.0;
  for (int k=0;k<128;k++){ S += stats[(size_t)k*256 + c]; Q += stats[(size_t)k*256 + 128 + c]; }
  const double M = (double)MROWS;
  double mean = S / M;
  double var  = Q / M - mean*mean;
  double inv  = 1.0 / sqrt(var + 1e-5);
  double a    = (double)gamma[c] * inv;
  g_A[aoff+c]  = (float)a;
  g_Bv[aoff+c] = (float)((double)beta[c] - mean * a);
}

// ---------------- K_final ----------------
__global__ __launch_bounds__(256) void k_final(float* __restrict__ outp){
  int idx = blockIdx.x*256 + threadIdx.x;
  int d = idx & 127;
  float a = g_A[128+d], b = g_Bv[128+d];
  float y = (a >= 0.f) ? g_mmax[idx] : g_mmin[idx];
  float v = fmaf(y, a, b);
  outp[idx] = fmaxf(v, 0.f);
}

extern "C" void kernel_launch(void* const* d_in, const int* in_sizes, int n_in,
                              void* d_out, int out_size, void* d_ws, size_t ws_size,
                              hipStream_t stream) {
  (void)in_sizes; (void)n_in; (void)out_size; (void)d_ws; (void)ws_size;
  const float* xyz    = (const float*)d_in[0];
  const float* points = (const float*)d_in[1];
  const int*   start  = (const int*)d_in[2];
  const float* W0 = (const float*)d_in[3];  const float* b0 = (const float*)d_in[4];
  const float* g0 = (const float*)d_in[5];  const float* be0= (const float*)d_in[6];
  const float* W1 = (const float*)d_in[7];  const float* b1 = (const float*)d_in[8];
  const float* g1 = (const float*)d_in[9];  const float* be1= (const float*)d_in[10];
  const float* W2 = (const float*)d_in[11]; const float* b2 = (const float*)d_in[12];
  const float* g2 = (const float*)d_in[13]; const float* be2= (const float*)d_in[14];

  float* out_xyz = (float*)d_out;
  float* out_pts = (float*)d_out + (size_t)NBATCH*SG*3;

  k_zero <<<384, 256, 0, stream>>>();
  k_pre  <<<256, 256, 0, stream>>>(xyz);
  k_fps  <<<NBATCH, NT, 0, stream>>>(start, out_xyz);
  k_ball <<<4096, 256, 0, stream>>>();

  k_mlpA<<<NGRP, 256, 0, stream>>>(points, W0, b0);
  k_stats<<<1, 128, 0, stream>>>(0, g0, be0, 0, 64);
  k_mlpB<<<NGRP, 256, 0, stream>>>(W1, b1);
  k_stats<<<1, 128, 0, stream>>>(1, g1, be1, 64, 64);
  k_mlpC<<<NGRP, 256, 0, stream>>>(W2, b2);
  k_stats<<<1, 128, 0, stream>>>(2, g2, be2, 128, 128);
  k_final<<<8192, 256, 0, stream>>>(out_pts);
}

// Round 5
// 2722.688 us; speedup vs baseline: 1.3430x; 1.1216x over previous
//
#include <hip/hip_runtime.h>
#include <stdint.h>
#include <stddef.h>

typedef unsigned long long u64;
typedef unsigned int u32;

#define NBATCH 8
#define NPTS   8192
#define SG     2048
#define KS     32
#define NGRP   (NBATCH*SG)      // 16384
#define MROWS  (NGRP*KS)        // 524288

// ---- ALL scratch in module-static device globals: immune to ws_size ----
__device__ float4 g_p4[NBATCH*NPTS];          // 1 MiB  {x,y,z,|p|^2}
__device__ float  g_cx[NGRP], g_cy[NGRP], g_cz[NGRP];
__device__ int    g_ball[(size_t)NGRP*KS];    // 2 MiB
__device__ double g_stats[3*128*256];         // 768 KiB
__device__ float  g_A[256], g_Bv[256];        // BN scale/shift: L0 @0, L1 @64, L2 @128
__device__ float  g_mmax[(size_t)NGRP*128];   // 8 MiB
__device__ float  g_mmin[(size_t)NGRP*128];   // 8 MiB
__device__ float  g_y0[(size_t)MROWS*64];     // 134 MiB raw L0 output
__device__ float  g_y1[(size_t)MROWS*64];     // 134 MiB raw L1 output

// ---------------- K_zero ----------------
__global__ __launch_bounds__(256) void k_zero(){
  int idx = blockIdx.x*256 + threadIdx.x;
  if (idx < 3*128*256) g_stats[idx] = 0.0;
}

// ---------------- K_pre ----------------
__global__ __launch_bounds__(256) void k_pre(const float* __restrict__ xyz){
#pragma clang fp contract(off)
  int idx = blockIdx.x*256 + threadIdx.x;
  if (idx >= NBATCH*NPTS) return;
  float x = xyz[idx*3+0];
  float y = xyz[idx*3+1];
  float z = xyz[idx*3+2];
  float xx = x*x; float yy = y*y; float zz = z*z;
  float s2 = (xx + yy) + zz;
  g_p4[idx] = make_float4(x,y,z,s2);
}

// ---------------- K_fps ----------------
// Evidence trail:
//   r0/r1: 256thr spilling regs — 2573us. r2: dist-in-LDS — DS-bound 3054us.
//   r3: 1024thr all-reg (VGPR=40) — 2634us. r4: dedup reduce (VALUBusy
//   2.58->1.73) — only 2452us. => latency-chain-bound: serial tail
//   [2 shfl, bar, wave0 {reads + u64 tree + 6-step u64 shfl ~300cy}, bar,
//    kfin read, fc GLOBAL load ~250cy] dominates while 15 waves idle.
// r5 chain surgery (exactness-preserving):
//   1) NO pre-barrier shuffles: every thread writes key to wk[t]; wave0
//      reads 16 strided keys/lane (one latency window) + 15-max ILP tree.
//   2) u64 max -> v_max_f64: keys are positive NaN-free f64 bit patterns
//      (dist f32 finite >=0 in high word => exp field never all-ones),
//      unique (idx field) => fmax ordering == u64 ordering bit-exactly.
//   3) fc from LDS point cache pc[8192] (128KiB static, preloaded once):
//      broadcast ds_read_b128 (~120cy) replaces L1-missing global (~250cy).
// Reduction over the same 1024 unique keys; max associative => identical
// winner => centroid sequence bit-identical. wk/kfin single-buffer safe
// via the two barriers (reads of iter it complete before writes of it+1).
// Distance math unchanged bits: contract(off), (a0+a1)+a2, fminf chain;
// gi = i*1024+t keeps ascending local i == ascending gi per thread.

#define NT  1024
#define PPT 8

#define FOR8(M) M(0) M(1) M(2) M(3) M(4) M(5) M(6) M(7)

#define DECLP(i) float px##i, py##i, pz##i, dd##i;

#define LOADP(i) { float4 p_ = g_p4[base + (i)*NT + t]; \
                   px##i = p_.x; py##i = p_.y; pz##i = p_.z; dd##i = 1e10f; }

#define UPD(i) { float dx = px##i - fc.x; \
                 float dy = py##i - fc.y; \
                 float dz = pz##i - fc.z; \
                 float a0 = dx*dx; float a1 = dy*dy; float a2 = dz*dz; \
                 float d  = (a0 + a1) + a2; \
                 float nd = fminf(dd##i, d); \
                 dd##i = nd; \
                 if (nd > bv){ bv = nd; bi = (i); } }

__global__ __launch_bounds__(NT, 1) void k_fps(const int* __restrict__ start, float* __restrict__ out_xyz){
  const int b = blockIdx.x;
  const int t = threadIdx.x;
  const int base = b*NPTS;
  __shared__ double wk[NT];                    // 8 KiB flat keys (as f64 bits)
  __shared__ double kfin;                      // winning key
  __shared__ __align__(16) float4 pc[NPTS];    // 128 KiB point cache

  // one-time preload of this batch's points into LDS
  for (int i = t; i < NPTS; i += NT) pc[i] = g_p4[base + i];

  FOR8(DECLP)
  FOR8(LOADP)

  int far = start[b];
  __syncthreads();                             // pc ready
  float4 fc = pc[far];
  if (t==0){
    g_cx[b*SG]=fc.x; g_cy[b*SG]=fc.y; g_cz[b*SG]=fc.z;
    size_t o = (size_t)(b*SG)*3;
    out_xyz[o+0]=fc.x; out_xyz[o+1]=fc.y; out_xyz[o+2]=fc.z;
  }
  for (int it=1; it<SG; ++it){
    float bv = -1.0f; int bi = 0;
    {
#pragma clang fp contract(off)
      FOR8(UPD)
    }
    int gi = bi*NT + t;
    u64 key = ((u64)__float_as_uint(bv) << 32) | (u32)(NPTS-1 - gi);
    wk[t] = __longlong_as_double((long long)key);
    __syncthreads();
    if (t < 64){
      // 16 strided reads: wk[t + 64j] — conflict-free-ish b64 pattern
      double v0  = wk[t      ], v1  = wk[t+ 64], v2  = wk[t+128], v3  = wk[t+192];
      double v4  = wk[t+256], v5  = wk[t+320], v6  = wk[t+384], v7  = wk[t+448];
      double v8  = wk[t+512], v9  = wk[t+576], v10 = wk[t+640], v11 = wk[t+704];
      double v12 = wk[t+768], v13 = wk[t+832], v14 = wk[t+896], v15 = wk[t+960];
      double a0 = fmax(v0,v1),   a1 = fmax(v2,v3),   a2 = fmax(v4,v5),   a3 = fmax(v6,v7);
      double a4 = fmax(v8,v9),   a5 = fmax(v10,v11), a6 = fmax(v12,v13), a7 = fmax(v14,v15);
      double b0 = fmax(a0,a1), b1 = fmax(a2,a3), b2 = fmax(a4,a5), b3 = fmax(a6,a7);
      double c0 = fmax(b0,b1), c1 = fmax(b2,b3);
      double m  = fmax(c0,c1);
#pragma unroll
      for (int off=32; off>=1; off>>=1){
        double o2 = __shfl_xor(m, off);
        m = fmax(m, o2);
      }
      if (t == 0) kfin = m;
    }
    __syncthreads();
    u64 km = (u64)__double_as_longlong(kfin);
    far = NPTS-1 - (int)(km & 0xffffffffu);
    fc = pc[far];
    if (t==0){
      g_cx[b*SG+it]=fc.x; g_cy[b*SG+it]=fc.y; g_cz[b*SG+it]=fc.z;
      size_t o = (size_t)(b*SG+it)*3;
      out_xyz[o+0]=fc.x; out_xyz[o+1]=fc.y; out_xyz[o+2]=fc.z;
    }
  }
}

// ---------------- K_ball: expansion form, FMA-ascending dot (PASSED r7, do not touch) ----------------
__global__ __launch_bounds__(256) void k_ball(){
  const int g = blockIdx.x*4 + (threadIdx.x>>6);
  const int lane = threadIdx.x & 63;
  const int b = g >> 11;
  const float4* pb4 = g_p4 + b*NPTS;
  float cxv = g_cx[g], cyv = g_cy[g], czv = g_cz[g];
  float s1;
  {
#pragma clang fp contract(off)
    float a = cxv*cxv; float bb = cyv*cyv; float cc = czv*czv;
    s1 = (a + bb) + cc;
  }
  const float R2 = 0.04f;
  int filled = 0, firstn = -1;
  for (int n0=0; n0<NPTS && filled<KS; n0+=64){
    float4 p = pb4[n0+lane];
    float sq;
    {
#pragma clang fp contract(off)
      float dt = cxv*p.x;
      dt = fmaf(cyv, p.y, dt);
      dt = fmaf(czv, p.z, dt);
      float ss = s1 + p.w;
      sq = ss - 2.0f*dt;
    }
    bool mem = !(sq > R2);
    u64 mk = __ballot(mem);
    if (firstn < 0 && mk) firstn = n0 + (__ffsll((unsigned long long)mk) - 1);
    int pos = filled + (int)__popcll(mk & ((1ull<<lane)-1ull));
    if (mem && pos < KS) g_ball[(size_t)g*KS + pos] = n0 + lane;
    filled += (int)__popcll(mk);
  }
  for (int s = filled + lane; s < KS; s += 64) g_ball[(size_t)g*KS+s] = firstn;
}

// ---------------- K_mlpA: gather + L0 -> Y0 (raw f32) + stats0 ----------------
__global__ __launch_bounds__(256) void k_mlpA(
    const float* __restrict__ points,
    const float* __restrict__ W0, const float* __restrict__ B0v){
  double* stats = g_stats;
  const int g = blockIdx.x, tid = threadIdx.x;
  const int b = g >> 11;
  __shared__ __align__(16) float xt[32][68];
  __shared__ __align__(16) float w0s[68][64];
  __shared__ float wsum[4][64], wsq[4][64];

  for (int i = tid; i < 67*64; i += 256) w0s[i>>6][i&63] = W0[i];
  if (tid < 64) w0s[67][tid] = 0.f;

  if (tid < 32){
    int n = g_ball[(size_t)g*KS + tid];
    float4 p = g_p4[b*NPTS + n];
    xt[tid][0] = p.x - g_cx[g];
    xt[tid][1] = p.y - g_cy[g];
    xt[tid][2] = p.z - g_cz[g];
    xt[tid][67] = 0.f;
  }
  {
    int k = tid >> 3, j = tid & 7;
    int n = g_ball[(size_t)g*KS + k];
    const float4* pr = (const float4*)(points + ((size_t)(b*NPTS + n))*64);
    float4 v0 = pr[j*2], v1 = pr[j*2+1];
    int c0 = 3 + j*8;
    xt[k][c0+0]=v0.x; xt[k][c0+1]=v0.y; xt[k][c0+2]=v0.z; xt[k][c0+3]=v0.w;
    xt[k][c0+4]=v1.x; xt[k][c0+5]=v1.y; xt[k][c0+6]=v1.z; xt[k][c0+7]=v1.w;
  }
  __syncthreads();

  const int k0 = (tid >> 4) * 2;
  const int d0 = (tid & 15) * 4;
  const int lane = tid & 63, w = tid >> 6;

  float acc0[4] = {0.f,0.f,0.f,0.f};
  float acc1[4] = {0.f,0.f,0.f,0.f};
#pragma unroll
  for (int cq = 0; cq < 17; ++cq){
    const int c = cq*4;
    float xa[4], xb[4], r0[4], r1[4], r2[4], r3[4];
    *(float4*)xa = *(const float4*)&xt[k0][c];
    *(float4*)xb = *(const float4*)&xt[k0+1][c];
    *(float4*)r0 = *(const float4*)&w0s[c+0][d0];
    *(float4*)r1 = *(const float4*)&w0s[c+1][d0];
    *(float4*)r2 = *(const float4*)&w0s[c+2][d0];
    *(float4*)r3 = *(const float4*)&w0s[c+3][d0];
#pragma unroll
    for (int j=0;j<4;j++){
      acc0[j] = fmaf(xa[0], r0[j], acc0[j]);
      acc0[j] = fmaf(xa[1], r1[j], acc0[j]);
      acc0[j] = fmaf(xa[2], r2[j], acc0[j]);
      acc0[j] = fmaf(xa[3], r3[j], acc0[j]);
      acc1[j] = fmaf(xb[0], r0[j], acc1[j]);
      acc1[j] = fmaf(xb[1], r1[j], acc1[j]);
      acc1[j] = fmaf(xb[2], r2[j], acc1[j]);
      acc1[j] = fmaf(xb[3], r3[j], acc1[j]);
    }
  }
#pragma unroll
  for (int j=0;j<4;j++){ float bv = B0v[d0+j]; acc0[j] += bv; acc1[j] += bv; }

  // store raw Y0
  {
    size_t r0 = ((size_t)g*KS + k0)*64 + d0;
    *(float4*)&g_y0[r0]      = *(float4*)acc0;
    *(float4*)&g_y0[r0 + 64] = *(float4*)acc1;
  }

  float s[4], q[4];
#pragma unroll
  for (int j=0;j<4;j++){ s[j] = acc0[j]+acc1[j]; q[j] = acc0[j]*acc0[j] + acc1[j]*acc1[j]; }
#pragma unroll
  for (int j=0;j<4;j++){
    s[j] += __shfl_down(s[j],32); s[j] += __shfl_down(s[j],16);
    q[j] += __shfl_down(q[j],32); q[j] += __shfl_down(q[j],16);
  }
  if (lane < 16){
#pragma unroll
    for (int j=0;j<4;j++){ wsum[w][lane*4+j] = s[j]; wsq[w][lane*4+j] = q[j]; }
  }
  __syncthreads();
  if (tid < 64){
    float S = wsum[0][tid]+wsum[1][tid]+wsum[2][tid]+wsum[3][tid];
    float Q = wsq[0][tid]+wsq[1][tid]+wsq[2][tid]+wsq[3][tid];
    int bucket = g & 127;
    atomicAdd(&stats[(size_t)bucket*256 + tid], (double)S);
    atomicAdd(&stats[(size_t)bucket*256 + 128 + tid], (double)Q);
  }
}

// ---------------- K_mlpB: Y0 + BN0/ReLU -> L1 -> Y1 (raw) + stats1 ----------------
__global__ __launch_bounds__(256) void k_mlpB(
    const float* __restrict__ W1, const float* __restrict__ B1v){
  double* stats = g_stats + (size_t)1*128*256;
  const int g = blockIdx.x, tid = threadIdx.x;
  __shared__ __align__(16) float xn[32][68];
  __shared__ __align__(16) float w1s[64][64];
  __shared__ float wsum[4][64], wsq[4][64];

  for (int i = tid; i < 64*64; i += 256) w1s[i>>6][i&63] = W1[i];
  {
    int k = tid >> 3, j = tid & 7;
    const float4* pr = (const float4*)(g_y0 + ((size_t)g*KS + k)*64);
    float4 v0 = pr[j*2], v1 = pr[j*2+1];
    int c0 = j*8;
    xn[k][c0+0] = fmaxf(fmaf(v0.x, g_A[c0+0], g_Bv[c0+0]), 0.f);
    xn[k][c0+1] = fmaxf(fmaf(v0.y, g_A[c0+1], g_Bv[c0+1]), 0.f);
    xn[k][c0+2] = fmaxf(fmaf(v0.z, g_A[c0+2], g_Bv[c0+2]), 0.f);
    xn[k][c0+3] = fmaxf(fmaf(v0.w, g_A[c0+3], g_Bv[c0+3]), 0.f);
    xn[k][c0+4] = fmaxf(fmaf(v1.x, g_A[c0+4], g_Bv[c0+4]), 0.f);
    xn[k][c0+5] = fmaxf(fmaf(v1.y, g_A[c0+5], g_Bv[c0+5]), 0.f);
    xn[k][c0+6] = fmaxf(fmaf(v1.z, g_A[c0+6], g_Bv[c0+6]), 0.f);
    xn[k][c0+7] = fmaxf(fmaf(v1.w, g_A[c0+7], g_Bv[c0+7]), 0.f);
  }
  __syncthreads();

  const int k0 = (tid >> 4) * 2;
  const int d0 = (tid & 15) * 4;
  const int lane = tid & 63, w = tid >> 6;

  float bc0[4] = {0.f,0.f,0.f,0.f};
  float bc1[4] = {0.f,0.f,0.f,0.f};
#pragma unroll
  for (int cq = 0; cq < 16; ++cq){
    const int c = cq*4;
    float xa[4], xb[4], r0[4], r1[4], r2[4], r3[4];
    *(float4*)xa = *(const float4*)&xn[k0][c];
    *(float4*)xb = *(const float4*)&xn[k0+1][c];
    *(float4*)r0 = *(const float4*)&w1s[c+0][d0];
    *(float4*)r1 = *(const float4*)&w1s[c+1][d0];
    *(float4*)r2 = *(const float4*)&w1s[c+2][d0];
    *(float4*)r3 = *(const float4*)&w1s[c+3][d0];
#pragma unroll
    for (int j=0;j<4;j++){
      bc0[j] = fmaf(xa[0], r0[j], bc0[j]);
      bc0[j] = fmaf(xa[1], r1[j], bc0[j]);
      bc0[j] = fmaf(xa[2], r2[j], bc0[j]);
      bc0[j] = fmaf(xa[3], r3[j], bc0[j]);
      bc1[j] = fmaf(xb[0], r0[j], bc1[j]);
      bc1[j] = fmaf(xb[1], r1[j], bc1[j]);
      bc1[j] = fmaf(xb[2], r2[j], bc1[j]);
      bc1[j] = fmaf(xb[3], r3[j], bc1[j]);
    }
  }
#pragma unroll
  for (int j=0;j<4;j++){ float bv = B1v[d0+j]; bc0[j] += bv; bc1[j] += bv; }

  {
    size_t r0 = ((size_t)g*KS + k0)*64 + d0;
    *(float4*)&g_y1[r0]      = *(float4*)bc0;
    *(float4*)&g_y1[r0 + 64] = *(float4*)bc1;
  }

  float s[4], q[4];
#pragma unroll
  for (int j=0;j<4;j++){ s[j] = bc0[j]+bc1[j]; q[j] = bc0[j]*bc0[j] + bc1[j]*bc1[j]; }
#pragma unroll
  for (int j=0;j<4;j++){
    s[j] += __shfl_down(s[j],32); s[j] += __shfl_down(s[j],16);
    q[j] += __shfl_down(q[j],32); q[j] += __shfl_down(q[j],16);
  }
  if (lane < 16){
#pragma unroll
    for (int j=0;j<4;j++){ wsum[w][lane*4+j] = s[j]; wsq[w][lane*4+j] = q[j]; }
  }
  __syncthreads();
  if (tid < 64){
    float S = wsum[0][tid]+wsum[1][tid]+wsum[2][tid]+wsum[3][tid];
    float Q = wsq[0][tid]+wsq[1][tid]+wsq[2][tid]+wsq[3][tid];
    int bucket = g & 127;
    atomicAdd(&stats[(size_t)bucket*256 + tid], (double)S);
    atomicAdd(&stats[(size_t)bucket*256 + 128 + tid], (double)Q);
  }
}

// ---------------- K_mlpC: Y1 + BN1/ReLU -> L2 -> stats2 + max/min ----------------
__global__ __launch_bounds__(256) void k_mlpC(
    const float* __restrict__ W2, const float* __restrict__ B2v){
  double* stats = g_stats + (size_t)2*128*256;
  const int g = blockIdx.x, tid = threadIdx.x;
  __shared__ __align__(16) float xt[32][68];
  __shared__ __align__(16) float w2s[64][128];
  __shared__ float wsum[4][128], wsq[4][128];
  __shared__ float wmx[4][128], wmn[4][128];

  for (int i = tid; i < 64*128; i += 256) w2s[i>>7][i&127] = W2[i];
  {
    int k = tid >> 3, j = tid & 7;
    const float4* pr = (const float4*)(g_y1 + ((size_t)g*KS + k)*64);
    float4 v0 = pr[j*2], v1 = pr[j*2+1];
    int c0 = j*8;
    xt[k][c0+0] = fmaxf(fmaf(v0.x, g_A[64+c0+0], g_Bv[64+c0+0]), 0.f);
    xt[k][c0+1] = fmaxf(fmaf(v0.y, g_A[64+c0+1], g_Bv[64+c0+1]), 0.f);
    xt[k][c0+2] = fmaxf(fmaf(v0.z, g_A[64+c0+2], g_Bv[64+c0+2]), 0.f);
    xt[k][c0+3] = fmaxf(fmaf(v0.w, g_A[64+c0+3], g_Bv[64+c0+3]), 0.f);
    xt[k][c0+4] = fmaxf(fmaf(v1.x, g_A[64+c0+4], g_Bv[64+c0+4]), 0.f);
    xt[k][c0+5] = fmaxf(fmaf(v1.y, g_A[64+c0+5], g_Bv[64+c0+5]), 0.f);
    xt[k][c0+6] = fmaxf(fmaf(v1.z, g_A[64+c0+6], g_Bv[64+c0+6]), 0.f);
    xt[k][c0+7] = fmaxf(fmaf(v1.w, g_A[64+c0+7], g_Bv[64+c0+7]), 0.f);
  }
  __syncthreads();

  const int k0 = (tid >> 4) * 2;
  const int e0 = (tid & 15) * 8;
  const int lane = tid & 63, w = tid >> 6;

  float c0a[8] = {0.f,0.f,0.f,0.f,0.f,0.f,0.f,0.f};
  float c1a[8] = {0.f,0.f,0.f,0.f,0.f,0.f,0.f,0.f};
#pragma unroll
  for (int cq = 0; cq < 16; ++cq){
    const int c = cq*4;
    float xa[4], xb[4], r0[8], r1[8], r2[8], r3[8];
    *(float4*)xa = *(const float4*)&xt[k0][c];
    *(float4*)xb = *(const float4*)&xt[k0+1][c];
    *(float4*)&r0[0] = *(const float4*)&w2s[c+0][e0]; *(float4*)&r0[4] = *(const float4*)&w2s[c+0][e0+4];
    *(float4*)&r1[0] = *(const float4*)&w2s[c+1][e0]; *(float4*)&r1[4] = *(const float4*)&w2s[c+1][e0+4];
    *(float4*)&r2[0] = *(const float4*)&w2s[c+2][e0]; *(float4*)&r2[4] = *(const float4*)&w2s[c+2][e0+4];
    *(float4*)&r3[0] = *(const float4*)&w2s[c+3][e0]; *(float4*)&r3[4] = *(const float4*)&w2s[c+3][e0+4];
#pragma unroll
    for (int j=0;j<8;j++){
      c0a[j] = fmaf(xa[0], r0[j], c0a[j]);
      c0a[j] = fmaf(xa[1], r1[j], c0a[j]);
      c0a[j] = fmaf(xa[2], r2[j], c0a[j]);
      c0a[j] = fmaf(xa[3], r3[j], c0a[j]);
      c1a[j] = fmaf(xb[0], r0[j], c1a[j]);
      c1a[j] = fmaf(xb[1], r1[j], c1a[j]);
      c1a[j] = fmaf(xb[2], r2[j], c1a[j]);
      c1a[j] = fmaf(xb[3], r3[j], c1a[j]);
    }
  }
#pragma unroll
  for (int j=0;j<8;j++){ float bv = B2v[e0+j]; c0a[j] += bv; c1a[j] += bv; }

  float s[8], q[8], mx[8], mn[8];
#pragma unroll
  for (int j=0;j<8;j++){
    s[j] = c0a[j]+c1a[j]; q[j] = c0a[j]*c0a[j] + c1a[j]*c1a[j];
    mx[j] = fmaxf(c0a[j], c1a[j]); mn[j] = fminf(c0a[j], c1a[j]);
  }
#pragma unroll
  for (int j=0;j<8;j++){
    s[j] += __shfl_down(s[j],32); s[j] += __shfl_down(s[j],16);
    q[j] += __shfl_down(q[j],32); q[j] += __shfl_down(q[j],16);
    mx[j] = fmaxf(mx[j], __shfl_xor(mx[j],16)); mx[j] = fmaxf(mx[j], __shfl_xor(mx[j],32));
    mn[j] = fminf(mn[j], __shfl_xor(mn[j],16)); mn[j] = fminf(mn[j], __shfl_xor(mn[j],32));
  }
  if (lane < 16){
#pragma unroll
    for (int j=0;j<8;j++){
      wsum[w][lane*8+j] = s[j]; wsq[w][lane*8+j] = q[j];
      wmx[w][lane*8+j] = mx[j]; wmn[w][lane*8+j] = mn[j];
    }
  }
  __syncthreads();
  if (tid < 128){
    float S = wsum[0][tid]+wsum[1][tid]+wsum[2][tid]+wsum[3][tid];
    float Q = wsq[0][tid]+wsq[1][tid]+wsq[2][tid]+wsq[3][tid];
    float MX = fmaxf(fmaxf(wmx[0][tid],wmx[1][tid]), fmaxf(wmx[2][tid],wmx[3][tid]));
    float MN = fminf(fminf(wmn[0][tid],wmn[1][tid]), fminf(wmn[2][tid],wmn[3][tid]));
    g_mmax[(size_t)g*128 + tid] = MX;
    g_mmin[(size_t)g*128 + tid] = MN;
    int bucket = g & 127;
    atomicAdd(&stats[(size_t)bucket*256 + tid], (double)S);
    atomicAdd(&stats[(size_t)bucket*256 + 128 + tid], (double)Q);
  }
}

// ---------------- K_stats ----------------
__global__ void k_stats(int stage, const float* __restrict__ gamma,
                        const float* __restrict__ beta, int aoff, int cout){
  int c = threadIdx.x;
  if (c >= cout) return;
  const double* stats = g_stats + (size_t)stage*128*256;
  double S=0.0, Q=0.0;
  for (int k=0;k<128;k++){ S += stats[(size_t)k*256 + c]; Q += stats[(size_t)k*256 + 128 + c]; }
  const double M = (double)MROWS;
  double mean = S / M;
  double var  = Q / M - mean*mean;
  double inv  = 1.0 / sqrt(var + 1e-5);
  double a    = (double)gamma[c] * inv;
  g_A[aoff+c]  = (float)a;
  g_Bv[aoff+c] = (float)((double)beta[c] - mean * a);
}

// ---------------- K_final ----------------
__global__ __launch_bounds__(256) void k_final(float* __restrict__ outp){
  int idx = blockIdx.x*256 + threadIdx.x;
  int d = idx & 127;
  float a = g_A[128+d], b = g_Bv[128+d];
  float y = (a >= 0.f) ? g_mmax[idx] : g_mmin[idx];
  float v = fmaf(y, a, b);
  outp[idx] = fmaxf(v, 0.f);
}

extern "C" void kernel_launch(void* const* d_in, const int* in_sizes, int n_in,
                              void* d_out, int out_size, void* d_ws, size_t ws_size,
                              hipStream_t stream) {
  (void)in_sizes; (void)n_in; (void)out_size; (void)d_ws; (void)ws_size;
  const float* xyz    = (const float*)d_in[0];
  const float* points = (const float*)d_in[1];
  const int*   start  = (const int*)d_in[2];
  const float* W0 = (const float*)d_in[3];  const float* b0 = (const float*)d_in[4];
  const float* g0 = (const float*)d_in[5];  const float* be0= (const float*)d_in[6];
  const float* W1 = (const float*)d_in[7];  const float* b1 = (const float*)d_in[8];
  const float* g1 = (const float*)d_in[9];  const float* be1= (const float*)d_in[10];
  const float* W2 = (const float*)d_in[11]; const float* b2 = (const float*)d_in[12];
  const float* g2 = (const float*)d_in[13]; const float* be2= (const float*)d_in[14];

  float* out_xyz = (float*)d_out;
  float* out_pts = (float*)d_out + (size_t)NBATCH*SG*3;

  k_zero <<<384, 256, 0, stream>>>();
  k_pre  <<<256, 256, 0, stream>>>(xyz);
  k_fps  <<<NBATCH, NT, 0, stream>>>(start, out_xyz);
  k_ball <<<4096, 256, 0, stream>>>();

  k_mlpA<<<NGRP, 256, 0, stream>>>(points, W0, b0);
  k_stats<<<1, 128, 0, stream>>>(0, g0, be0, 0, 64);
  k_mlpB<<<NGRP, 256, 0, stream>>>(W1, b1);
  k_stats<<<1, 128, 0, stream>>>(1, g1, be1, 64, 64);
  k_mlpC<<<NGRP, 256, 0, stream>>>(W2, b2);
  k_stats<<<1, 128, 0, stream>>>(2, g2, be2, 128, 128);
  k_final<<<8192, 256, 0, stream>>>(out_pts);
}

// Round 6
// 2703.684 us; speedup vs baseline: 1.3525x; 1.0070x over previous
//
#include <hip/hip_runtime.h>
#include <stdint.h>
#include <stddef.h>

typedef unsigned long long u64;
typedef unsigned int u32;

#define NBATCH 8
#define NPTS   8192
#define SG     2048
#define KS     32
#define NGRP   (NBATCH*SG)      // 16384
#define MROWS  (NGRP*KS)        // 524288

// ---- ALL scratch in module-static device globals: immune to ws_size ----
__device__ float4 g_p4[NBATCH*NPTS];          // 1 MiB  {x,y,z,|p|^2}
__device__ float  g_cx[NGRP], g_cy[NGRP], g_cz[NGRP];
__device__ int    g_ball[(size_t)NGRP*KS];    // 2 MiB
__device__ double g_stats[3*128*256];         // 768 KiB
__device__ float  g_A[256], g_Bv[256];        // BN scale/shift: L0 @0, L1 @64, L2 @128
__device__ float  g_mmax[(size_t)NGRP*128];   // 8 MiB
__device__ float  g_mmin[(size_t)NGRP*128];   // 8 MiB
__device__ float  g_y0[(size_t)MROWS*64];     // 134 MiB raw L0 output
__device__ float  g_y1[(size_t)MROWS*64];     // 134 MiB raw L1 output

// ---------------- K_zero ----------------
__global__ __launch_bounds__(256) void k_zero(){
  int idx = blockIdx.x*256 + threadIdx.x;
  if (idx < 3*128*256) g_stats[idx] = 0.0;
}

// ---------------- K_pre ----------------
__global__ __launch_bounds__(256) void k_pre(const float* __restrict__ xyz){
#pragma clang fp contract(off)
  int idx = blockIdx.x*256 + threadIdx.x;
  if (idx >= NBATCH*NPTS) return;
  float x = xyz[idx*3+0];
  float y = xyz[idx*3+1];
  float z = xyz[idx*3+2];
  float xx = x*x; float yy = y*y; float zz = z*z;
  float s2 = (xx + yy) + zz;
  g_p4[idx] = make_float4(x,y,z,s2);
}

// ---------------- K_fps ----------------
// Evidence trail: r3 all-reg 2634us; r4 dedup 2452us; r5 (flat wave0 reduce,
// f64-max keys, LDS point cache) 2123us. Still latency-chain-bound; the
// remaining tail (~1120cy of ~2490cy/iter) is the 6-step __shfl_xor f64
// chain (2 ds_bpermute round-trips/step, wave0-serial) + two barriers +
// kfin round-trip.
// r6: DPP-based reduce, ONE barrier.
//   * in-wave 64->1 (all 16 waves parallel): 4 DPP steps (quad_perm xor1
//     0xB1, xor2 0x4E, ROW_HALF_MIRROR 0x141, ROW_MIRROR 0x140) reduce
//     each 16-lane row entirely in the VALU (no LDS round-trip), then
//     2 __shfl_xor (16,32) finish; all lanes hold the wave max.
//   * lane0 writes 1 partial/wave -> wk16[it&1][16] (double-buffered).
//   * ONE barrier; every lane reads wk16[s][lane&15] (16 b64 = 32 banks,
//     conflict-free) + 4 DPP steps -> global max in every lane; decode
//     far; fc = pc[far] broadcast. No kfin, no wave0-only phase.
// Exactness: same 1024 unique keys; max associative+commutative; f64-bit
// ordering == u64 ordering (keys positive, NaN-free: f32 dist in high
// word keeps exp field below all-ones; unique via index field) => winner
// and centroid sequence bit-identical. wk16 dbuf: writes to buffer s in
// iter it+2 are separated from iter-it reads by two barriers => race-free
// with one barrier/iter. All 64 lanes active at every DPP/shfl step.
// Distance math unchanged bits: contract(off), (a0+a1)+a2, fminf chain;
// gi = i*1024+t keeps ascending local i == ascending gi per thread.

#define NT  1024
#define PPT 8

#define FOR8(M) M(0) M(1) M(2) M(3) M(4) M(5) M(6) M(7)

#define DECLP(i) float px##i, py##i, pz##i, dd##i;

#define LOADP(i) { float4 p_ = g_p4[base + (i)*NT + t]; \
                   px##i = p_.x; py##i = p_.y; pz##i = p_.z; dd##i = 1e10f; }

#define UPD(i) { float dx = px##i - fc.x; \
                 float dy = py##i - fc.y; \
                 float dz = pz##i - fc.z; \
                 float a0 = dx*dx; float a1 = dy*dy; float a2 = dz*dz; \
                 float d  = (a0 + a1) + a2; \
                 float nd = fminf(dd##i, d); \
                 dd##i = nd; \
                 if (nd > bv){ bv = nd; bi = (i); } }

// one DPP max step on an f64-bits key: 2 dpp movs + v_max_f64
template <int CTRL>
__device__ __forceinline__ double dpp_max_step(double v){
  u64 k  = (u64)__double_as_longlong(v);
  int lo = __builtin_amdgcn_update_dpp(0, (int)(u32)k,        CTRL, 0xf, 0xf, true);
  int hi = __builtin_amdgcn_update_dpp(0, (int)(u32)(k>>32),  CTRL, 0xf, 0xf, true);
  double nv = __longlong_as_double((long long)(((u64)(u32)hi << 32) | (u32)lo));
  return fmax(v, nv);
}

__global__ __launch_bounds__(NT, 1) void k_fps(const int* __restrict__ start, float* __restrict__ out_xyz){
  const int b = blockIdx.x;
  const int t = threadIdx.x;
  const int base = b*NPTS;
  __shared__ double wk16[2][16];               // per-wave partials, dbuf
  __shared__ __align__(16) float4 pc[NPTS];    // 128 KiB point cache

  // one-time preload of this batch's points into LDS
  for (int i = t; i < NPTS; i += NT) pc[i] = g_p4[base + i];

  FOR8(DECLP)
  FOR8(LOADP)

  int far = start[b];
  __syncthreads();                             // pc ready
  float4 fc = pc[far];
  if (t==0){
    g_cx[b*SG]=fc.x; g_cy[b*SG]=fc.y; g_cz[b*SG]=fc.z;
    size_t o = (size_t)(b*SG)*3;
    out_xyz[o+0]=fc.x; out_xyz[o+1]=fc.y; out_xyz[o+2]=fc.z;
  }
  const int lane = t & 63, w = t >> 6;   // w in 0..15
  for (int it=1; it<SG; ++it){
    float bv = -1.0f; int bi = 0;
    {
#pragma clang fp contract(off)
      FOR8(UPD)
    }
    int gi = bi*NT + t;
    u64 key = ((u64)__float_as_uint(bv) << 32) | (u32)(NPTS-1 - gi);
    double kv = __longlong_as_double((long long)key);
    // in-wave 64 -> 1 (all lanes end with the wave max)
    kv = dpp_max_step<0xB1>(kv);    // quad_perm [1,0,3,2]  (xor1)
    kv = dpp_max_step<0x4E>(kv);    // quad_perm [2,3,0,1]  (xor2)
    kv = dpp_max_step<0x141>(kv);   // ROW_HALF_MIRROR      (8-group)
    kv = dpp_max_step<0x140>(kv);   // ROW_MIRROR           (16-group)
    { double o2 = __shfl_xor(kv, 16); kv = fmax(kv, o2); }
    { double o2 = __shfl_xor(kv, 32); kv = fmax(kv, o2); }
    const int s = it & 1;
    if (lane == 0) wk16[s][w] = kv;
    __syncthreads();
    // every lane: read one of the 16 partials (32 banks, conflict-free),
    // then 4 DPP steps reduce the 16 within each row -> global max
    double km = wk16[s][lane & 15];
    km = dpp_max_step<0xB1>(km);
    km = dpp_max_step<0x4E>(km);
    km = dpp_max_step<0x141>(km);
    km = dpp_max_step<0x140>(km);
    u64 kmu = (u64)__double_as_longlong(km);
    far = NPTS-1 - (int)(kmu & 0xffffffffu);
    fc = pc[far];
    if (t==0){
      g_cx[b*SG+it]=fc.x; g_cy[b*SG+it]=fc.y; g_cz[b*SG+it]=fc.z;
      size_t o = (size_t)(b*SG+it)*3;
      out_xyz[o+0]=fc.x; out_xyz[o+1]=fc.y; out_xyz[o+2]=fc.z;
    }
  }
}

// ---------------- K_ball: expansion form, FMA-ascending dot (PASSED r7, do not touch) ----------------
__global__ __launch_bounds__(256) void k_ball(){
  const int g = blockIdx.x*4 + (threadIdx.x>>6);
  const int lane = threadIdx.x & 63;
  const int b = g >> 11;
  const float4* pb4 = g_p4 + b*NPTS;
  float cxv = g_cx[g], cyv = g_cy[g], czv = g_cz[g];
  float s1;
  {
#pragma clang fp contract(off)
    float a = cxv*cxv; float bb = cyv*cyv; float cc = czv*czv;
    s1 = (a + bb) + cc;
  }
  const float R2 = 0.04f;
  int filled = 0, firstn = -1;
  for (int n0=0; n0<NPTS && filled<KS; n0+=64){
    float4 p = pb4[n0+lane];
    float sq;
    {
#pragma clang fp contract(off)
      float dt = cxv*p.x;
      dt = fmaf(cyv, p.y, dt);
      dt = fmaf(czv, p.z, dt);
      float ss = s1 + p.w;
      sq = ss - 2.0f*dt;
    }
    bool mem = !(sq > R2);
    u64 mk = __ballot(mem);
    if (firstn < 0 && mk) firstn = n0 + (__ffsll((unsigned long long)mk) - 1);
    int pos = filled + (int)__popcll(mk & ((1ull<<lane)-1ull));
    if (mem && pos < KS) g_ball[(size_t)g*KS + pos] = n0 + lane;
    filled += (int)__popcll(mk);
  }
  for (int s = filled + lane; s < KS; s += 64) g_ball[(size_t)g*KS+s] = firstn;
}

// ---------------- K_mlpA: gather + L0 -> Y0 (raw f32) + stats0 ----------------
__global__ __launch_bounds__(256) void k_mlpA(
    const float* __restrict__ points,
    const float* __restrict__ W0, const float* __restrict__ B0v){
  double* stats = g_stats;
  const int g = blockIdx.x, tid = threadIdx.x;
  const int b = g >> 11;
  __shared__ __align__(16) float xt[32][68];
  __shared__ __align__(16) float w0s[68][64];
  __shared__ float wsum[4][64], wsq[4][64];

  for (int i = tid; i < 67*64; i += 256) w0s[i>>6][i&63] = W0[i];
  if (tid < 64) w0s[67][tid] = 0.f;

  if (tid < 32){
    int n = g_ball[(size_t)g*KS + tid];
    float4 p = g_p4[b*NPTS + n];
    xt[tid][0] = p.x - g_cx[g];
    xt[tid][1] = p.y - g_cy[g];
    xt[tid][2] = p.z - g_cz[g];
    xt[tid][67] = 0.f;
  }
  {
    int k = tid >> 3, j = tid & 7;
    int n = g_ball[(size_t)g*KS + k];
    const float4* pr = (const float4*)(points + ((size_t)(b*NPTS + n))*64);
    float4 v0 = pr[j*2], v1 = pr[j*2+1];
    int c0 = 3 + j*8;
    xt[k][c0+0]=v0.x; xt[k][c0+1]=v0.y; xt[k][c0+2]=v0.z; xt[k][c0+3]=v0.w;
    xt[k][c0+4]=v1.x; xt[k][c0+5]=v1.y; xt[k][c0+6]=v1.z; xt[k][c0+7]=v1.w;
  }
  __syncthreads();

  const int k0 = (tid >> 4) * 2;
  const int d0 = (tid & 15) * 4;
  const int lane = tid & 63, w = tid >> 6;

  float acc0[4] = {0.f,0.f,0.f,0.f};
  float acc1[4] = {0.f,0.f,0.f,0.f};
#pragma unroll
  for (int cq = 0; cq < 17; ++cq){
    const int c = cq*4;
    float xa[4], xb[4], r0[4], r1[4], r2[4], r3[4];
    *(float4*)xa = *(const float4*)&xt[k0][c];
    *(float4*)xb = *(const float4*)&xt[k0+1][c];
    *(float4*)r0 = *(const float4*)&w0s[c+0][d0];
    *(float4*)r1 = *(const float4*)&w0s[c+1][d0];
    *(float4*)r2 = *(const float4*)&w0s[c+2][d0];
    *(float4*)r3 = *(const float4*)&w0s[c+3][d0];
#pragma unroll
    for (int j=0;j<4;j++){
      acc0[j] = fmaf(xa[0], r0[j], acc0[j]);
      acc0[j] = fmaf(xa[1], r1[j], acc0[j]);
      acc0[j] = fmaf(xa[2], r2[j], acc0[j]);
      acc0[j] = fmaf(xa[3], r3[j], acc0[j]);
      acc1[j] = fmaf(xb[0], r0[j], acc1[j]);
      acc1[j] = fmaf(xb[1], r1[j], acc1[j]);
      acc1[j] = fmaf(xb[2], r2[j], acc1[j]);
      acc1[j] = fmaf(xb[3], r3[j], acc1[j]);
    }
  }
#pragma unroll
  for (int j=0;j<4;j++){ float bv = B0v[d0+j]; acc0[j] += bv; acc1[j] += bv; }

  // store raw Y0
  {
    size_t r0 = ((size_t)g*KS + k0)*64 + d0;
    *(float4*)&g_y0[r0]      = *(float4*)acc0;
    *(float4*)&g_y0[r0 + 64] = *(float4*)acc1;
  }

  float s[4], q[4];
#pragma unroll
  for (int j=0;j<4;j++){ s[j] = acc0[j]+acc1[j]; q[j] = acc0[j]*acc0[j] + acc1[j]*acc1[j]; }
#pragma unroll
  for (int j=0;j<4;j++){
    s[j] += __shfl_down(s[j],32); s[j] += __shfl_down(s[j],16);
    q[j] += __shfl_down(q[j],32); q[j] += __shfl_down(q[j],16);
  }
  if (lane < 16){
#pragma unroll
    for (int j=0;j<4;j++){ wsum[w][lane*4+j] = s[j]; wsq[w][lane*4+j] = q[j]; }
  }
  __syncthreads();
  if (tid < 64){
    float S = wsum[0][tid]+wsum[1][tid]+wsum[2][tid]+wsum[3][tid];
    float Q = wsq[0][tid]+wsq[1][tid]+wsq[2][tid]+wsq[3][tid];
    int bucket = g & 127;
    atomicAdd(&stats[(size_t)bucket*256 + tid], (double)S);
    atomicAdd(&stats[(size_t)bucket*256 + 128 + tid], (double)Q);
  }
}

// ---------------- K_mlpB: Y0 + BN0/ReLU -> L1 -> Y1 (raw) + stats1 ----------------
__global__ __launch_bounds__(256) void k_mlpB(
    const float* __restrict__ W1, const float* __restrict__ B1v){
  double* stats = g_stats + (size_t)1*128*256;
  const int g = blockIdx.x, tid = threadIdx.x;
  __shared__ __align__(16) float xn[32][68];
  __shared__ __align__(16) float w1s[64][64];
  __shared__ float wsum[4][64], wsq[4][64];

  for (int i = tid; i < 64*64; i += 256) w1s[i>>6][i&63] = W1[i];
  {
    int k = tid >> 3, j = tid & 7;
    const float4* pr = (const float4*)(g_y0 + ((size_t)g*KS + k)*64);
    float4 v0 = pr[j*2], v1 = pr[j*2+1];
    int c0 = j*8;
    xn[k][c0+0] = fmaxf(fmaf(v0.x, g_A[c0+0], g_Bv[c0+0]), 0.f);
    xn[k][c0+1] = fmaxf(fmaf(v0.y, g_A[c0+1], g_Bv[c0+1]), 0.f);
    xn[k][c0+2] = fmaxf(fmaf(v0.z, g_A[c0+2], g_Bv[c0+2]), 0.f);
    xn[k][c0+3] = fmaxf(fmaf(v0.w, g_A[c0+3], g_Bv[c0+3]), 0.f);
    xn[k][c0+4] = fmaxf(fmaf(v1.x, g_A[c0+4], g_Bv[c0+4]), 0.f);
    xn[k][c0+5] = fmaxf(fmaf(v1.y, g_A[c0+5], g_Bv[c0+5]), 0.f);
    xn[k][c0+6] = fmaxf(fmaf(v1.z, g_A[c0+6], g_Bv[c0+6]), 0.f);
    xn[k][c0+7] = fmaxf(fmaf(v1.w, g_A[c0+7], g_Bv[c0+7]), 0.f);
  }
  __syncthreads();

  const int k0 = (tid >> 4) * 2;
  const int d0 = (tid & 15) * 4;
  const int lane = tid & 63, w = tid >> 6;

  float bc0[4] = {0.f,0.f,0.f,0.f};
  float bc1[4] = {0.f,0.f,0.f,0.f};
#pragma unroll
  for (int cq = 0; cq < 16; ++cq){
    const int c = cq*4;
    float xa[4], xb[4], r0[4], r1[4], r2[4], r3[4];
    *(float4*)xa = *(const float4*)&xn[k0][c];
    *(float4*)xb = *(const float4*)&xn[k0+1][c];
    *(float4*)r0 = *(const float4*)&w1s[c+0][d0];
    *(float4*)r1 = *(const float4*)&w1s[c+1][d0];
    *(float4*)r2 = *(const float4*)&w1s[c+2][d0];
    *(float4*)r3 = *(const float4*)&w1s[c+3][d0];
#pragma unroll
    for (int j=0;j<4;j++){
      bc0[j] = fmaf(xa[0], r0[j], bc0[j]);
      bc0[j] = fmaf(xa[1], r1[j], bc0[j]);
      bc0[j] = fmaf(xa[2], r2[j], bc0[j]);
      bc0[j] = fmaf(xa[3], r3[j], bc0[j]);
      bc1[j] = fmaf(xb[0], r0[j], bc1[j]);
      bc1[j] = fmaf(xb[1], r1[j], bc1[j]);
      bc1[j] = fmaf(xb[2], r2[j], bc1[j]);
      bc1[j] = fmaf(xb[3], r3[j], bc1[j]);
    }
  }
#pragma unroll
  for (int j=0;j<4;j++){ float bv = B1v[d0+j]; bc0[j] += bv; bc1[j] += bv; }

  {
    size_t r0 = ((size_t)g*KS + k0)*64 + d0;
    *(float4*)&g_y1[r0]      = *(float4*)bc0;
    *(float4*)&g_y1[r0 + 64] = *(float4*)bc1;
  }

  float s[4], q[4];
#pragma unroll
  for (int j=0;j<4;j++){ s[j] = bc0[j]+bc1[j]; q[j] = bc0[j]*bc0[j] + bc1[j]*bc1[j]; }
#pragma unroll
  for (int j=0;j<4;j++){
    s[j] += __shfl_down(s[j],32); s[j] += __shfl_down(s[j],16);
    q[j] += __shfl_down(q[j],32); q[j] += __shfl_down(q[j],16);
  }
  if (lane < 16){
#pragma unroll
    for (int j=0;j<4;j++){ wsum[w][lane*4+j] = s[j]; wsq[w][lane*4+j] = q[j]; }
  }
  __syncthreads();
  if (tid < 64){
    float S = wsum[0][tid]+wsum[1][tid]+wsum[2][tid]+wsum[3][tid];
    float Q = wsq[0][tid]+wsq[1][tid]+wsq[2][tid]+wsq[3][tid];
    int bucket = g & 127;
    atomicAdd(&stats[(size_t)bucket*256 + tid], (double)S);
    atomicAdd(&stats[(size_t)bucket*256 + 128 + tid], (double)Q);
  }
}

// ---------------- K_mlpC: Y1 + BN1/ReLU -> L2 -> stats2 + max/min ----------------
__global__ __launch_bounds__(256) void k_mlpC(
    const float* __restrict__ W2, const float* __restrict__ B2v){
  double* stats = g_stats + (size_t)2*128*256;
  const int g = blockIdx.x, tid = threadIdx.x;
  __shared__ __align__(16) float xt[32][68];
  __shared__ __align__(16) float w2s[64][128];
  __shared__ float wsum[4][128], wsq[4][128];
  __shared__ float wmx[4][128], wmn[4][128];

  for (int i = tid; i < 64*128; i += 256) w2s[i>>7][i&127] = W2[i];
  {
    int k = tid >> 3, j = tid & 7;
    const float4* pr = (const float4*)(g_y1 + ((size_t)g*KS + k)*64);
    float4 v0 = pr[j*2], v1 = pr[j*2+1];
    int c0 = j*8;
    xt[k][c0+0] = fmaxf(fmaf(v0.x, g_A[64+c0+0], g_Bv[64+c0+0]), 0.f);
    xt[k][c0+1] = fmaxf(fmaf(v0.y, g_A[64+c0+1], g_Bv[64+c0+1]), 0.f);
    xt[k][c0+2] = fmaxf(fmaf(v0.z, g_A[64+c0+2], g_Bv[64+c0+2]), 0.f);
    xt[k][c0+3] = fmaxf(fmaf(v0.w, g_A[64+c0+3], g_Bv[64+c0+3]), 0.f);
    xt[k][c0+4] = fmaxf(fmaf(v1.x, g_A[64+c0+4], g_Bv[64+c0+4]), 0.f);
    xt[k][c0+5] = fmaxf(fmaf(v1.y, g_A[64+c0+5], g_Bv[64+c0+5]), 0.f);
    xt[k][c0+6] = fmaxf(fmaf(v1.z, g_A[64+c0+6], g_Bv[64+c0+6]), 0.f);
    xt[k][c0+7] = fmaxf(fmaf(v1.w, g_A[64+c0+7], g_Bv[64+c0+7]), 0.f);
  }
  __syncthreads();

  const int k0 = (tid >> 4) * 2;
  const int e0 = (tid & 15) * 8;
  const int lane = tid & 63, w = tid >> 6;

  float c0a[8] = {0.f,0.f,0.f,0.f,0.f,0.f,0.f,0.f};
  float c1a[8] = {0.f,0.f,0.f,0.f,0.f,0.f,0.f,0.f};
#pragma unroll
  for (int cq = 0; cq < 16; ++cq){
    const int c = cq*4;
    float xa[4], xb[4], r0[8], r1[8], r2[8], r3[8];
    *(float4*)xa = *(const float4*)&xt[k0][c];
    *(float4*)xb = *(const float4*)&xt[k0+1][c];
    *(float4*)&r0[0] = *(const float4*)&w2s[c+0][e0]; *(float4*)&r0[4] = *(const float4*)&w2s[c+0][e0+4];
    *(float4*)&r1[0] = *(const float4*)&w2s[c+1][e0]; *(float4*)&r1[4] = *(const float4*)&w2s[c+1][e0+4];
    *(float4*)&r2[0] = *(const float4*)&w2s[c+2][e0]; *(float4*)&r2[4] = *(const float4*)&w2s[c+2][e0+4];
    *(float4*)&r3[0] = *(const float4*)&w2s[c+3][e0]; *(float4*)&r3[4] = *(const float4*)&w2s[c+3][e0+4];
#pragma unroll
    for (int j=0;j<8;j++){
      c0a[j] = fmaf(xa[0], r0[j], c0a[j]);
      c0a[j] = fmaf(xa[1], r1[j], c0a[j]);
      c0a[j] = fmaf(xa[2], r2[j], c0a[j]);
      c0a[j] = fmaf(xa[3], r3[j], c0a[j]);
      c1a[j] = fmaf(xb[0], r0[j], c1a[j]);
      c1a[j] = fmaf(xb[1], r1[j], c1a[j]);
      c1a[j] = fmaf(xb[2], r2[j], c1a[j]);
      c1a[j] = fmaf(xb[3], r3[j], c1a[j]);
    }
  }
#pragma unroll
  for (int j=0;j<8;j++){ float bv = B2v[e0+j]; c0a[j] += bv; c1a[j] += bv; }

  float s[8], q[8], mx[8], mn[8];
#pragma unroll
  for (int j=0;j<8;j++){
    s[j] = c0a[j]+c1a[j]; q[j] = c0a[j]*c0a[j] + c1a[j]*c1a[j];
    mx[j] = fmaxf(c0a[j], c1a[j]); mn[j] = fminf(c0a[j], c1a[j]);
  }
#pragma unroll
  for (int j=0;j<8;j++){
    s[j] += __shfl_down(s[j],32); s[j] += __shfl_down(s[j],16);
    q[j] += __shfl_down(q[j],32); q[j] += __shfl_down(q[j],16);
    mx[j] = fmaxf(mx[j], __shfl_xor(mx[j],16)); mx[j] = fmaxf(mx[j], __shfl_xor(mx[j],32));
    mn[j] = fminf(mn[j], __shfl_xor(mn[j],16)); mn[j] = fminf(mn[j], __shfl_xor(mn[j],32));
  }
  if (lane < 16){
#pragma unroll
    for (int j=0;j<8;j++){
      wsum[w][lane*8+j] = s[j]; wsq[w][lane*8+j] = q[j];
      wmx[w][lane*8+j] = mx[j]; wmn[w][lane*8+j] = mn[j];
    }
  }
  __syncthreads();
  if (tid < 128){
    float S = wsum[0][tid]+wsum[1][tid]+wsum[2][tid]+wsum[3][tid];
    float Q = wsq[0][tid]+wsq[1][tid]+wsq[2][tid]+wsq[3][tid];
    float MX = fmaxf(fmaxf(wmx[0][tid],wmx[1][tid]), fmaxf(wmx[2][tid],wmx[3][tid]));
    float MN = fminf(fminf(wmn[0][tid],wmn[1][tid]), fminf(wmn[2][tid],wmn[3][tid]));
    g_mmax[(size_t)g*128 + tid] = MX;
    g_mmin[(size_t)g*128 + tid] = MN;
    int bucket = g & 127;
    atomicAdd(&stats[(size_t)bucket*256 + tid], (double)S);
    atomicAdd(&stats[(size_t)bucket*256 + 128 + tid], (double)Q);
  }
}

// ---------------- K_stats ----------------
__global__ void k_stats(int stage, const float* __restrict__ gamma,
                        const float* __restrict__ beta, int aoff, int cout){
  int c = threadIdx.x;
  if (c >= cout) return;
  const double* stats = g_stats + (size_t)stage*128*256;
  double S=0.0, Q=0.0;
  for (int k=0;k<128;k++){ S += stats[(size_t)k*256 + c]; Q += stats[(size_t)k*256 + 128 + c]; }
  const double M = (double)MROWS;
  double mean = S / M;
  double var  = Q / M - mean*mean;
  double inv  = 1.0 / sqrt(var + 1e-5);
  double a    = (double)gamma[c] * inv;
  g_A[aoff+c]  = (float)a;
  g_Bv[aoff+c] = (float)((double)beta[c] - mean * a);
}

// ---------------- K_final ----------------
__global__ __launch_bounds__(256) void k_final(float* __restrict__ outp){
  int idx = blockIdx.x*256 + threadIdx.x;
  int d = idx & 127;
  float a = g_A[128+d], b = g_Bv[128+d];
  float y = (a >= 0.f) ? g_mmax[idx] : g_mmin[idx];
  float v = fmaf(y, a, b);
  outp[idx] = fmaxf(v, 0.f);
}

extern "C" void kernel_launch(void* const* d_in, const int* in_sizes, int n_in,
                              void* d_out, int out_size, void* d_ws, size_t ws_size,
                              hipStream_t stream) {
  (void)in_sizes; (void)n_in; (void)out_size; (void)d_ws; (void)ws_size;
  const float* xyz    = (const float*)d_in[0];
  const float* points = (const float*)d_in[1];
  const int*   start  = (const int*)d_in[2];
  const float* W0 = (const float*)d_in[3];  const float* b0 = (const float*)d_in[4];
  const float* g0 = (const float*)d_in[5];  const float* be0= (const float*)d_in[6];
  const float* W1 = (const float*)d_in[7];  const float* b1 = (const float*)d_in[8];
  const float* g1 = (const float*)d_in[9];  const float* be1= (const float*)d_in[10];
  const float* W2 = (const float*)d_in[11]; const float* b2 = (const float*)d_in[12];
  const float* g2 = (const float*)d_in[13]; const float* be2= (const float*)d_in[14];

  float* out_xyz = (float*)d_out;
  float* out_pts = (float*)d_out + (size_t)NBATCH*SG*3;

  k_zero <<<384, 256, 0, stream>>>();
  k_pre  <<<256, 256, 0, stream>>>(xyz);
  k_fps  <<<NBATCH, NT, 0, stream>>>(start, out_xyz);
  k_ball <<<4096, 256, 0, stream>>>();

  k_mlpA<<<NGRP, 256, 0, stream>>>(points, W0, b0);
  k_stats<<<1, 128, 0, stream>>>(0, g0, be0, 0, 64);
  k_mlpB<<<NGRP, 256, 0, stream>>>(W1, b1);
  k_stats<<<1, 128, 0, stream>>>(1, g1, be1, 64, 64);
  k_mlpC<<<NGRP, 256, 0, stream>>>(W2, b2);
  k_stats<<<1, 128, 0, stream>>>(2, g2, be2, 128, 128);
  k_final<<<8192, 256, 0, stream>>>(out_pts);
}

// Round 7
// 2695.152 us; speedup vs baseline: 1.3567x; 1.0032x over previous
//
#include <hip/hip_runtime.h>
#include <stdint.h>
#include <stddef.h>

typedef unsigned long long u64;
typedef unsigned int u32;

#define NBATCH 8
#define NPTS   8192
#define SG     2048
#define KS     32
#define NGRP   (NBATCH*SG)      // 16384
#define MROWS  (NGRP*KS)        // 524288

// ---- ALL scratch in module-static device globals: immune to ws_size ----
__device__ float4 g_p4[NBATCH*NPTS];          // 1 MiB  {x,y,z,|p|^2}
__device__ float  g_cx[NGRP], g_cy[NGRP], g_cz[NGRP];
__device__ int    g_ball[(size_t)NGRP*KS];    // 2 MiB
__device__ double g_stats[3*128*256];         // 768 KiB
__device__ float  g_A[256], g_Bv[256];        // BN scale/shift: L0 @0, L1 @64, L2 @128
__device__ float  g_mmax[(size_t)NGRP*128];   // 8 MiB
__device__ float  g_mmin[(size_t)NGRP*128];   // 8 MiB
__device__ float  g_y0[(size_t)MROWS*64];     // 134 MiB raw L0 output
__device__ float  g_y1[(size_t)MROWS*64];     // 134 MiB raw L1 output

// ---------------- K_zero ----------------
__global__ __launch_bounds__(256) void k_zero(){
  int idx = blockIdx.x*256 + threadIdx.x;
  if (idx < 3*128*256) g_stats[idx] = 0.0;
}

// ---------------- K_pre ----------------
__global__ __launch_bounds__(256) void k_pre(const float* __restrict__ xyz){
#pragma clang fp contract(off)
  int idx = blockIdx.x*256 + threadIdx.x;
  if (idx >= NBATCH*NPTS) return;
  float x = xyz[idx*3+0];
  float y = xyz[idx*3+1];
  float z = xyz[idx*3+2];
  float xx = x*x; float yy = y*y; float zz = z*z;
  float s2 = (xx + yy) + zz;
  g_p4[idx] = make_float4(x,y,z,s2);
}

// ---------------- K_fps ----------------
// Evidence trail: r4 2452us -> r5 (flat reduce, f64 keys, LDS pc) 2123us ->
// r6 (DPP reduce, 1 barrier) 2107us with VALUBusy UP (1.93->2.69 => ~86%
// on active CUs). r6's null result falsified the shuffle-chain theory.
// Chain audit gap (~900cy/iter) pinpoints the in-loop t==0 GLOBAL stores:
// __syncthreads() == s_waitcnt vmcnt(0) lgkmcnt(0); s_barrier, so wave 0
// must drain 6 global_store_dword to L2/HBM (~300-800cy write-ack) before
// EVERY barrier, stalling all 16 waves, every iteration.
// r7 FIX: zero global stores in the loop.
//   * in-loop: t==0 writes only the winning index to LDS fars[it]
//     (ds_write -> lgkmcnt, absorbed by next barrier's drain).
//   * epilogue after the loop (one barrier): parallel pass writes
//     g_cx/g_cy/g_cz + out_xyz for all 2048 centroids from fars + pc.
//     Same values, written once; consumers (k_ball/k_mlpA) only run after
//     kernel end. LDS: 128K pc + 8K fars + 256B partials ~= 139.5K.
// Everything else byte-identical to r6 (UPD math frozen; DPP/f64 reduce
// proven exact in r6: keys positive NaN-free unique f64 bit patterns,
// max associative => winner bit-identical; wk16 dbuf race-free).

#define NT  1024
#define PPT 8

#define FOR8(M) M(0) M(1) M(2) M(3) M(4) M(5) M(6) M(7)

#define DECLP(i) float px##i, py##i, pz##i, dd##i;

#define LOADP(i) { float4 p_ = g_p4[base + (i)*NT + t]; \
                   px##i = p_.x; py##i = p_.y; pz##i = p_.z; dd##i = 1e10f; }

#define UPD(i) { float dx = px##i - fc.x; \
                 float dy = py##i - fc.y; \
                 float dz = pz##i - fc.z; \
                 float a0 = dx*dx; float a1 = dy*dy; float a2 = dz*dz; \
                 float d  = (a0 + a1) + a2; \
                 float nd = fminf(dd##i, d); \
                 dd##i = nd; \
                 if (nd > bv){ bv = nd; bi = (i); } }

// one DPP max step on an f64-bits key: 2 dpp movs + v_max_f64
template <int CTRL>
__device__ __forceinline__ double dpp_max_step(double v){
  u64 k  = (u64)__double_as_longlong(v);
  int lo = __builtin_amdgcn_update_dpp(0, (int)(u32)k,        CTRL, 0xf, 0xf, true);
  int hi = __builtin_amdgcn_update_dpp(0, (int)(u32)(k>>32),  CTRL, 0xf, 0xf, true);
  double nv = __longlong_as_double((long long)(((u64)(u32)hi << 32) | (u32)lo));
  return fmax(v, nv);
}

__global__ __launch_bounds__(NT, 1) void k_fps(const int* __restrict__ start, float* __restrict__ out_xyz){
  const int b = blockIdx.x;
  const int t = threadIdx.x;
  const int base = b*NPTS;
  __shared__ double wk16[2][16];               // per-wave partials, dbuf
  __shared__ int    fars[SG];                  // 8 KiB winning indices
  __shared__ __align__(16) float4 pc[NPTS];    // 128 KiB point cache

  // one-time preload of this batch's points into LDS
  for (int i = t; i < NPTS; i += NT) pc[i] = g_p4[base + i];

  FOR8(DECLP)
  FOR8(LOADP)

  int far = start[b];
  __syncthreads();                             // pc ready
  float4 fc = pc[far];
  if (t==0) fars[0] = far;
  const int lane = t & 63, w = t >> 6;   // w in 0..15
  for (int it=1; it<SG; ++it){
    float bv = -1.0f; int bi = 0;
    {
#pragma clang fp contract(off)
      FOR8(UPD)
    }
    int gi = bi*NT + t;
    u64 key = ((u64)__float_as_uint(bv) << 32) | (u32)(NPTS-1 - gi);
    double kv = __longlong_as_double((long long)key);
    // in-wave 64 -> 1 (all lanes end with the wave max)
    kv = dpp_max_step<0xB1>(kv);    // quad_perm [1,0,3,2]  (xor1)
    kv = dpp_max_step<0x4E>(kv);    // quad_perm [2,3,0,1]  (xor2)
    kv = dpp_max_step<0x141>(kv);   // ROW_HALF_MIRROR      (8-group)
    kv = dpp_max_step<0x140>(kv);   // ROW_MIRROR           (16-group)
    { double o2 = __shfl_xor(kv, 16); kv = fmax(kv, o2); }
    { double o2 = __shfl_xor(kv, 32); kv = fmax(kv, o2); }
    const int s = it & 1;
    if (lane == 0) wk16[s][w] = kv;
    __syncthreads();
    // every lane: read one of the 16 partials (32 banks, conflict-free),
    // then 4 DPP steps reduce the 16 within each row -> global max
    double km = wk16[s][lane & 15];
    km = dpp_max_step<0xB1>(km);
    km = dpp_max_step<0x4E>(km);
    km = dpp_max_step<0x141>(km);
    km = dpp_max_step<0x140>(km);
    u64 kmu = (u64)__double_as_longlong(km);
    far = NPTS-1 - (int)(kmu & 0xffffffffu);
    fc = pc[far];
    if (t==0) fars[it] = far;                  // LDS only — no vmem in loop
  }
  __syncthreads();                             // fars complete
  // epilogue: write all centroids once (same values, same locations)
  for (int it = t; it < SG; it += NT){
    int f = fars[it];
    float4 p = pc[f];
    int gidx = b*SG + it;
    g_cx[gidx] = p.x; g_cy[gidx] = p.y; g_cz[gidx] = p.z;
    size_t o = (size_t)gidx*3;
    out_xyz[o+0]=p.x; out_xyz[o+1]=p.y; out_xyz[o+2]=p.z;
  }
}

// ---------------- K_ball: expansion form, FMA-ascending dot (PASSED r7, do not touch) ----------------
__global__ __launch_bounds__(256) void k_ball(){
  const int g = blockIdx.x*4 + (threadIdx.x>>6);
  const int lane = threadIdx.x & 63;
  const int b = g >> 11;
  const float4* pb4 = g_p4 + b*NPTS;
  float cxv = g_cx[g], cyv = g_cy[g], czv = g_cz[g];
  float s1;
  {
#pragma clang fp contract(off)
    float a = cxv*cxv; float bb = cyv*cyv; float cc = czv*czv;
    s1 = (a + bb) + cc;
  }
  const float R2 = 0.04f;
  int filled = 0, firstn = -1;
  for (int n0=0; n0<NPTS && filled<KS; n0+=64){
    float4 p = pb4[n0+lane];
    float sq;
    {
#pragma clang fp contract(off)
      float dt = cxv*p.x;
      dt = fmaf(cyv, p.y, dt);
      dt = fmaf(czv, p.z, dt);
      float ss = s1 + p.w;
      sq = ss - 2.0f*dt;
    }
    bool mem = !(sq > R2);
    u64 mk = __ballot(mem);
    if (firstn < 0 && mk) firstn = n0 + (__ffsll((unsigned long long)mk) - 1);
    int pos = filled + (int)__popcll(mk & ((1ull<<lane)-1ull));
    if (mem && pos < KS) g_ball[(size_t)g*KS + pos] = n0 + lane;
    filled += (int)__popcll(mk);
  }
  for (int s = filled + lane; s < KS; s += 64) g_ball[(size_t)g*KS+s] = firstn;
}

// ---------------- K_mlpA: gather + L0 -> Y0 (raw f32) + stats0 ----------------
__global__ __launch_bounds__(256) void k_mlpA(
    const float* __restrict__ points,
    const float* __restrict__ W0, const float* __restrict__ B0v){
  double* stats = g_stats;
  const int g = blockIdx.x, tid = threadIdx.x;
  const int b = g >> 11;
  __shared__ __align__(16) float xt[32][68];
  __shared__ __align__(16) float w0s[68][64];
  __shared__ float wsum[4][64], wsq[4][64];

  for (int i = tid; i < 67*64; i += 256) w0s[i>>6][i&63] = W0[i];
  if (tid < 64) w0s[67][tid] = 0.f;

  if (tid < 32){
    int n = g_ball[(size_t)g*KS + tid];
    float4 p = g_p4[b*NPTS + n];
    xt[tid][0] = p.x - g_cx[g];
    xt[tid][1] = p.y - g_cy[g];
    xt[tid][2] = p.z - g_cz[g];
    xt[tid][67] = 0.f;
  }
  {
    int k = tid >> 3, j = tid & 7;
    int n = g_ball[(size_t)g*KS + k];
    const float4* pr = (const float4*)(points + ((size_t)(b*NPTS + n))*64);
    float4 v0 = pr[j*2], v1 = pr[j*2+1];
    int c0 = 3 + j*8;
    xt[k][c0+0]=v0.x; xt[k][c0+1]=v0.y; xt[k][c0+2]=v0.z; xt[k][c0+3]=v0.w;
    xt[k][c0+4]=v1.x; xt[k][c0+5]=v1.y; xt[k][c0+6]=v1.z; xt[k][c0+7]=v1.w;
  }
  __syncthreads();

  const int k0 = (tid >> 4) * 2;
  const int d0 = (tid & 15) * 4;
  const int lane = tid & 63, w = tid >> 6;

  float acc0[4] = {0.f,0.f,0.f,0.f};
  float acc1[4] = {0.f,0.f,0.f,0.f};
#pragma unroll
  for (int cq = 0; cq < 17; ++cq){
    const int c = cq*4;
    float xa[4], xb[4], r0[4], r1[4], r2[4], r3[4];
    *(float4*)xa = *(const float4*)&xt[k0][c];
    *(float4*)xb = *(const float4*)&xt[k0+1][c];
    *(float4*)r0 = *(const float4*)&w0s[c+0][d0];
    *(float4*)r1 = *(const float4*)&w0s[c+1][d0];
    *(float4*)r2 = *(const float4*)&w0s[c+2][d0];
    *(float4*)r3 = *(const float4*)&w0s[c+3][d0];
#pragma unroll
    for (int j=0;j<4;j++){
      acc0[j] = fmaf(xa[0], r0[j], acc0[j]);
      acc0[j] = fmaf(xa[1], r1[j], acc0[j]);
      acc0[j] = fmaf(xa[2], r2[j], acc0[j]);
      acc0[j] = fmaf(xa[3], r3[j], acc0[j]);
      acc1[j] = fmaf(xb[0], r0[j], acc1[j]);
      acc1[j] = fmaf(xb[1], r1[j], acc1[j]);
      acc1[j] = fmaf(xb[2], r2[j], acc1[j]);
      acc1[j] = fmaf(xb[3], r3[j], acc1[j]);
    }
  }
#pragma unroll
  for (int j=0;j<4;j++){ float bv = B0v[d0+j]; acc0[j] += bv; acc1[j] += bv; }

  // store raw Y0
  {
    size_t r0 = ((size_t)g*KS + k0)*64 + d0;
    *(float4*)&g_y0[r0]      = *(float4*)acc0;
    *(float4*)&g_y0[r0 + 64] = *(float4*)acc1;
  }

  float s[4], q[4];
#pragma unroll
  for (int j=0;j<4;j++){ s[j] = acc0[j]+acc1[j]; q[j] = acc0[j]*acc0[j] + acc1[j]*acc1[j]; }
#pragma unroll
  for (int j=0;j<4;j++){
    s[j] += __shfl_down(s[j],32); s[j] += __shfl_down(s[j],16);
    q[j] += __shfl_down(q[j],32); q[j] += __shfl_down(q[j],16);
  }
  if (lane < 16){
#pragma unroll
    for (int j=0;j<4;j++){ wsum[w][lane*4+j] = s[j]; wsq[w][lane*4+j] = q[j]; }
  }
  __syncthreads();
  if (tid < 64){
    float S = wsum[0][tid]+wsum[1][tid]+wsum[2][tid]+wsum[3][tid];
    float Q = wsq[0][tid]+wsq[1][tid]+wsq[2][tid]+wsq[3][tid];
    int bucket = g & 127;
    atomicAdd(&stats[(size_t)bucket*256 + tid], (double)S);
    atomicAdd(&stats[(size_t)bucket*256 + 128 + tid], (double)Q);
  }
}

// ---------------- K_mlpB: Y0 + BN0/ReLU -> L1 -> Y1 (raw) + stats1 ----------------
__global__ __launch_bounds__(256) void k_mlpB(
    const float* __restrict__ W1, const float* __restrict__ B1v){
  double* stats = g_stats + (size_t)1*128*256;
  const int g = blockIdx.x, tid = threadIdx.x;
  __shared__ __align__(16) float xn[32][68];
  __shared__ __align__(16) float w1s[64][64];
  __shared__ float wsum[4][64], wsq[4][64];

  for (int i = tid; i < 64*64; i += 256) w1s[i>>6][i&63] = W1[i];
  {
    int k = tid >> 3, j = tid & 7;
    const float4* pr = (const float4*)(g_y0 + ((size_t)g*KS + k)*64);
    float4 v0 = pr[j*2], v1 = pr[j*2+1];
    int c0 = j*8;
    xn[k][c0+0] = fmaxf(fmaf(v0.x, g_A[c0+0], g_Bv[c0+0]), 0.f);
    xn[k][c0+1] = fmaxf(fmaf(v0.y, g_A[c0+1], g_Bv[c0+1]), 0.f);
    xn[k][c0+2] = fmaxf(fmaf(v0.z, g_A[c0+2], g_Bv[c0+2]), 0.f);
    xn[k][c0+3] = fmaxf(fmaf(v0.w, g_A[c0+3], g_Bv[c0+3]), 0.f);
    xn[k][c0+4] = fmaxf(fmaf(v1.x, g_A[c0+4], g_Bv[c0+4]), 0.f);
    xn[k][c0+5] = fmaxf(fmaf(v1.y, g_A[c0+5], g_Bv[c0+5]), 0.f);
    xn[k][c0+6] = fmaxf(fmaf(v1.z, g_A[c0+6], g_Bv[c0+6]), 0.f);
    xn[k][c0+7] = fmaxf(fmaf(v1.w, g_A[c0+7], g_Bv[c0+7]), 0.f);
  }
  __syncthreads();

  const int k0 = (tid >> 4) * 2;
  const int d0 = (tid & 15) * 4;
  const int lane = tid & 63, w = tid >> 6;

  float bc0[4] = {0.f,0.f,0.f,0.f};
  float bc1[4] = {0.f,0.f,0.f,0.f};
#pragma unroll
  for (int cq = 0; cq < 16; ++cq){
    const int c = cq*4;
    float xa[4], xb[4], r0[4], r1[4], r2[4], r3[4];
    *(float4*)xa = *(const float4*)&xn[k0][c];
    *(float4*)xb = *(const float4*)&xn[k0+1][c];
    *(float4*)r0 = *(const float4*)&w1s[c+0][d0];
    *(float4*)r1 = *(const float4*)&w1s[c+1][d0];
    *(float4*)r2 = *(const float4*)&w1s[c+2][d0];
    *(float4*)r3 = *(const float4*)&w1s[c+3][d0];
#pragma unroll
    for (int j=0;j<4;j++){
      bc0[j] = fmaf(xa[0], r0[j], bc0[j]);
      bc0[j] = fmaf(xa[1], r1[j], bc0[j]);
      bc0[j] = fmaf(xa[2], r2[j], bc0[j]);
      bc0[j] = fmaf(xa[3], r3[j], bc0[j]);
      bc1[j] = fmaf(xb[0], r0[j], bc1[j]);
      bc1[j] = fmaf(xb[1], r1[j], bc1[j]);
      bc1[j] = fmaf(xb[2], r2[j], bc1[j]);
      bc1[j] = fmaf(xb[3], r3[j], bc1[j]);
    }
  }
#pragma unroll
  for (int j=0;j<4;j++){ float bv = B1v[d0+j]; bc0[j] += bv; bc1[j] += bv; }

  {
    size_t r0 = ((size_t)g*KS + k0)*64 + d0;
    *(float4*)&g_y1[r0]      = *(float4*)bc0;
    *(float4*)&g_y1[r0 + 64] = *(float4*)bc1;
  }

  float s[4], q[4];
#pragma unroll
  for (int j=0;j<4;j++){ s[j] = bc0[j]+bc1[j]; q[j] = bc0[j]*bc0[j] + bc1[j]*bc1[j]; }
#pragma unroll
  for (int j=0;j<4;j++){
    s[j] += __shfl_down(s[j],32); s[j] += __shfl_down(s[j],16);
    q[j] += __shfl_down(q[j],32); q[j] += __shfl_down(q[j],16);
  }
  if (lane < 16){
#pragma unroll
    for (int j=0;j<4;j++){ wsum[w][lane*4+j] = s[j]; wsq[w][lane*4+j] = q[j]; }
  }
  __syncthreads();
  if (tid < 64){
    float S = wsum[0][tid]+wsum[1][tid]+wsum[2][tid]+wsum[3][tid];
    float Q = wsq[0][tid]+wsq[1][tid]+wsq[2][tid]+wsq[3][tid];
    int bucket = g & 127;
    atomicAdd(&stats[(size_t)bucket*256 + tid], (double)S);
    atomicAdd(&stats[(size_t)bucket*256 + 128 + tid], (double)Q);
  }
}

// ---------------- K_mlpC: Y1 + BN1/ReLU -> L2 -> stats2 + max/min ----------------
__global__ __launch_bounds__(256) void k_mlpC(
    const float* __restrict__ W2, const float* __restrict__ B2v){
  double* stats = g_stats + (size_t)2*128*256;
  const int g = blockIdx.x, tid = threadIdx.x;
  __shared__ __align__(16) float xt[32][68];
  __shared__ __align__(16) float w2s[64][128];
  __shared__ float wsum[4][128], wsq[4][128];
  __shared__ float wmx[4][128], wmn[4][128];

  for (int i = tid; i < 64*128; i += 256) w2s[i>>7][i&127] = W2[i];
  {
    int k = tid >> 3, j = tid & 7;
    const float4* pr = (const float4*)(g_y1 + ((size_t)g*KS + k)*64);
    float4 v0 = pr[j*2], v1 = pr[j*2+1];
    int c0 = j*8;
    xt[k][c0+0] = fmaxf(fmaf(v0.x, g_A[64+c0+0], g_Bv[64+c0+0]), 0.f);
    xt[k][c0+1] = fmaxf(fmaf(v0.y, g_A[64+c0+1], g_Bv[64+c0+1]), 0.f);
    xt[k][c0+2] = fmaxf(fmaf(v0.z, g_A[64+c0+2], g_Bv[64+c0+2]), 0.f);
    xt[k][c0+3] = fmaxf(fmaf(v0.w, g_A[64+c0+3], g_Bv[64+c0+3]), 0.f);
    xt[k][c0+4] = fmaxf(fmaf(v1.x, g_A[64+c0+4], g_Bv[64+c0+4]), 0.f);
    xt[k][c0+5] = fmaxf(fmaf(v1.y, g_A[64+c0+5], g_Bv[64+c0+5]), 0.f);
    xt[k][c0+6] = fmaxf(fmaf(v1.z, g_A[64+c0+6], g_Bv[64+c0+6]), 0.f);
    xt[k][c0+7] = fmaxf(fmaf(v1.w, g_A[64+c0+7], g_Bv[64+c0+7]), 0.f);
  }
  __syncthreads();

  const int k0 = (tid >> 4) * 2;
  const int e0 = (tid & 15) * 8;
  const int lane = tid & 63, w = tid >> 6;

  float c0a[8] = {0.f,0.f,0.f,0.f,0.f,0.f,0.f,0.f};
  float c1a[8] = {0.f,0.f,0.f,0.f,0.f,0.f,0.f,0.f};
#pragma unroll
  for (int cq = 0; cq < 16; ++cq){
    const int c = cq*4;
    float xa[4], xb[4], r0[8], r1[8], r2[8], r3[8];
    *(float4*)xa = *(const float4*)&xt[k0][c];
    *(float4*)xb = *(const float4*)&xt[k0+1][c];
    *(float4*)&r0[0] = *(const float4*)&w2s[c+0][e0]; *(float4*)&r0[4] = *(const float4*)&w2s[c+0][e0+4];
    *(float4*)&r1[0] = *(const float4*)&w2s[c+1][e0]; *(float4*)&r1[4] = *(const float4*)&w2s[c+1][e0+4];
    *(float4*)&r2[0] = *(const float4*)&w2s[c+2][e0]; *(float4*)&r2[4] = *(const float4*)&w2s[c+2][e0+4];
    *(float4*)&r3[0] = *(const float4*)&w2s[c+3][e0]; *(float4*)&r3[4] = *(const float4*)&w2s[c+3][e0+4];
#pragma unroll
    for (int j=0;j<8;j++){
      c0a[j] = fmaf(xa[0], r0[j], c0a[j]);
      c0a[j] = fmaf(xa[1], r1[j], c0a[j]);
      c0a[j] = fmaf(xa[2], r2[j], c0a[j]);
      c0a[j] = fmaf(xa[3], r3[j], c0a[j]);
      c1a[j] = fmaf(xb[0], r0[j], c1a[j]);
      c1a[j] = fmaf(xb[1], r1[j], c1a[j]);
      c1a[j] = fmaf(xb[2], r2[j], c1a[j]);
      c1a[j] = fmaf(xb[3], r3[j], c1a[j]);
    }
  }
#pragma unroll
  for (int j=0;j<8;j++){ float bv = B2v[e0+j]; c0a[j] += bv; c1a[j] += bv; }

  float s[8], q[8], mx[8], mn[8];
#pragma unroll
  for (int j=0;j<8;j++){
    s[j] = c0a[j]+c1a[j]; q[j] = c0a[j]*c0a[j] + c1a[j]*c1a[j];
    mx[j] = fmaxf(c0a[j], c1a[j]); mn[j] = fminf(c0a[j], c1a[j]);
  }
#pragma unroll
  for (int j=0;j<8;j++){
    s[j] += __shfl_down(s[j],32); s[j] += __shfl_down(s[j],16);
    q[j] += __shfl_down(q[j],32); q[j] += __shfl_down(q[j],16);
    mx[j] = fmaxf(mx[j], __shfl_xor(mx[j],16)); mx[j] = fmaxf(mx[j], __shfl_xor(mx[j],32));
    mn[j] = fminf(mn[j], __shfl_xor(mn[j],16)); mn[j] = fminf(mn[j], __shfl_xor(mn[j],32));
  }
  if (lane < 16){
#pragma unroll
    for (int j=0;j<8;j++){
      wsum[w][lane*8+j] = s[j]; wsq[w][lane*8+j] = q[j];
      wmx[w][lane*8+j] = mx[j]; wmn[w][lane*8+j] = mn[j];
    }
  }
  __syncthreads();
  if (tid < 128){
    float S = wsum[0][tid]+wsum[1][tid]+wsum[2][tid]+wsum[3][tid];
    float Q = wsq[0][tid]+wsq[1][tid]+wsq[2][tid]+wsq[3][tid];
    float MX = fmaxf(fmaxf(wmx[0][tid],wmx[1][tid]), fmaxf(wmx[2][tid],wmx[3][tid]));
    float MN = fminf(fminf(wmn[0][tid],wmn[1][tid]), fminf(wmn[2][tid],wmn[3][tid]));
    g_mmax[(size_t)g*128 + tid] = MX;
    g_mmin[(size_t)g*128 + tid] = MN;
    int bucket = g & 127;
    atomicAdd(&stats[(size_t)bucket*256 + tid], (double)S);
    atomicAdd(&stats[(size_t)bucket*256 + 128 + tid], (double)Q);
  }
}

// ---------------- K_stats ----------------
__global__ void k_stats(int stage, const float* __restrict__ gamma,
                        const float* __restrict__ beta, int aoff, int cout){
  int c = threadIdx.x;
  if (c >= cout) return;
  const double* stats = g_stats + (size_t)stage*128*256;
  double S=0.0, Q=0.0;
  for (int k=0;k<128;k++){ S += stats[(size_t)k*256 + c]; Q += stats[(size_t)k*256 + 128 + c]; }
  const double M = (double)MROWS;
  double mean = S / M;
  double var  = Q / M - mean*mean;
  double inv  = 1.0 / sqrt(var + 1e-5);
  double a    = (double)gamma[c] * inv;
  g_A[aoff+c]  = (float)a;
  g_Bv[aoff+c] = (float)((double)beta[c] - mean * a);
}

// ---------------- K_final ----------------
__global__ __launch_bounds__(256) void k_final(float* __restrict__ outp){
  int idx = blockIdx.x*256 + threadIdx.x;
  int d = idx & 127;
  float a = g_A[128+d], b = g_Bv[128+d];
  float y = (a >= 0.f) ? g_mmax[idx] : g_mmin[idx];
  float v = fmaf(y, a, b);
  outp[idx] = fmaxf(v, 0.f);
}

extern "C" void kernel_launch(void* const* d_in, const int* in_sizes, int n_in,
                              void* d_out, int out_size, void* d_ws, size_t ws_size,
                              hipStream_t stream) {
  (void)in_sizes; (void)n_in; (void)out_size; (void)d_ws; (void)ws_size;
  const float* xyz    = (const float*)d_in[0];
  const float* points = (const float*)d_in[1];
  const int*   start  = (const int*)d_in[2];
  const float* W0 = (const float*)d_in[3];  const float* b0 = (const float*)d_in[4];
  const float* g0 = (const float*)d_in[5];  const float* be0= (const float*)d_in[6];
  const float* W1 = (const float*)d_in[7];  const float* b1 = (const float*)d_in[8];
  const float* g1 = (const float*)d_in[9];  const float* be1= (const float*)d_in[10];
  const float* W2 = (const float*)d_in[11]; const float* b2 = (const float*)d_in[12];
  const float* g2 = (const float*)d_in[13]; const float* be2= (const float*)d_in[14];

  float* out_xyz = (float*)d_out;
  float* out_pts = (float*)d_out + (size_t)NBATCH*SG*3;

  k_zero <<<384, 256, 0, stream>>>();
  k_pre  <<<256, 256, 0, stream>>>(xyz);
  k_fps  <<<NBATCH, NT, 0, stream>>>(start, out_xyz);
  k_ball <<<4096, 256, 0, stream>>>();

  k_mlpA<<<NGRP, 256, 0, stream>>>(points, W0, b0);
  k_stats<<<1, 128, 0, stream>>>(0, g0, be0, 0, 64);
  k_mlpB<<<NGRP, 256, 0, stream>>>(W1, b1);
  k_stats<<<1, 128, 0, stream>>>(1, g1, be1, 64, 64);
  k_mlpC<<<NGRP, 256, 0, stream>>>(W2, b2);
  k_stats<<<1, 128, 0, stream>>>(2, g2, be2, 128, 128);
  k_final<<<8192, 256, 0, stream>>>(out_pts);
}

// Round 8
// 2596.692 us; speedup vs baseline: 1.4082x; 1.0379x over previous
//
#include <hip/hip_runtime.h>
#include <stdint.h>
#include <stddef.h>

typedef unsigned long long u64;
typedef unsigned int u32;
typedef float f32x2 __attribute__((ext_vector_type(2)));

#define NBATCH 8
#define NPTS   8192
#define SG     2048
#define KS     32
#define NGRP   (NBATCH*SG)      // 16384
#define MROWS  (NGRP*KS)        // 524288

// ---- ALL scratch in module-static device globals: immune to ws_size ----
__device__ float4 g_p4[NBATCH*NPTS];          // 1 MiB  {x,y,z,|p|^2}
__device__ float  g_cx[NGRP], g_cy[NGRP], g_cz[NGRP];
__device__ int    g_ball[(size_t)NGRP*KS];    // 2 MiB
__device__ double g_stats[3*128*256];         // 768 KiB
__device__ float  g_A[256], g_Bv[256];        // BN scale/shift: L0 @0, L1 @64, L2 @128
__device__ float  g_mmax[(size_t)NGRP*128];   // 8 MiB
__device__ float  g_mmin[(size_t)NGRP*128];   // 8 MiB
__device__ float  g_y0[(size_t)MROWS*64];     // 134 MiB raw L0 output
__device__ float  g_y1[(size_t)MROWS*64];     // 134 MiB raw L1 output

// ---------------- K_zero ----------------
__global__ __launch_bounds__(256) void k_zero(){
  int idx = blockIdx.x*256 + threadIdx.x;
  if (idx < 3*128*256) g_stats[idx] = 0.0;
}

// ---------------- K_pre ----------------
__global__ __launch_bounds__(256) void k_pre(const float* __restrict__ xyz){
#pragma clang fp contract(off)
  int idx = blockIdx.x*256 + threadIdx.x;
  if (idx >= NBATCH*NPTS) return;
  float x = xyz[idx*3+0];
  float y = xyz[idx*3+1];
  float z = xyz[idx*3+2];
  float xx = x*x; float yy = y*y; float zz = z*z;
  float s2 = (xx + yy) + zz;
  g_p4[idx] = make_float4(x,y,z,s2);
}

// ---------------- K_fps ----------------
// Evidence trail: r5 2123 -> r6 (DPP reduce) 2107 -> r7 (no vmem in loop)
// 2105. Three nulls; VALUBusy scaled rose 62%->86% across r5->r6 at flat
// duration => kernel converted stall into issue and is now VALU-ISSUE-
// bound on its 8 CUs. Only instruction-count reduction can move it.
// r8: packed-f32 UPD.
//   * distance math on f32x2 (pairs of points): backend selects VOP3P
//     v_pk_add_f32 / v_pk_mul_f32 (gfx90a+ packed FP32) -> 2 IEEE f32
//     ops per instruction. 64 scalar arith ops -> 32 packed.
//   * scan: fmaxf tree for bv (folds to v_max3_f32) + DESCENDING
//     equality-select for bi => smallest index achieving max == original
//     first-max tie-break under strict-> ascending scan.
// Exactness: element-wise IEEE identical op sequence (sub, mul,
// (a0+a1)+a2, fminf) under contract(off); n[j] == point j*NT+t exactly
// as before; bv = exact max of same non-NaN values; gi/key/f64-DPP
// reduce untouched => centroid sequence bit-identical. If the backend
// scalarizes the vectors, codegen == previous (downside-safe).

#define NT  1024
#define PPT 8

#define FOR4(M) M(0) M(1) M(2) M(3)

#define DECLP2(i) f32x2 px##i, py##i, pz##i, dd##i;

#define LOADP2(i) { float4 pA = g_p4[base + (2*(i)  )*NT + t]; \
                    float4 pB = g_p4[base + (2*(i)+1)*NT + t]; \
                    px##i.x = pA.x; px##i.y = pB.x; \
                    py##i.x = pA.y; py##i.y = pB.y; \
                    pz##i.x = pA.z; pz##i.y = pB.z; \
                    dd##i.x = 1e10f; dd##i.y = 1e10f; }

// element-wise identical math: sub, square, (a0+a1)+a2, fminf
#define UPD2(i) { f32x2 dx = px##i - fcx; \
                  f32x2 dy = py##i - fcy; \
                  f32x2 dz = pz##i - fcz; \
                  f32x2 a0 = dx*dx; f32x2 a1 = dy*dy; f32x2 a2 = dz*dz; \
                  f32x2 d  = (a0 + a1) + a2; \
                  f32x2 nd; \
                  nd.x = fminf(dd##i.x, d.x); \
                  nd.y = fminf(dd##i.y, d.y); \
                  dd##i = nd; \
                  n[2*(i)] = nd.x; n[2*(i)+1] = nd.y; }

// one DPP max step on an f64-bits key: 2 dpp movs + v_max_f64
template <int CTRL>
__device__ __forceinline__ double dpp_max_step(double v){
  u64 k  = (u64)__double_as_longlong(v);
  int lo = __builtin_amdgcn_update_dpp(0, (int)(u32)k,        CTRL, 0xf, 0xf, true);
  int hi = __builtin_amdgcn_update_dpp(0, (int)(u32)(k>>32),  CTRL, 0xf, 0xf, true);
  double nv = __longlong_as_double((long long)(((u64)(u32)hi << 32) | (u32)lo));
  return fmax(v, nv);
}

__global__ __launch_bounds__(NT, 1) void k_fps(const int* __restrict__ start, float* __restrict__ out_xyz){
  const int b = blockIdx.x;
  const int t = threadIdx.x;
  const int base = b*NPTS;
  __shared__ double wk16[2][16];               // per-wave partials, dbuf
  __shared__ int    fars[SG];                  // 8 KiB winning indices
  __shared__ __align__(16) float4 pc[NPTS];    // 128 KiB point cache

  // one-time preload of this batch's points into LDS
  for (int i = t; i < NPTS; i += NT) pc[i] = g_p4[base + i];

  FOR4(DECLP2)
  FOR4(LOADP2)

  int far = start[b];
  __syncthreads();                             // pc ready
  float4 fc = pc[far];
  if (t==0) fars[0] = far;
  const int lane = t & 63, w = t >> 6;   // w in 0..15
  for (int it=1; it<SG; ++it){
    float n[8];
    {
#pragma clang fp contract(off)
      const f32x2 fcx = {fc.x, fc.x};
      const f32x2 fcy = {fc.y, fc.y};
      const f32x2 fcz = {fc.z, fc.z};
      FOR4(UPD2)
    }
    // bv = exact max of the 8 running-min distances (non-NaN, >=0)
    float bv = fmaxf(fmaxf(fmaxf(n[0],n[1]), fmaxf(n[2],n[3])),
                     fmaxf(fmaxf(n[4],n[5]), fmaxf(n[6],n[7])));
    // smallest index achieving bv == original first-max tie-break
    int bi = 7;
#pragma unroll
    for (int i=6; i>=0; --i) bi = (n[i]==bv) ? i : bi;

    int gi = bi*NT + t;
    u64 key = ((u64)__float_as_uint(bv) << 32) | (u32)(NPTS-1 - gi);
    double kv = __longlong_as_double((long long)key);
    // in-wave 64 -> 1 (all lanes end with the wave max)
    kv = dpp_max_step<0xB1>(kv);    // quad_perm [1,0,3,2]  (xor1)
    kv = dpp_max_step<0x4E>(kv);    // quad_perm [2,3,0,1]  (xor2)
    kv = dpp_max_step<0x141>(kv);   // ROW_HALF_MIRROR      (8-group)
    kv = dpp_max_step<0x140>(kv);   // ROW_MIRROR           (16-group)
    { double o2 = __shfl_xor(kv, 16); kv = fmax(kv, o2); }
    { double o2 = __shfl_xor(kv, 32); kv = fmax(kv, o2); }
    const int s = it & 1;
    if (lane == 0) wk16[s][w] = kv;
    __syncthreads();
    // every lane: read one of the 16 partials (32 banks, conflict-free),
    // then 4 DPP steps reduce the 16 within each row -> global max
    double km = wk16[s][lane & 15];
    km = dpp_max_step<0xB1>(km);
    km = dpp_max_step<0x4E>(km);
    km = dpp_max_step<0x141>(km);
    km = dpp_max_step<0x140>(km);
    u64 kmu = (u64)__double_as_longlong(km);
    far = NPTS-1 - (int)(kmu & 0xffffffffu);
    fc = pc[far];
    if (t==0) fars[it] = far;                  // LDS only — no vmem in loop
  }
  __syncthreads();                             // fars complete
  // epilogue: write all centroids once (same values, same locations)
  for (int it = t; it < SG; it += NT){
    int f = fars[it];
    float4 p = pc[f];
    int gidx = b*SG + it;
    g_cx[gidx] = p.x; g_cy[gidx] = p.y; g_cz[gidx] = p.z;
    size_t o = (size_t)gidx*3;
    out_xyz[o+0]=p.x; out_xyz[o+1]=p.y; out_xyz[o+2]=p.z;
  }
}

// ---------------- K_ball: expansion form, FMA-ascending dot (PASSED r7, do not touch) ----------------
__global__ __launch_bounds__(256) void k_ball(){
  const int g = blockIdx.x*4 + (threadIdx.x>>6);
  const int lane = threadIdx.x & 63;
  const int b = g >> 11;
  const float4* pb4 = g_p4 + b*NPTS;
  float cxv = g_cx[g], cyv = g_cy[g], czv = g_cz[g];
  float s1;
  {
#pragma clang fp contract(off)
    float a = cxv*cxv; float bb = cyv*cyv; float cc = czv*czv;
    s1 = (a + bb) + cc;
  }
  const float R2 = 0.04f;
  int filled = 0, firstn = -1;
  for (int n0=0; n0<NPTS && filled<KS; n0+=64){
    float4 p = pb4[n0+lane];
    float sq;
    {
#pragma clang fp contract(off)
      float dt = cxv*p.x;
      dt = fmaf(cyv, p.y, dt);
      dt = fmaf(czv, p.z, dt);
      float ss = s1 + p.w;
      sq = ss - 2.0f*dt;
    }
    bool mem = !(sq > R2);
    u64 mk = __ballot(mem);
    if (firstn < 0 && mk) firstn = n0 + (__ffsll((unsigned long long)mk) - 1);
    int pos = filled + (int)__popcll(mk & ((1ull<<lane)-1ull));
    if (mem && pos < KS) g_ball[(size_t)g*KS + pos] = n0 + lane;
    filled += (int)__popcll(mk);
  }
  for (int s = filled + lane; s < KS; s += 64) g_ball[(size_t)g*KS+s] = firstn;
}

// ---------------- K_mlpA: gather + L0 -> Y0 (raw f32) + stats0 ----------------
__global__ __launch_bounds__(256) void k_mlpA(
    const float* __restrict__ points,
    const float* __restrict__ W0, const float* __restrict__ B0v){
  double* stats = g_stats;
  const int g = blockIdx.x, tid = threadIdx.x;
  const int b = g >> 11;
  __shared__ __align__(16) float xt[32][68];
  __shared__ __align__(16) float w0s[68][64];
  __shared__ float wsum[4][64], wsq[4][64];

  for (int i = tid; i < 67*64; i += 256) w0s[i>>6][i&63] = W0[i];
  if (tid < 64) w0s[67][tid] = 0.f;

  if (tid < 32){
    int n = g_ball[(size_t)g*KS + tid];
    float4 p = g_p4[b*NPTS + n];
    xt[tid][0] = p.x - g_cx[g];
    xt[tid][1] = p.y - g_cy[g];
    xt[tid][2] = p.z - g_cz[g];
    xt[tid][67] = 0.f;
  }
  {
    int k = tid >> 3, j = tid & 7;
    int n = g_ball[(size_t)g*KS + k];
    const float4* pr = (const float4*)(points + ((size_t)(b*NPTS + n))*64);
    float4 v0 = pr[j*2], v1 = pr[j*2+1];
    int c0 = 3 + j*8;
    xt[k][c0+0]=v0.x; xt[k][c0+1]=v0.y; xt[k][c0+2]=v0.z; xt[k][c0+3]=v0.w;
    xt[k][c0+4]=v1.x; xt[k][c0+5]=v1.y; xt[k][c0+6]=v1.z; xt[k][c0+7]=v1.w;
  }
  __syncthreads();

  const int k0 = (tid >> 4) * 2;
  const int d0 = (tid & 15) * 4;
  const int lane = tid & 63, w = tid >> 6;

  float acc0[4] = {0.f,0.f,0.f,0.f};
  float acc1[4] = {0.f,0.f,0.f,0.f};
#pragma unroll
  for (int cq = 0; cq < 17; ++cq){
    const int c = cq*4;
    float xa[4], xb[4], r0[4], r1[4], r2[4], r3[4];
    *(float4*)xa = *(const float4*)&xt[k0][c];
    *(float4*)xb = *(const float4*)&xt[k0+1][c];
    *(float4*)r0 = *(const float4*)&w0s[c+0][d0];
    *(float4*)r1 = *(const float4*)&w0s[c+1][d0];
    *(float4*)r2 = *(const float4*)&w0s[c+2][d0];
    *(float4*)r3 = *(const float4*)&w0s[c+3][d0];
#pragma unroll
    for (int j=0;j<4;j++){
      acc0[j] = fmaf(xa[0], r0[j], acc0[j]);
      acc0[j] = fmaf(xa[1], r1[j], acc0[j]);
      acc0[j] = fmaf(xa[2], r2[j], acc0[j]);
      acc0[j] = fmaf(xa[3], r3[j], acc0[j]);
      acc1[j] = fmaf(xb[0], r0[j], acc1[j]);
      acc1[j] = fmaf(xb[1], r1[j], acc1[j]);
      acc1[j] = fmaf(xb[2], r2[j], acc1[j]);
      acc1[j] = fmaf(xb[3], r3[j], acc1[j]);
    }
  }
#pragma unroll
  for (int j=0;j<4;j++){ float bv = B0v[d0+j]; acc0[j] += bv; acc1[j] += bv; }

  // store raw Y0
  {
    size_t r0 = ((size_t)g*KS + k0)*64 + d0;
    *(float4*)&g_y0[r0]      = *(float4*)acc0;
    *(float4*)&g_y0[r0 + 64] = *(float4*)acc1;
  }

  float s[4], q[4];
#pragma unroll
  for (int j=0;j<4;j++){ s[j] = acc0[j]+acc1[j]; q[j] = acc0[j]*acc0[j] + acc1[j]*acc1[j]; }
#pragma unroll
  for (int j=0;j<4;j++){
    s[j] += __shfl_down(s[j],32); s[j] += __shfl_down(s[j],16);
    q[j] += __shfl_down(q[j],32); q[j] += __shfl_down(q[j],16);
  }
  if (lane < 16){
#pragma unroll
    for (int j=0;j<4;j++){ wsum[w][lane*4+j] = s[j]; wsq[w][lane*4+j] = q[j]; }
  }
  __syncthreads();
  if (tid < 64){
    float S = wsum[0][tid]+wsum[1][tid]+wsum[2][tid]+wsum[3][tid];
    float Q = wsq[0][tid]+wsq[1][tid]+wsq[2][tid]+wsq[3][tid];
    int bucket = g & 127;
    atomicAdd(&stats[(size_t)bucket*256 + tid], (double)S);
    atomicAdd(&stats[(size_t)bucket*256 + 128 + tid], (double)Q);
  }
}

// ---------------- K_mlpB: Y0 + BN0/ReLU -> L1 -> Y1 (raw) + stats1 ----------------
__global__ __launch_bounds__(256) void k_mlpB(
    const float* __restrict__ W1, const float* __restrict__ B1v){
  double* stats = g_stats + (size_t)1*128*256;
  const int g = blockIdx.x, tid = threadIdx.x;
  __shared__ __align__(16) float xn[32][68];
  __shared__ __align__(16) float w1s[64][64];
  __shared__ float wsum[4][64], wsq[4][64];

  for (int i = tid; i < 64*64; i += 256) w1s[i>>6][i&63] = W1[i];
  {
    int k = tid >> 3, j = tid & 7;
    const float4* pr = (const float4*)(g_y0 + ((size_t)g*KS + k)*64);
    float4 v0 = pr[j*2], v1 = pr[j*2+1];
    int c0 = j*8;
    xn[k][c0+0] = fmaxf(fmaf(v0.x, g_A[c0+0], g_Bv[c0+0]), 0.f);
    xn[k][c0+1] = fmaxf(fmaf(v0.y, g_A[c0+1], g_Bv[c0+1]), 0.f);
    xn[k][c0+2] = fmaxf(fmaf(v0.z, g_A[c0+2], g_Bv[c0+2]), 0.f);
    xn[k][c0+3] = fmaxf(fmaf(v0.w, g_A[c0+3], g_Bv[c0+3]), 0.f);
    xn[k][c0+4] = fmaxf(fmaf(v1.x, g_A[c0+4], g_Bv[c0+4]), 0.f);
    xn[k][c0+5] = fmaxf(fmaf(v1.y, g_A[c0+5], g_Bv[c0+5]), 0.f);
    xn[k][c0+6] = fmaxf(fmaf(v1.z, g_A[c0+6], g_Bv[c0+6]), 0.f);
    xn[k][c0+7] = fmaxf(fmaf(v1.w, g_A[c0+7], g_Bv[c0+7]), 0.f);
  }
  __syncthreads();

  const int k0 = (tid >> 4) * 2;
  const int d0 = (tid & 15) * 4;
  const int lane = tid & 63, w = tid >> 6;

  float bc0[4] = {0.f,0.f,0.f,0.f};
  float bc1[4] = {0.f,0.f,0.f,0.f};
#pragma unroll
  for (int cq = 0; cq < 16; ++cq){
    const int c = cq*4;
    float xa[4], xb[4], r0[4], r1[4], r2[4], r3[4];
    *(float4*)xa = *(const float4*)&xn[k0][c];
    *(float4*)xb = *(const float4*)&xn[k0+1][c];
    *(float4*)r0 = *(const float4*)&w1s[c+0][d0];
    *(float4*)r1 = *(const float4*)&w1s[c+1][d0];
    *(float4*)r2 = *(const float4*)&w1s[c+2][d0];
    *(float4*)r3 = *(const float4*)&w1s[c+3][d0];
#pragma unroll
    for (int j=0;j<4;j++){
      bc0[j] = fmaf(xa[0], r0[j], bc0[j]);
      bc0[j] = fmaf(xa[1], r1[j], bc0[j]);
      bc0[j] = fmaf(xa[2], r2[j], bc0[j]);
      bc0[j] = fmaf(xa[3], r3[j], bc0[j]);
      bc1[j] = fmaf(xb[0], r0[j], bc1[j]);
      bc1[j] = fmaf(xb[1], r1[j], bc1[j]);
      bc1[j] = fmaf(xb[2], r2[j], bc1[j]);
      bc1[j] = fmaf(xb[3], r3[j], bc1[j]);
    }
  }
#pragma unroll
  for (int j=0;j<4;j++){ float bv = B1v[d0+j]; bc0[j] += bv; bc1[j] += bv; }

  {
    size_t r0 = ((size_t)g*KS + k0)*64 + d0;
    *(float4*)&g_y1[r0]      = *(float4*)bc0;
    *(float4*)&g_y1[r0 + 64] = *(float4*)bc1;
  }

  float s[4], q[4];
#pragma unroll
  for (int j=0;j<4;j++){ s[j] = bc0[j]+bc1[j]; q[j] = bc0[j]*bc0[j] + bc1[j]*bc1[j]; }
#pragma unroll
  for (int j=0;j<4;j++){
    s[j] += __shfl_down(s[j],32); s[j] += __shfl_down(s[j],16);
    q[j] += __shfl_down(q[j],32); q[j] += __shfl_down(q[j],16);
  }
  if (lane < 16){
#pragma unroll
    for (int j=0;j<4;j++){ wsum[w][lane*4+j] = s[j]; wsq[w][lane*4+j] = q[j]; }
  }
  __syncthreads();
  if (tid < 64){
    float S = wsum[0][tid]+wsum[1][tid]+wsum[2][tid]+wsum[3][tid];
    float Q = wsq[0][tid]+wsq[1][tid]+wsq[2][tid]+wsq[3][tid];
    int bucket = g & 127;
    atomicAdd(&stats[(size_t)bucket*256 + tid], (double)S);
    atomicAdd(&stats[(size_t)bucket*256 + 128 + tid], (double)Q);
  }
}

// ---------------- K_mlpC: Y1 + BN1/ReLU -> L2 -> stats2 + max/min ----------------
__global__ __launch_bounds__(256) void k_mlpC(
    const float* __restrict__ W2, const float* __restrict__ B2v){
  double* stats = g_stats + (size_t)2*128*256;
  const int g = blockIdx.x, tid = threadIdx.x;
  __shared__ __align__(16) float xt[32][68];
  __shared__ __align__(16) float w2s[64][128];
  __shared__ float wsum[4][128], wsq[4][128];
  __shared__ float wmx[4][128], wmn[4][128];

  for (int i = tid; i < 64*128; i += 256) w2s[i>>7][i&127] = W2[i];
  {
    int k = tid >> 3, j = tid & 7;
    const float4* pr = (const float4*)(g_y1 + ((size_t)g*KS + k)*64);
    float4 v0 = pr[j*2], v1 = pr[j*2+1];
    int c0 = j*8;
    xt[k][c0+0] = fmaxf(fmaf(v0.x, g_A[64+c0+0], g_Bv[64+c0+0]), 0.f);
    xt[k][c0+1] = fmaxf(fmaf(v0.y, g_A[64+c0+1], g_Bv[64+c0+1]), 0.f);
    xt[k][c0+2] = fmaxf(fmaf(v0.z, g_A[64+c0+2], g_Bv[64+c0+2]), 0.f);
    xt[k][c0+3] = fmaxf(fmaf(v0.w, g_A[64+c0+3], g_Bv[64+c0+3]), 0.f);
    xt[k][c0+4] = fmaxf(fmaf(v1.x, g_A[64+c0+4], g_Bv[64+c0+4]), 0.f);
    xt[k][c0+5] = fmaxf(fmaf(v1.y, g_A[64+c0+5], g_Bv[64+c0+5]), 0.f);
    xt[k][c0+6] = fmaxf(fmaf(v1.z, g_A[64+c0+6], g_Bv[64+c0+6]), 0.f);
    xt[k][c0+7] = fmaxf(fmaf(v1.w, g_A[64+c0+7], g_Bv[64+c0+7]), 0.f);
  }
  __syncthreads();

  const int k0 = (tid >> 4) * 2;
  const int e0 = (tid & 15) * 8;
  const int lane = tid & 63, w = tid >> 6;

  float c0a[8] = {0.f,0.f,0.f,0.f,0.f,0.f,0.f,0.f};
  float c1a[8] = {0.f,0.f,0.f,0.f,0.f,0.f,0.f,0.f};
#pragma unroll
  for (int cq = 0; cq < 16; ++cq){
    const int c = cq*4;
    float xa[4], xb[4], r0[8], r1[8], r2[8], r3[8];
    *(float4*)xa = *(const float4*)&xt[k0][c];
    *(float4*)xb = *(const float4*)&xt[k0+1][c];
    *(float4*)&r0[0] = *(const float4*)&w2s[c+0][e0]; *(float4*)&r0[4] = *(const float4*)&w2s[c+0][e0+4];
    *(float4*)&r1[0] = *(const float4*)&w2s[c+1][e0]; *(float4*)&r1[4] = *(const float4*)&w2s[c+1][e0+4];
    *(float4*)&r2[0] = *(const float4*)&w2s[c+2][e0]; *(float4*)&r2[4] = *(const float4*)&w2s[c+2][e0+4];
    *(float4*)&r3[0] = *(const float4*)&w2s[c+3][e0]; *(float4*)&r3[4] = *(const float4*)&w2s[c+3][e0+4];
#pragma unroll
    for (int j=0;j<8;j++){
      c0a[j] = fmaf(xa[0], r0[j], c0a[j]);
      c0a[j] = fmaf(xa[1], r1[j], c0a[j]);
      c0a[j] = fmaf(xa[2], r2[j], c0a[j]);
      c0a[j] = fmaf(xa[3], r3[j], c0a[j]);
      c1a[j] = fmaf(xb[0], r0[j], c1a[j]);
      c1a[j] = fmaf(xb[1], r1[j], c1a[j]);
      c1a[j] = fmaf(xb[2], r2[j], c1a[j]);
      c1a[j] = fmaf(xb[3], r3[j], c1a[j]);
    }
  }
#pragma unroll
  for (int j=0;j<8;j++){ float bv = B2v[e0+j]; c0a[j] += bv; c1a[j] += bv; }

  float s[8], q[8], mx[8], mn[8];
#pragma unroll
  for (int j=0;j<8;j++){
    s[j] = c0a[j]+c1a[j]; q[j] = c0a[j]*c0a[j] + c1a[j]*c1a[j];
    mx[j] = fmaxf(c0a[j], c1a[j]); mn[j] = fminf(c0a[j], c1a[j]);
  }
#pragma unroll
  for (int j=0;j<8;j++){
    s[j] += __shfl_down(s[j],32); s[j] += __shfl_down(s[j],16);
    q[j] += __shfl_down(q[j],32); q[j] += __shfl_down(q[j],16);
    mx[j] = fmaxf(mx[j], __shfl_xor(mx[j],16)); mx[j] = fmaxf(mx[j], __shfl_xor(mx[j],32));
    mn[j] = fminf(mn[j], __shfl_xor(mn[j],16)); mn[j] = fminf(mn[j], __shfl_xor(mn[j],32));
  }
  if (lane < 16){
#pragma unroll
    for (int j=0;j<8;j++){
      wsum[w][lane*8+j] = s[j]; wsq[w][lane*8+j] = q[j];
      wmx[w][lane*8+j] = mx[j]; wmn[w][lane*8+j] = mn[j];
    }
  }
  __syncthreads();
  if (tid < 128){
    float S = wsum[0][tid]+wsum[1][tid]+wsum[2][tid]+wsum[3][tid];
    float Q = wsq[0][tid]+wsq[1][tid]+wsq[2][tid]+wsq[3][tid];
    float MX = fmaxf(fmaxf(wmx[0][tid],wmx[1][tid]), fmaxf(wmx[2][tid],wmx[3][tid]));
    float MN = fminf(fminf(wmn[0][tid],wmn[1][tid]), fminf(wmn[2][tid],wmn[3][tid]));
    g_mmax[(size_t)g*128 + tid] = MX;
    g_mmin[(size_t)g*128 + tid] = MN;
    int bucket = g & 127;
    atomicAdd(&stats[(size_t)bucket*256 + tid], (double)S);
    atomicAdd(&stats[(size_t)bucket*256 + 128 + tid], (double)Q);
  }
}

// ---------------- K_stats ----------------
__global__ void k_stats(int stage, const float* __restrict__ gamma,
                        const float* __restrict__ beta, int aoff, int cout){
  int c = threadIdx.x;
  if (c >= cout) return;
  const double* stats = g_stats + (size_t)stage*128*256;
  double S=0.0, Q=0.0;
  for (int k=0;k<128;k++){ S += stats[(size_t)k*256 + c]; Q += stats[(size_t)k*256 + 128 + c]; }
  const double M = (double)MROWS;
  double mean = S / M;
  double var  = Q / M - mean*mean;
  double inv  = 1.0 / sqrt(var + 1e-5);
  double a    = (double)gamma[c] * inv;
  g_A[aoff+c]  = (float)a;
  g_Bv[aoff+c] = (float)((double)beta[c] - mean * a);
}

// ---------------- K_final ----------------
__global__ __launch_bounds__(256) void k_final(float* __restrict__ outp){
  int idx = blockIdx.x*256 + threadIdx.x;
  int d = idx & 127;
  float a = g_A[128+d], b = g_Bv[128+d];
  float y = (a >= 0.f) ? g_mmax[idx] : g_mmin[idx];
  float v = fmaf(y, a, b);
  outp[idx] = fmaxf(v, 0.f);
}

extern "C" void kernel_launch(void* const* d_in, const int* in_sizes, int n_in,
                              void* d_out, int out_size, void* d_ws, size_t ws_size,
                              hipStream_t stream) {
  (void)in_sizes; (void)n_in; (void)out_size; (void)d_ws; (void)ws_size;
  const float* xyz    = (const float*)d_in[0];
  const float* points = (const float*)d_in[1];
  const int*   start  = (const int*)d_in[2];
  const float* W0 = (const float*)d_in[3];  const float* b0 = (const float*)d_in[4];
  const float* g0 = (const float*)d_in[5];  const float* be0= (const float*)d_in[6];
  const float* W1 = (const float*)d_in[7];  const float* b1 = (const float*)d_in[8];
  const float* g1 = (const float*)d_in[9];  const float* be1= (const float*)d_in[10];
  const float* W2 = (const float*)d_in[11]; const float* b2 = (const float*)d_in[12];
  const float* g2 = (const float*)d_in[13]; const float* be2= (const float*)d_in[14];

  float* out_xyz = (float*)d_out;
  float* out_pts = (float*)d_out + (size_t)NBATCH*SG*3;

  k_zero <<<384, 256, 0, stream>>>();
  k_pre  <<<256, 256, 0, stream>>>(xyz);
  k_fps  <<<NBATCH, NT, 0, stream>>>(start, out_xyz);
  k_ball <<<4096, 256, 0, stream>>>();

  k_mlpA<<<NGRP, 256, 0, stream>>>(points, W0, b0);
  k_stats<<<1, 128, 0, stream>>>(0, g0, be0, 0, 64);
  k_mlpB<<<NGRP, 256, 0, stream>>>(W1, b1);
  k_stats<<<1, 128, 0, stream>>>(1, g1, be1, 64, 64);
  k_mlpC<<<NGRP, 256, 0, stream>>>(W2, b2);
  k_stats<<<1, 128, 0, stream>>>(2, g2, be2, 128, 128);
  k_final<<<8192, 256, 0, stream>>>(out_pts);
}

// Round 9
// 2399.261 us; speedup vs baseline: 1.5241x; 1.0823x over previous
//
#include <hip/hip_runtime.h>
#include <stdint.h>
#include <stddef.h>

typedef unsigned long long u64;
typedef unsigned int u32;
typedef float f32x2 __attribute__((ext_vector_type(2)));

#define NBATCH 8
#define NPTS   8192
#define SG     2048
#define KS     32
#define NGRP   (NBATCH*SG)      // 16384
#define MROWS  (NGRP*KS)        // 524288

// ---- ALL scratch in module-static device globals: immune to ws_size ----
__device__ float4 g_p4[NBATCH*NPTS];          // 1 MiB  {x,y,z,|p|^2}
__device__ float  g_cx[NGRP], g_cy[NGRP], g_cz[NGRP];
__device__ int    g_ball[(size_t)NGRP*KS];    // 2 MiB
__device__ double g_stats[3*128*256];         // 768 KiB
__device__ float  g_A[256], g_Bv[256];        // BN scale/shift: L0 @0, L1 @64, L2 @128
__device__ float  g_mmax[(size_t)NGRP*128];   // 8 MiB
__device__ float  g_mmin[(size_t)NGRP*128];   // 8 MiB
__device__ float  g_y0[(size_t)MROWS*64];     // 134 MiB raw L0 output
__device__ float  g_y1[(size_t)MROWS*64];     // 134 MiB raw L1 output

// ---------------- K_zero ----------------
__global__ __launch_bounds__(256) void k_zero(){
  int idx = blockIdx.x*256 + threadIdx.x;
  if (idx < 3*128*256) g_stats[idx] = 0.0;
}

// ---------------- K_pre ----------------
__global__ __launch_bounds__(256) void k_pre(const float* __restrict__ xyz){
#pragma clang fp contract(off)
  int idx = blockIdx.x*256 + threadIdx.x;
  if (idx >= NBATCH*NPTS) return;
  float x = xyz[idx*3+0];
  float y = xyz[idx*3+1];
  float z = xyz[idx*3+2];
  float xx = x*x; float yy = y*y; float zz = z*z;
  float s2 = (xx + yy) + zz;
  g_p4[idx] = make_float4(x,y,z,s2);
}

// ---------------- K_fps ----------------
// Evidence trail: r5 2123 -> r6 DPP 2107 -> r7 no-vmem 2105 -> r8 packed
// 2006us. Cost model: issue+ALU ~1100cy + chain ~450cy, measured 2352cy/
// iter => ~1000cy unmodeled. Every remaining reduce-path micro-lever cost-
// models as a wash. The one never-varied factor: BARRIER POPULATION —
// 16-wave s_barrier arrival-skew/rewake every iteration (also explains the
// r6/r7 nulls: chain cuts absorbed by barrier skew).
// r9: 512 threads x 16 pts/thread, 8 waves per barrier (half population).
//   * all state in regs: 24 xyz f32x2 + 8 dd f32x2 = 64 VGPR + temps ~80,
//     under the empirically observed 88 budget => no spill (r2's confounds
//     — LDS-dist DS storm, scalar math — are both absent here).
//   * per-SIMD issue conserved (2 waves x ~330 vs 4 x ~212 cy).
//   * cross-wave reduce over 8 partials: wk8[s][lane&7] + 3 DPP steps
//     (xor1, xor2, ROW_HALF_MIRROR = 8-group butterfly, validated r6-r8).
// Exactness: UPD element-wise IEEE sequence frozen (contract off, sub,
// mul, (a0+a1)+a2, fminf); n[j] <-> point j*512+t; gi = bi*NT+t ascending
// with local index => same tie-break; f64-bit key max proven exact
// (positive, NaN-free, unique); max associative => winner bit-identical;
// wk8 dbuf race-free via one barrier/iter (reads of iter it precede
// writes of it+2 by two barriers).

#define NT  512
#define PPT 16

#define FOR8(M) M(0) M(1) M(2) M(3) M(4) M(5) M(6) M(7)

#define DECLP2(i) f32x2 px##i, py##i, pz##i, dd##i;

#define LOADP2(i) { float4 pA = g_p4[base + (2*(i)  )*NT + t]; \
                    float4 pB = g_p4[base + (2*(i)+1)*NT + t]; \
                    px##i.x = pA.x; px##i.y = pB.x; \
                    py##i.x = pA.y; py##i.y = pB.y; \
                    pz##i.x = pA.z; pz##i.y = pB.z; \
                    dd##i.x = 1e10f; dd##i.y = 1e10f; }

// element-wise identical math: sub, square, (a0+a1)+a2, fminf
#define UPD2(i) { f32x2 dx = px##i - fcx; \
                  f32x2 dy = py##i - fcy; \
                  f32x2 dz = pz##i - fcz; \
                  f32x2 a0 = dx*dx; f32x2 a1 = dy*dy; f32x2 a2 = dz*dz; \
                  f32x2 d  = (a0 + a1) + a2; \
                  f32x2 nd; \
                  nd.x = fminf(dd##i.x, d.x); \
                  nd.y = fminf(dd##i.y, d.y); \
                  dd##i = nd; \
                  n[2*(i)] = nd.x; n[2*(i)+1] = nd.y; }

// one DPP max step on an f64-bits key: 2 dpp movs + v_max_f64
template <int CTRL>
__device__ __forceinline__ double dpp_max_step(double v){
  u64 k  = (u64)__double_as_longlong(v);
  int lo = __builtin_amdgcn_update_dpp(0, (int)(u32)k,        CTRL, 0xf, 0xf, true);
  int hi = __builtin_amdgcn_update_dpp(0, (int)(u32)(k>>32),  CTRL, 0xf, 0xf, true);
  double nv = __longlong_as_double((long long)(((u64)(u32)hi << 32) | (u32)lo));
  return fmax(v, nv);
}

__global__ __launch_bounds__(NT, 1) void k_fps(const int* __restrict__ start, float* __restrict__ out_xyz){
  const int b = blockIdx.x;
  const int t = threadIdx.x;
  const int base = b*NPTS;
  __shared__ double wk8[2][8];                 // per-wave partials, dbuf
  __shared__ int    fars[SG];                  // 8 KiB winning indices
  __shared__ __align__(16) float4 pc[NPTS];    // 128 KiB point cache

  // one-time preload of this batch's points into LDS
  for (int i = t; i < NPTS; i += NT) pc[i] = g_p4[base + i];

  FOR8(DECLP2)
  FOR8(LOADP2)

  int far = start[b];
  __syncthreads();                             // pc ready
  float4 fc = pc[far];
  if (t==0) fars[0] = far;
  const int lane = t & 63, w = t >> 6;   // w in 0..7
  for (int it=1; it<SG; ++it){
    float n[16];
    {
#pragma clang fp contract(off)
      const f32x2 fcx = {fc.x, fc.x};
      const f32x2 fcy = {fc.y, fc.y};
      const f32x2 fcz = {fc.z, fc.z};
      FOR8(UPD2)
    }
    // bv = exact max of the 16 running-min distances (non-NaN, >=0)
    float m0 = fmaxf(fmaxf(fmaxf(n[0],n[1]),  fmaxf(n[2],n[3])),
                     fmaxf(fmaxf(n[4],n[5]),  fmaxf(n[6],n[7])));
    float m1 = fmaxf(fmaxf(fmaxf(n[8],n[9]),  fmaxf(n[10],n[11])),
                     fmaxf(fmaxf(n[12],n[13]),fmaxf(n[14],n[15])));
    float bv = fmaxf(m0, m1);
    // smallest index achieving bv == original first-max tie-break
    int bi = 15;
#pragma unroll
    for (int i=14; i>=0; --i) bi = (n[i]==bv) ? i : bi;

    int gi = bi*NT + t;
    u64 key = ((u64)__float_as_uint(bv) << 32) | (u32)(NPTS-1 - gi);
    double kv = __longlong_as_double((long long)key);
    // in-wave 64 -> 1 (all lanes end with the wave max)
    kv = dpp_max_step<0xB1>(kv);    // quad_perm [1,0,3,2]  (xor1)
    kv = dpp_max_step<0x4E>(kv);    // quad_perm [2,3,0,1]  (xor2)
    kv = dpp_max_step<0x141>(kv);   // ROW_HALF_MIRROR      (8-group)
    kv = dpp_max_step<0x140>(kv);   // ROW_MIRROR           (16-group)
    { double o2 = __shfl_xor(kv, 16); kv = fmax(kv, o2); }
    { double o2 = __shfl_xor(kv, 32); kv = fmax(kv, o2); }
    const int s = it & 1;
    if (lane == 0) wk8[s][w] = kv;
    __syncthreads();
    // every lane: read one of the 8 partials, then 3 DPP steps reduce
    // each 8-lane group -> global max in every lane
    double km = wk8[s][lane & 7];
    km = dpp_max_step<0xB1>(km);
    km = dpp_max_step<0x4E>(km);
    km = dpp_max_step<0x141>(km);
    u64 kmu = (u64)__double_as_longlong(km);
    far = NPTS-1 - (int)(kmu & 0xffffffffu);
    fc = pc[far];
    if (t==0) fars[it] = far;                  // LDS only — no vmem in loop
  }
  __syncthreads();                             // fars complete
  // epilogue: write all centroids once (same values, same locations)
  for (int it = t; it < SG; it += NT){
    int f = fars[it];
    float4 p = pc[f];
    int gidx = b*SG + it;
    g_cx[gidx] = p.x; g_cy[gidx] = p.y; g_cz[gidx] = p.z;
    size_t o = (size_t)gidx*3;
    out_xyz[o+0]=p.x; out_xyz[o+1]=p.y; out_xyz[o+2]=p.z;
  }
}

// ---------------- K_ball: expansion form, FMA-ascending dot (PASSED r7, do not touch) ----------------
__global__ __launch_bounds__(256) void k_ball(){
  const int g = blockIdx.x*4 + (threadIdx.x>>6);
  const int lane = threadIdx.x & 63;
  const int b = g >> 11;
  const float4* pb4 = g_p4 + b*NPTS;
  float cxv = g_cx[g], cyv = g_cy[g], czv = g_cz[g];
  float s1;
  {
#pragma clang fp contract(off)
    float a = cxv*cxv; float bb = cyv*cyv; float cc = czv*czv;
    s1 = (a + bb) + cc;
  }
  const float R2 = 0.04f;
  int filled = 0, firstn = -1;
  for (int n0=0; n0<NPTS && filled<KS; n0+=64){
    float4 p = pb4[n0+lane];
    float sq;
    {
#pragma clang fp contract(off)
      float dt = cxv*p.x;
      dt = fmaf(cyv, p.y, dt);
      dt = fmaf(czv, p.z, dt);
      float ss = s1 + p.w;
      sq = ss - 2.0f*dt;
    }
    bool mem = !(sq > R2);
    u64 mk = __ballot(mem);
    if (firstn < 0 && mk) firstn = n0 + (__ffsll((unsigned long long)mk) - 1);
    int pos = filled + (int)__popcll(mk & ((1ull<<lane)-1ull));
    if (mem && pos < KS) g_ball[(size_t)g*KS + pos] = n0 + lane;
    filled += (int)__popcll(mk);
  }
  for (int s = filled + lane; s < KS; s += 64) g_ball[(size_t)g*KS+s] = firstn;
}

// ---------------- K_mlpA: gather + L0 -> Y0 (raw f32) + stats0 ----------------
__global__ __launch_bounds__(256) void k_mlpA(
    const float* __restrict__ points,
    const float* __restrict__ W0, const float* __restrict__ B0v){
  double* stats = g_stats;
  const int g = blockIdx.x, tid = threadIdx.x;
  const int b = g >> 11;
  __shared__ __align__(16) float xt[32][68];
  __shared__ __align__(16) float w0s[68][64];
  __shared__ float wsum[4][64], wsq[4][64];

  for (int i = tid; i < 67*64; i += 256) w0s[i>>6][i&63] = W0[i];
  if (tid < 64) w0s[67][tid] = 0.f;

  if (tid < 32){
    int n = g_ball[(size_t)g*KS + tid];
    float4 p = g_p4[b*NPTS + n];
    xt[tid][0] = p.x - g_cx[g];
    xt[tid][1] = p.y - g_cy[g];
    xt[tid][2] = p.z - g_cz[g];
    xt[tid][67] = 0.f;
  }
  {
    int k = tid >> 3, j = tid & 7;
    int n = g_ball[(size_t)g*KS + k];
    const float4* pr = (const float4*)(points + ((size_t)(b*NPTS + n))*64);
    float4 v0 = pr[j*2], v1 = pr[j*2+1];
    int c0 = 3 + j*8;
    xt[k][c0+0]=v0.x; xt[k][c0+1]=v0.y; xt[k][c0+2]=v0.z; xt[k][c0+3]=v0.w;
    xt[k][c0+4]=v1.x; xt[k][c0+5]=v1.y; xt[k][c0+6]=v1.z; xt[k][c0+7]=v1.w;
  }
  __syncthreads();

  const int k0 = (tid >> 4) * 2;
  const int d0 = (tid & 15) * 4;
  const int lane = tid & 63, w = tid >> 6;

  float acc0[4] = {0.f,0.f,0.f,0.f};
  float acc1[4] = {0.f,0.f,0.f,0.f};
#pragma unroll
  for (int cq = 0; cq < 17; ++cq){
    const int c = cq*4;
    float xa[4], xb[4], r0[4], r1[4], r2[4], r3[4];
    *(float4*)xa = *(const float4*)&xt[k0][c];
    *(float4*)xb = *(const float4*)&xt[k0+1][c];
    *(float4*)r0 = *(const float4*)&w0s[c+0][d0];
    *(float4*)r1 = *(const float4*)&w0s[c+1][d0];
    *(float4*)r2 = *(const float4*)&w0s[c+2][d0];
    *(float4*)r3 = *(const float4*)&w0s[c+3][d0];
#pragma unroll
    for (int j=0;j<4;j++){
      acc0[j] = fmaf(xa[0], r0[j], acc0[j]);
      acc0[j] = fmaf(xa[1], r1[j], acc0[j]);
      acc0[j] = fmaf(xa[2], r2[j], acc0[j]);
      acc0[j] = fmaf(xa[3], r3[j], acc0[j]);
      acc1[j] = fmaf(xb[0], r0[j], acc1[j]);
      acc1[j] = fmaf(xb[1], r1[j], acc1[j]);
      acc1[j] = fmaf(xb[2], r2[j], acc1[j]);
      acc1[j] = fmaf(xb[3], r3[j], acc1[j]);
    }
  }
#pragma unroll
  for (int j=0;j<4;j++){ float bv = B0v[d0+j]; acc0[j] += bv; acc1[j] += bv; }

  // store raw Y0
  {
    size_t r0 = ((size_t)g*KS + k0)*64 + d0;
    *(float4*)&g_y0[r0]      = *(float4*)acc0;
    *(float4*)&g_y0[r0 + 64] = *(float4*)acc1;
  }

  float s[4], q[4];
#pragma unroll
  for (int j=0;j<4;j++){ s[j] = acc0[j]+acc1[j]; q[j] = acc0[j]*acc0[j] + acc1[j]*acc1[j]; }
#pragma unroll
  for (int j=0;j<4;j++){
    s[j] += __shfl_down(s[j],32); s[j] += __shfl_down(s[j],16);
    q[j] += __shfl_down(q[j],32); q[j] += __shfl_down(q[j],16);
  }
  if (lane < 16){
#pragma unroll
    for (int j=0;j<4;j++){ wsum[w][lane*4+j] = s[j]; wsq[w][lane*4+j] = q[j]; }
  }
  __syncthreads();
  if (tid < 64){
    float S = wsum[0][tid]+wsum[1][tid]+wsum[2][tid]+wsum[3][tid];
    float Q = wsq[0][tid]+wsq[1][tid]+wsq[2][tid]+wsq[3][tid];
    int bucket = g & 127;
    atomicAdd(&stats[(size_t)bucket*256 + tid], (double)S);
    atomicAdd(&stats[(size_t)bucket*256 + 128 + tid], (double)Q);
  }
}

// ---------------- K_mlpB: Y0 + BN0/ReLU -> L1 -> Y1 (raw) + stats1 ----------------
__global__ __launch_bounds__(256) void k_mlpB(
    const float* __restrict__ W1, const float* __restrict__ B1v){
  double* stats = g_stats + (size_t)1*128*256;
  const int g = blockIdx.x, tid = threadIdx.x;
  __shared__ __align__(16) float xn[32][68];
  __shared__ __align__(16) float w1s[64][64];
  __shared__ float wsum[4][64], wsq[4][64];

  for (int i = tid; i < 64*64; i += 256) w1s[i>>6][i&63] = W1[i];
  {
    int k = tid >> 3, j = tid & 7;
    const float4* pr = (const float4*)(g_y0 + ((size_t)g*KS + k)*64);
    float4 v0 = pr[j*2], v1 = pr[j*2+1];
    int c0 = j*8;
    xn[k][c0+0] = fmaxf(fmaf(v0.x, g_A[c0+0], g_Bv[c0+0]), 0.f);
    xn[k][c0+1] = fmaxf(fmaf(v0.y, g_A[c0+1], g_Bv[c0+1]), 0.f);
    xn[k][c0+2] = fmaxf(fmaf(v0.z, g_A[c0+2], g_Bv[c0+2]), 0.f);
    xn[k][c0+3] = fmaxf(fmaf(v0.w, g_A[c0+3], g_Bv[c0+3]), 0.f);
    xn[k][c0+4] = fmaxf(fmaf(v1.x, g_A[c0+4], g_Bv[c0+4]), 0.f);
    xn[k][c0+5] = fmaxf(fmaf(v1.y, g_A[c0+5], g_Bv[c0+5]), 0.f);
    xn[k][c0+6] = fmaxf(fmaf(v1.z, g_A[c0+6], g_Bv[c0+6]), 0.f);
    xn[k][c0+7] = fmaxf(fmaf(v1.w, g_A[c0+7], g_Bv[c0+7]), 0.f);
  }
  __syncthreads();

  const int k0 = (tid >> 4) * 2;
  const int d0 = (tid & 15) * 4;
  const int lane = tid & 63, w = tid >> 6;

  float bc0[4] = {0.f,0.f,0.f,0.f};
  float bc1[4] = {0.f,0.f,0.f,0.f};
#pragma unroll
  for (int cq = 0; cq < 16; ++cq){
    const int c = cq*4;
    float xa[4], xb[4], r0[4], r1[4], r2[4], r3[4];
    *(float4*)xa = *(const float4*)&xn[k0][c];
    *(float4*)xb = *(const float4*)&xn[k0+1][c];
    *(float4*)r0 = *(const float4*)&w1s[c+0][d0];
    *(float4*)r1 = *(const float4*)&w1s[c+1][d0];
    *(float4*)r2 = *(const float4*)&w1s[c+2][d0];
    *(float4*)r3 = *(const float4*)&w1s[c+3][d0];
#pragma unroll
    for (int j=0;j<4;j++){
      bc0[j] = fmaf(xa[0], r0[j], bc0[j]);
      bc0[j] = fmaf(xa[1], r1[j], bc0[j]);
      bc0[j] = fmaf(xa[2], r2[j], bc0[j]);
      bc0[j] = fmaf(xa[3], r3[j], bc0[j]);
      bc1[j] = fmaf(xb[0], r0[j], bc1[j]);
      bc1[j] = fmaf(xb[1], r1[j], bc1[j]);
      bc1[j] = fmaf(xb[2], r2[j], bc1[j]);
      bc1[j] = fmaf(xb[3], r3[j], bc1[j]);
    }
  }
#pragma unroll
  for (int j=0;j<4;j++){ float bv = B1v[d0+j]; bc0[j] += bv; bc1[j] += bv; }

  {
    size_t r0 = ((size_t)g*KS + k0)*64 + d0;
    *(float4*)&g_y1[r0]      = *(float4*)bc0;
    *(float4*)&g_y1[r0 + 64] = *(float4*)bc1;
  }

  float s[4], q[4];
#pragma unroll
  for (int j=0;j<4;j++){ s[j] = bc0[j]+bc1[j]; q[j] = bc0[j]*bc0[j] + bc1[j]*bc1[j]; }
#pragma unroll
  for (int j=0;j<4;j++){
    s[j] += __shfl_down(s[j],32); s[j] += __shfl_down(s[j],16);
    q[j] += __shfl_down(q[j],32); q[j] += __shfl_down(q[j],16);
  }
  if (lane < 16){
#pragma unroll
    for (int j=0;j<4;j++){ wsum[w][lane*4+j] = s[j]; wsq[w][lane*4+j] = q[j]; }
  }
  __syncthreads();
  if (tid < 64){
    float S = wsum[0][tid]+wsum[1][tid]+wsum[2][tid]+wsum[3][tid];
    float Q = wsq[0][tid]+wsq[1][tid]+wsq[2][tid]+wsq[3][tid];
    int bucket = g & 127;
    atomicAdd(&stats[(size_t)bucket*256 + tid], (double)S);
    atomicAdd(&stats[(size_t)bucket*256 + 128 + tid], (double)Q);
  }
}

// ---------------- K_mlpC: Y1 + BN1/ReLU -> L2 -> stats2 + max/min ----------------
__global__ __launch_bounds__(256) void k_mlpC(
    const float* __restrict__ W2, const float* __restrict__ B2v){
  double* stats = g_stats + (size_t)2*128*256;
  const int g = blockIdx.x, tid = threadIdx.x;
  __shared__ __align__(16) float xt[32][68];
  __shared__ __align__(16) float w2s[64][128];
  __shared__ float wsum[4][128], wsq[4][128];
  __shared__ float wmx[4][128], wmn[4][128];

  for (int i = tid; i < 64*128; i += 256) w2s[i>>7][i&127] = W2[i];
  {
    int k = tid >> 3, j = tid & 7;
    const float4* pr = (const float4*)(g_y1 + ((size_t)g*KS + k)*64);
    float4 v0 = pr[j*2], v1 = pr[j*2+1];
    int c0 = j*8;
    xt[k][c0+0] = fmaxf(fmaf(v0.x, g_A[64+c0+0], g_Bv[64+c0+0]), 0.f);
    xt[k][c0+1] = fmaxf(fmaf(v0.y, g_A[64+c0+1], g_Bv[64+c0+1]), 0.f);
    xt[k][c0+2] = fmaxf(fmaf(v0.z, g_A[64+c0+2], g_Bv[64+c0+2]), 0.f);
    xt[k][c0+3] = fmaxf(fmaf(v0.w, g_A[64+c0+3], g_Bv[64+c0+3]), 0.f);
    xt[k][c0+4] = fmaxf(fmaf(v1.x, g_A[64+c0+4], g_Bv[64+c0+4]), 0.f);
    xt[k][c0+5] = fmaxf(fmaf(v1.y, g_A[64+c0+5], g_Bv[64+c0+5]), 0.f);
    xt[k][c0+6] = fmaxf(fmaf(v1.z, g_A[64+c0+6], g_Bv[64+c0+6]), 0.f);
    xt[k][c0+7] = fmaxf(fmaf(v1.w, g_A[64+c0+7], g_Bv[64+c0+7]), 0.f);
  }
  __syncthreads();

  const int k0 = (tid >> 4) * 2;
  const int e0 = (tid & 15) * 8;
  const int lane = tid & 63, w = tid >> 6;

  float c0a[8] = {0.f,0.f,0.f,0.f,0.f,0.f,0.f,0.f};
  float c1a[8] = {0.f,0.f,0.f,0.f,0.f,0.f,0.f,0.f};
#pragma unroll
  for (int cq = 0; cq < 16; ++cq){
    const int c = cq*4;
    float xa[4], xb[4], r0[8], r1[8], r2[8], r3[8];
    *(float4*)xa = *(const float4*)&xt[k0][c];
    *(float4*)xb = *(const float4*)&xt[k0+1][c];
    *(float4*)&r0[0] = *(const float4*)&w2s[c+0][e0]; *(float4*)&r0[4] = *(const float4*)&w2s[c+0][e0+4];
    *(float4*)&r1[0] = *(const float4*)&w2s[c+1][e0]; *(float4*)&r1[4] = *(const float4*)&w2s[c+1][e0+4];
    *(float4*)&r2[0] = *(const float4*)&w2s[c+2][e0]; *(float4*)&r2[4] = *(const float4*)&w2s[c+2][e0+4];
    *(float4*)&r3[0] = *(const float4*)&w2s[c+3][e0]; *(float4*)&r3[4] = *(const float4*)&w2s[c+3][e0+4];
#pragma unroll
    for (int j=0;j<8;j++){
      c0a[j] = fmaf(xa[0], r0[j], c0a[j]);
      c0a[j] = fmaf(xa[1], r1[j], c0a[j]);
      c0a[j] = fmaf(xa[2], r2[j], c0a[j]);
      c0a[j] = fmaf(xa[3], r3[j], c0a[j]);
      c1a[j] = fmaf(xb[0], r0[j], c1a[j]);
      c1a[j] = fmaf(xb[1], r1[j], c1a[j]);
      c1a[j] = fmaf(xb[2], r2[j], c1a[j]);
      c1a[j] = fmaf(xb[3], r3[j], c1a[j]);
    }
  }
#pragma unroll
  for (int j=0;j<8;j++){ float bv = B2v[e0+j]; c0a[j] += bv; c1a[j] += bv; }

  float s[8], q[8], mx[8], mn[8];
#pragma unroll
  for (int j=0;j<8;j++){
    s[j] = c0a[j]+c1a[j]; q[j] = c0a[j]*c0a[j] + c1a[j]*c1a[j];
    mx[j] = fmaxf(c0a[j], c1a[j]); mn[j] = fminf(c0a[j], c1a[j]);
  }
#pragma unroll
  for (int j=0;j<8;j++){
    s[j] += __shfl_down(s[j],32); s[j] += __shfl_down(s[j],16);
    q[j] += __shfl_down(q[j],32); q[j] += __shfl_down(q[j],16);
    mx[j] = fmaxf(mx[j], __shfl_xor(mx[j],16)); mx[j] = fmaxf(mx[j], __shfl_xor(mx[j],32));
    mn[j] = fminf(mn[j], __shfl_xor(mn[j],16)); mn[j] = fminf(mn[j], __shfl_xor(mn[j],32));
  }
  if (lane < 16){
#pragma unroll
    for (int j=0;j<8;j++){
      wsum[w][lane*8+j] = s[j]; wsq[w][lane*8+j] = q[j];
      wmx[w][lane*8+j] = mx[j]; wmn[w][lane*8+j] = mn[j];
    }
  }
  __syncthreads();
  if (tid < 128){
    float S = wsum[0][tid]+wsum[1][tid]+wsum[2][tid]+wsum[3][tid];
    float Q = wsq[0][tid]+wsq[1][tid]+wsq[2][tid]+wsq[3][tid];
    float MX = fmaxf(fmaxf(wmx[0][tid],wmx[1][tid]), fmaxf(wmx[2][tid],wmx[3][tid]));
    float MN = fminf(fminf(wmn[0][tid],wmn[1][tid]), fminf(wmn[2][tid],wmn[3][tid]));
    g_mmax[(size_t)g*128 + tid] = MX;
    g_mmin[(size_t)g*128 + tid] = MN;
    int bucket = g & 127;
    atomicAdd(&stats[(size_t)bucket*256 + tid], (double)S);
    atomicAdd(&stats[(size_t)bucket*256 + 128 + tid], (double)Q);
  }
}

// ---------------- K_stats ----------------
__global__ void k_stats(int stage, const float* __restrict__ gamma,
                        const float* __restrict__ beta, int aoff, int cout){
  int c = threadIdx.x;
  if (c >= cout) return;
  const double* stats = g_stats + (size_t)stage*128*256;
  double S=0.0, Q=0.0;
  for (int k=0;k<128;k++){ S += stats[(size_t)k*256 + c]; Q += stats[(size_t)k*256 + 128 + c]; }
  const double M = (double)MROWS;
  double mean = S / M;
  double var  = Q / M - mean*mean;
  double inv  = 1.0 / sqrt(var + 1e-5);
  double a    = (double)gamma[c] * inv;
  g_A[aoff+c]  = (float)a;
  g_Bv[aoff+c] = (float)((double)beta[c] - mean * a);
}

// ---------------- K_final ----------------
__global__ __launch_bounds__(256) void k_final(float* __restrict__ outp){
  int idx = blockIdx.x*256 + threadIdx.x;
  int d = idx & 127;
  float a = g_A[128+d], b = g_Bv[128+d];
  float y = (a >= 0.f) ? g_mmax[idx] : g_mmin[idx];
  float v = fmaf(y, a, b);
  outp[idx] = fmaxf(v, 0.f);
}

extern "C" void kernel_launch(void* const* d_in, const int* in_sizes, int n_in,
                              void* d_out, int out_size, void* d_ws, size_t ws_size,
                              hipStream_t stream) {
  (void)in_sizes; (void)n_in; (void)out_size; (void)d_ws; (void)ws_size;
  const float* xyz    = (const float*)d_in[0];
  const float* points = (const float*)d_in[1];
  const int*   start  = (const int*)d_in[2];
  const float* W0 = (const float*)d_in[3];  const float* b0 = (const float*)d_in[4];
  const float* g0 = (const float*)d_in[5];  const float* be0= (const float*)d_in[6];
  const float* W1 = (const float*)d_in[7];  const float* b1 = (const float*)d_in[8];
  const float* g1 = (const float*)d_in[9];  const float* be1= (const float*)d_in[10];
  const float* W2 = (const float*)d_in[11]; const float* b2 = (const float*)d_in[12];
  const float* g2 = (const float*)d_in[13]; const float* be2= (const float*)d_in[14];

  float* out_xyz = (float*)d_out;
  float* out_pts = (float*)d_out + (size_t)NBATCH*SG*3;

  k_zero <<<384, 256, 0, stream>>>();
  k_pre  <<<256, 256, 0, stream>>>(xyz);
  k_fps  <<<NBATCH, NT, 0, stream>>>(start, out_xyz);
  k_ball <<<4096, 256, 0, stream>>>();

  k_mlpA<<<NGRP, 256, 0, stream>>>(points, W0, b0);
  k_stats<<<1, 128, 0, stream>>>(0, g0, be0, 0, 64);
  k_mlpB<<<NGRP, 256, 0, stream>>>(W1, b1);
  k_stats<<<1, 128, 0, stream>>>(1, g1, be1, 64, 64);
  k_mlpC<<<NGRP, 256, 0, stream>>>(W2, b2);
  k_stats<<<1, 128, 0, stream>>>(2, g2, be2, 128, 128);
  k_final<<<8192, 256, 0, stream>>>(out_pts);
}

// Round 10
// 2086.275 us; speedup vs baseline: 1.7527x; 1.1500x over previous
//
#include <hip/hip_runtime.h>
#include <stdint.h>
#include <stddef.h>

typedef unsigned long long u64;
typedef unsigned int u32;
typedef float f32x2 __attribute__((ext_vector_type(2)));

#define NBATCH 8
#define NPTS   8192
#define SG     2048
#define KS     32
#define NGRP   (NBATCH*SG)      // 16384
#define MROWS  (NGRP*KS)        // 524288

// ---- ALL scratch in module-static device globals: immune to ws_size ----
__device__ float4 g_p4[NBATCH*NPTS];          // 1 MiB  {x,y,z,|p|^2}
__device__ float  g_cx[NGRP], g_cy[NGRP], g_cz[NGRP];
__device__ int    g_ball[(size_t)NGRP*KS];    // 2 MiB
__device__ double g_stats[3*128*256];         // 768 KiB
__device__ float  g_A[256], g_Bv[256];        // BN scale/shift: L0 @0, L1 @64, L2 @128
__device__ float  g_mmax[(size_t)NGRP*128];   // 8 MiB
__device__ float  g_mmin[(size_t)NGRP*128];   // 8 MiB
__device__ float  g_y0[(size_t)MROWS*64];     // 134 MiB raw L0 output
__device__ float  g_y1[(size_t)MROWS*64];     // 134 MiB raw L1 output

// ---------------- K_zero ----------------
__global__ __launch_bounds__(256) void k_zero(){
  int idx = blockIdx.x*256 + threadIdx.x;
  if (idx < 3*128*256) g_stats[idx] = 0.0;
}

// ---------------- K_pre ----------------
__global__ __launch_bounds__(256) void k_pre(const float* __restrict__ xyz){
#pragma clang fp contract(off)
  int idx = blockIdx.x*256 + threadIdx.x;
  if (idx >= NBATCH*NPTS) return;
  float x = xyz[idx*3+0];
  float y = xyz[idx*3+1];
  float z = xyz[idx*3+2];
  float xx = x*x; float yy = y*y; float zz = z*z;
  float s2 = (xx + yy) + zz;
  g_p4[idx] = make_float4(x,y,z,s2);
}

// ---------------- K_fps ----------------
// Evidence: r8 packed 2006us -> r9 (512thr, 8 waves/barrier) 1808us —
// barrier-population theory CONFIRMED (~230cy/iter saved). Residual:
// 2120cy/iter, VALUBusy scaled ~67% => ~355 emitted instr/wave — the
// scan/key machinery (fmax tree + 30-op cmp/cndmask tie-break) and the
// 2 f64 __shfl_xor (4 ds_bpermute round-trips) dominate the non-UPD part.
// r10 bundle (instruction/latency cuts, exactness-frozen):
//   1) incremental f64-key max fused into UPD: klo[j] = 8191-(j*NT+t)
//      hoisted (loop-invariant); per point kk = fmax(kk, {bits(nd),klo}).
//      Deletes tree+bi chain+key build (~49 instr) and the n[16] array.
//      Exactness: identical key set; old path computed exactly max_i
//      key_i; max associative => same winner bits. kk init 0.0 exact
//      (keys >= +0.0; a key can equal +0.0 only if it IS the max).
//   2) ROW_BCAST15/31 DPP finisher replaces the 2 f64 shfl_xor
//      (saves 4 ds_bpermute ~70cy serial): after 4 row steps, bcast15+max,
//      bcast31+max -> lane 63 holds wave max and writes the partial.
//      bound_ctrl 0-fill harmless under max of non-negative keys.
// All else frozen: UPD IEEE sequence (contract off, sub, mul, (a0+a1)+a2,
// fminf); 8-wave single-barrier structure; cross-wave 8-partial DPP
// reduce; wk8 dbuf race-free; epilogue-only global stores.

#define NT  512
#define PPT 16

#define FOR8(M) M(0) M(1) M(2) M(3) M(4) M(5) M(6) M(7)

#define DECLP2(i) f32x2 px##i, py##i, pz##i, dd##i;

#define LOADP2(i) { float4 pA = g_p4[base + (2*(i)  )*NT + t]; \
                    float4 pB = g_p4[base + (2*(i)+1)*NT + t]; \
                    px##i.x = pA.x; px##i.y = pB.x; \
                    py##i.x = pA.y; py##i.y = pB.y; \
                    pz##i.x = pA.z; pz##i.y = pB.z; \
                    dd##i.x = 1e10f; dd##i.y = 1e10f; }

// element-wise identical math: sub, square, (a0+a1)+a2, fminf;
// then fuse the argmax via f64-bit key max (klo hoisted, loop-invariant)
#define UPD2(i) { f32x2 dx = px##i - fcx; \
                  f32x2 dy = py##i - fcy; \
                  f32x2 dz = pz##i - fcz; \
                  f32x2 a0 = dx*dx; f32x2 a1 = dy*dy; f32x2 a2 = dz*dz; \
                  f32x2 d  = (a0 + a1) + a2; \
                  float ndx = fminf(dd##i.x, d.x); \
                  float ndy = fminf(dd##i.y, d.y); \
                  dd##i.x = ndx; dd##i.y = ndy; \
                  u64 kx = ((u64)__float_as_uint(ndx) << 32) | klo[2*(i)]; \
                  u64 ky = ((u64)__float_as_uint(ndy) << 32) | klo[2*(i)+1]; \
                  kk = fmax(kk, __longlong_as_double((long long)kx)); \
                  kk = fmax(kk, __longlong_as_double((long long)ky)); }

// one DPP max step on an f64-bits key: 2 dpp movs + v_max_f64
template <int CTRL>
__device__ __forceinline__ double dpp_max_step(double v){
  u64 k  = (u64)__double_as_longlong(v);
  int lo = __builtin_amdgcn_update_dpp(0, (int)(u32)k,        CTRL, 0xf, 0xf, true);
  int hi = __builtin_amdgcn_update_dpp(0, (int)(u32)(k>>32),  CTRL, 0xf, 0xf, true);
  double nv = __longlong_as_double((long long)(((u64)(u32)hi << 32) | (u32)lo));
  return fmax(v, nv);
}

__global__ __launch_bounds__(NT, 1) void k_fps(const int* __restrict__ start, float* __restrict__ out_xyz){
  const int b = blockIdx.x;
  const int t = threadIdx.x;
  const int base = b*NPTS;
  __shared__ double wk8[2][8];                 // per-wave partials, dbuf
  __shared__ int    fars[SG];                  // 8 KiB winning indices
  __shared__ __align__(16) float4 pc[NPTS];    // 128 KiB point cache

  // one-time preload of this batch's points into LDS
  for (int i = t; i < NPTS; i += NT) pc[i] = g_p4[base + i];

  FOR8(DECLP2)
  FOR8(LOADP2)

  // loop-invariant key low-words: klo[j] = 8191 - (j*NT + t)
  u32 klo[PPT];
#pragma unroll
  for (int j = 0; j < PPT; ++j) klo[j] = (u32)(NPTS-1 - (j*NT + t));

  int far = start[b];
  __syncthreads();                             // pc ready
  float4 fc = pc[far];
  if (t==0) fars[0] = far;
  const int lane = t & 63, w = t >> 6;   // w in 0..7
  for (int it=1; it<SG; ++it){
    double kk = 0.0;                           // exact: all keys >= +0.0
    {
#pragma clang fp contract(off)
      const f32x2 fcx = {fc.x, fc.x};
      const f32x2 fcy = {fc.y, fc.y};
      const f32x2 fcz = {fc.z, fc.z};
      FOR8(UPD2)
    }
    // in-wave 64 -> lane63 (row reduce + bcast finisher, all-VALU)
    double kv = kk;
    kv = dpp_max_step<0xB1>(kv);    // quad_perm [1,0,3,2]  (xor1)
    kv = dpp_max_step<0x4E>(kv);    // quad_perm [2,3,0,1]  (xor2)
    kv = dpp_max_step<0x141>(kv);   // ROW_HALF_MIRROR      (8-group)
    kv = dpp_max_step<0x140>(kv);   // ROW_MIRROR           (16-group)
    kv = dpp_max_step<0x142>(kv);   // ROW_BCAST15: row r -> row r+1
    kv = dpp_max_step<0x143>(kv);   // ROW_BCAST31: half 0 -> half 1
    const int s = it & 1;
    if (lane == 63) wk8[s][w] = kv; // lane 63 holds the wave max
    __syncthreads();
    // every lane: read one of the 8 partials (broadcast reads), then
    // 3 DPP steps reduce each 8-lane group -> global max in every lane
    double km = wk8[s][lane & 7];
    km = dpp_max_step<0xB1>(km);
    km = dpp_max_step<0x4E>(km);
    km = dpp_max_step<0x141>(km);
    u64 kmu = (u64)__double_as_longlong(km);
    far = NPTS-1 - (int)(kmu & 0xffffffffu);
    fc = pc[far];
    if (t==0) fars[it] = far;                  // LDS only — no vmem in loop
  }
  __syncthreads();                             // fars complete
  // epilogue: write all centroids once (same values, same locations)
  for (int it = t; it < SG; it += NT){
    int f = fars[it];
    float4 p = pc[f];
    int gidx = b*SG + it;
    g_cx[gidx] = p.x; g_cy[gidx] = p.y; g_cz[gidx] = p.z;
    size_t o = (size_t)gidx*3;
    out_xyz[o+0]=p.x; out_xyz[o+1]=p.y; out_xyz[o+2]=p.z;
  }
}

// ---------------- K_ball: expansion form, FMA-ascending dot (PASSED r7, do not touch) ----------------
__global__ __launch_bounds__(256) void k_ball(){
  const int g = blockIdx.x*4 + (threadIdx.x>>6);
  const int lane = threadIdx.x & 63;
  const int b = g >> 11;
  const float4* pb4 = g_p4 + b*NPTS;
  float cxv = g_cx[g], cyv = g_cy[g], czv = g_cz[g];
  float s1;
  {
#pragma clang fp contract(off)
    float a = cxv*cxv; float bb = cyv*cyv; float cc = czv*czv;
    s1 = (a + bb) + cc;
  }
  const float R2 = 0.04f;
  int filled = 0, firstn = -1;
  for (int n0=0; n0<NPTS && filled<KS; n0+=64){
    float4 p = pb4[n0+lane];
    float sq;
    {
#pragma clang fp contract(off)
      float dt = cxv*p.x;
      dt = fmaf(cyv, p.y, dt);
      dt = fmaf(czv, p.z, dt);
      float ss = s1 + p.w;
      sq = ss - 2.0f*dt;
    }
    bool mem = !(sq > R2);
    u64 mk = __ballot(mem);
    if (firstn < 0 && mk) firstn = n0 + (__ffsll((unsigned long long)mk) - 1);
    int pos = filled + (int)__popcll(mk & ((1ull<<lane)-1ull));
    if (mem && pos < KS) g_ball[(size_t)g*KS + pos] = n0 + lane;
    filled += (int)__popcll(mk);
  }
  for (int s = filled + lane; s < KS; s += 64) g_ball[(size_t)g*KS+s] = firstn;
}

// ---------------- K_mlpA: gather + L0 -> Y0 (raw f32) + stats0 ----------------
__global__ __launch_bounds__(256) void k_mlpA(
    const float* __restrict__ points,
    const float* __restrict__ W0, const float* __restrict__ B0v){
  double* stats = g_stats;
  const int g = blockIdx.x, tid = threadIdx.x;
  const int b = g >> 11;
  __shared__ __align__(16) float xt[32][68];
  __shared__ __align__(16) float w0s[68][64];
  __shared__ float wsum[4][64], wsq[4][64];

  for (int i = tid; i < 67*64; i += 256) w0s[i>>6][i&63] = W0[i];
  if (tid < 64) w0s[67][tid] = 0.f;

  if (tid < 32){
    int n = g_ball[(size_t)g*KS + tid];
    float4 p = g_p4[b*NPTS + n];
    xt[tid][0] = p.x - g_cx[g];
    xt[tid][1] = p.y - g_cy[g];
    xt[tid][2] = p.z - g_cz[g];
    xt[tid][67] = 0.f;
  }
  {
    int k = tid >> 3, j = tid & 7;
    int n = g_ball[(size_t)g*KS + k];
    const float4* pr = (const float4*)(points + ((size_t)(b*NPTS + n))*64);
    float4 v0 = pr[j*2], v1 = pr[j*2+1];
    int c0 = 3 + j*8;
    xt[k][c0+0]=v0.x; xt[k][c0+1]=v0.y; xt[k][c0+2]=v0.z; xt[k][c0+3]=v0.w;
    xt[k][c0+4]=v1.x; xt[k][c0+5]=v1.y; xt[k][c0+6]=v1.z; xt[k][c0+7]=v1.w;
  }
  __syncthreads();

  const int k0 = (tid >> 4) * 2;
  const int d0 = (tid & 15) * 4;
  const int lane = tid & 63, w = tid >> 6;

  float acc0[4] = {0.f,0.f,0.f,0.f};
  float acc1[4] = {0.f,0.f,0.f,0.f};
#pragma unroll
  for (int cq = 0; cq < 17; ++cq){
    const int c = cq*4;
    float xa[4], xb[4], r0[4], r1[4], r2[4], r3[4];
    *(float4*)xa = *(const float4*)&xt[k0][c];
    *(float4*)xb = *(const float4*)&xt[k0+1][c];
    *(float4*)r0 = *(const float4*)&w0s[c+0][d0];
    *(float4*)r1 = *(const float4*)&w0s[c+1][d0];
    *(float4*)r2 = *(const float4*)&w0s[c+2][d0];
    *(float4*)r3 = *(const float4*)&w0s[c+3][d0];
#pragma unroll
    for (int j=0;j<4;j++){
      acc0[j] = fmaf(xa[0], r0[j], acc0[j]);
      acc0[j] = fmaf(xa[1], r1[j], acc0[j]);
      acc0[j] = fmaf(xa[2], r2[j], acc0[j]);
      acc0[j] = fmaf(xa[3], r3[j], acc0[j]);
      acc1[j] = fmaf(xb[0], r0[j], acc1[j]);
      acc1[j] = fmaf(xb[1], r1[j], acc1[j]);
      acc1[j] = fmaf(xb[2], r2[j], acc1[j]);
      acc1[j] = fmaf(xb[3], r3[j], acc1[j]);
    }
  }
#pragma unroll
  for (int j=0;j<4;j++){ float bv = B0v[d0+j]; acc0[j] += bv; acc1[j] += bv; }

  // store raw Y0
  {
    size_t r0 = ((size_t)g*KS + k0)*64 + d0;
    *(float4*)&g_y0[r0]      = *(float4*)acc0;
    *(float4*)&g_y0[r0 + 64] = *(float4*)acc1;
  }

  float s[4], q[4];
#pragma unroll
  for (int j=0;j<4;j++){ s[j] = acc0[j]+acc1[j]; q[j] = acc0[j]*acc0[j] + acc1[j]*acc1[j]; }
#pragma unroll
  for (int j=0;j<4;j++){
    s[j] += __shfl_down(s[j],32); s[j] += __shfl_down(s[j],16);
    q[j] += __shfl_down(q[j],32); q[j] += __shfl_down(q[j],16);
  }
  if (lane < 16){
#pragma unroll
    for (int j=0;j<4;j++){ wsum[w][lane*4+j] = s[j]; wsq[w][lane*4+j] = q[j]; }
  }
  __syncthreads();
  if (tid < 64){
    float S = wsum[0][tid]+wsum[1][tid]+wsum[2][tid]+wsum[3][tid];
    float Q = wsq[0][tid]+wsq[1][tid]+wsq[2][tid]+wsq[3][tid];
    int bucket = g & 127;
    atomicAdd(&stats[(size_t)bucket*256 + tid], (double)S);
    atomicAdd(&stats[(size_t)bucket*256 + 128 + tid], (double)Q);
  }
}

// ---------------- K_mlpB: Y0 + BN0/ReLU -> L1 -> Y1 (raw) + stats1 ----------------
__global__ __launch_bounds__(256) void k_mlpB(
    const float* __restrict__ W1, const float* __restrict__ B1v){
  double* stats = g_stats + (size_t)1*128*256;
  const int g = blockIdx.x, tid = threadIdx.x;
  __shared__ __align__(16) float xn[32][68];
  __shared__ __align__(16) float w1s[64][64];
  __shared__ float wsum[4][64], wsq[4][64];

  for (int i = tid; i < 64*64; i += 256) w1s[i>>6][i&63] = W1[i];
  {
    int k = tid >> 3, j = tid & 7;
    const float4* pr = (const float4*)(g_y0 + ((size_t)g*KS + k)*64);
    float4 v0 = pr[j*2], v1 = pr[j*2+1];
    int c0 = j*8;
    xn[k][c0+0] = fmaxf(fmaf(v0.x, g_A[c0+0], g_Bv[c0+0]), 0.f);
    xn[k][c0+1] = fmaxf(fmaf(v0.y, g_A[c0+1], g_Bv[c0+1]), 0.f);
    xn[k][c0+2] = fmaxf(fmaf(v0.z, g_A[c0+2], g_Bv[c0+2]), 0.f);
    xn[k][c0+3] = fmaxf(fmaf(v0.w, g_A[c0+3], g_Bv[c0+3]), 0.f);
    xn[k][c0+4] = fmaxf(fmaf(v1.x, g_A[c0+4], g_Bv[c0+4]), 0.f);
    xn[k][c0+5] = fmaxf(fmaf(v1.y, g_A[c0+5], g_Bv[c0+5]), 0.f);
    xn[k][c0+6] = fmaxf(fmaf(v1.z, g_A[c0+6], g_Bv[c0+6]), 0.f);
    xn[k][c0+7] = fmaxf(fmaf(v1.w, g_A[c0+7], g_Bv[c0+7]), 0.f);
  }
  __syncthreads();

  const int k0 = (tid >> 4) * 2;
  const int d0 = (tid & 15) * 4;
  const int lane = tid & 63, w = tid >> 6;

  float bc0[4] = {0.f,0.f,0.f,0.f};
  float bc1[4] = {0.f,0.f,0.f,0.f};
#pragma unroll
  for (int cq = 0; cq < 16; ++cq){
    const int c = cq*4;
    float xa[4], xb[4], r0[4], r1[4], r2[4], r3[4];
    *(float4*)xa = *(const float4*)&xn[k0][c];
    *(float4*)xb = *(const float4*)&xn[k0+1][c];
    *(float4*)r0 = *(const float4*)&w1s[c+0][d0];
    *(float4*)r1 = *(const float4*)&w1s[c+1][d0];
    *(float4*)r2 = *(const float4*)&w1s[c+2][d0];
    *(float4*)r3 = *(const float4*)&w1s[c+3][d0];
#pragma unroll
    for (int j=0;j<4;j++){
      bc0[j] = fmaf(xa[0], r0[j], bc0[j]);
      bc0[j] = fmaf(xa[1], r1[j], bc0[j]);
      bc0[j] = fmaf(xa[2], r2[j], bc0[j]);
      bc0[j] = fmaf(xa[3], r3[j], bc0[j]);
      bc1[j] = fmaf(xb[0], r0[j], bc1[j]);
      bc1[j] = fmaf(xb[1], r1[j], bc1[j]);
      bc1[j] = fmaf(xb[2], r2[j], bc1[j]);
      bc1[j] = fmaf(xb[3], r3[j], bc1[j]);
    }
  }
#pragma unroll
  for (int j=0;j<4;j++){ float bv = B1v[d0+j]; bc0[j] += bv; bc1[j] += bv; }

  {
    size_t r0 = ((size_t)g*KS + k0)*64 + d0;
    *(float4*)&g_y1[r0]      = *(float4*)bc0;
    *(float4*)&g_y1[r0 + 64] = *(float4*)bc1;
  }

  float s[4], q[4];
#pragma unroll
  for (int j=0;j<4;j++){ s[j] = bc0[j]+bc1[j]; q[j] = bc0[j]*bc0[j] + bc1[j]*bc1[j]; }
#pragma unroll
  for (int j=0;j<4;j++){
    s[j] += __shfl_down(s[j],32); s[j] += __shfl_down(s[j],16);
    q[j] += __shfl_down(q[j],32); q[j] += __shfl_down(q[j],16);
  }
  if (lane < 16){
#pragma unroll
    for (int j=0;j<4;j++){ wsum[w][lane*4+j] = s[j]; wsq[w][lane*4+j] = q[j]; }
  }
  __syncthreads();
  if (tid < 64){
    float S = wsum[0][tid]+wsum[1][tid]+wsum[2][tid]+wsum[3][tid];
    float Q = wsq[0][tid]+wsq[1][tid]+wsq[2][tid]+wsq[3][tid];
    int bucket = g & 127;
    atomicAdd(&stats[(size_t)bucket*256 + tid], (double)S);
    atomicAdd(&stats[(size_t)bucket*256 + 128 + tid], (double)Q);
  }
}

// ---------------- K_mlpC: Y1 + BN1/ReLU -> L2 -> stats2 + max/min ----------------
__global__ __launch_bounds__(256) void k_mlpC(
    const float* __restrict__ W2, const float* __restrict__ B2v){
  double* stats = g_stats + (size_t)2*128*256;
  const int g = blockIdx.x, tid = threadIdx.x;
  __shared__ __align__(16) float xt[32][68];
  __shared__ __align__(16) float w2s[64][128];
  __shared__ float wsum[4][128], wsq[4][128];
  __shared__ float wmx[4][128], wmn[4][128];

  for (int i = tid; i < 64*128; i += 256) w2s[i>>7][i&127] = W2[i];
  {
    int k = tid >> 3, j = tid & 7;
    const float4* pr = (const float4*)(g_y1 + ((size_t)g*KS + k)*64);
    float4 v0 = pr[j*2], v1 = pr[j*2+1];
    int c0 = j*8;
    xt[k][c0+0] = fmaxf(fmaf(v0.x, g_A[64+c0+0], g_Bv[64+c0+0]), 0.f);
    xt[k][c0+1] = fmaxf(fmaf(v0.y, g_A[64+c0+1], g_Bv[64+c0+1]), 0.f);
    xt[k][c0+2] = fmaxf(fmaf(v0.z, g_A[64+c0+2], g_Bv[64+c0+2]), 0.f);
    xt[k][c0+3] = fmaxf(fmaf(v0.w, g_A[64+c0+3], g_Bv[64+c0+3]), 0.f);
    xt[k][c0+4] = fmaxf(fmaf(v1.x, g_A[64+c0+4], g_Bv[64+c0+4]), 0.f);
    xt[k][c0+5] = fmaxf(fmaf(v1.y, g_A[64+c0+5], g_Bv[64+c0+5]), 0.f);
    xt[k][c0+6] = fmaxf(fmaf(v1.z, g_A[64+c0+6], g_Bv[64+c0+6]), 0.f);
    xt[k][c0+7] = fmaxf(fmaf(v1.w, g_A[64+c0+7], g_Bv[64+c0+7]), 0.f);
  }
  __syncthreads();

  const int k0 = (tid >> 4) * 2;
  const int e0 = (tid & 15) * 8;
  const int lane = tid & 63, w = tid >> 6;

  float c0a[8] = {0.f,0.f,0.f,0.f,0.f,0.f,0.f,0.f};
  float c1a[8] = {0.f,0.f,0.f,0.f,0.f,0.f,0.f,0.f};
#pragma unroll
  for (int cq = 0; cq < 16; ++cq){
    const int c = cq*4;
    float xa[4], xb[4], r0[8], r1[8], r2[8], r3[8];
    *(float4*)xa = *(const float4*)&xt[k0][c];
    *(float4*)xb = *(const float4*)&xt[k0+1][c];
    *(float4*)&r0[0] = *(const float4*)&w2s[c+0][e0]; *(float4*)&r0[4] = *(const float4*)&w2s[c+0][e0+4];
    *(float4*)&r1[0] = *(const float4*)&w2s[c+1][e0]; *(float4*)&r1[4] = *(const float4*)&w2s[c+1][e0+4];
    *(float4*)&r2[0] = *(const float4*)&w2s[c+2][e0]; *(float4*)&r2[4] = *(const float4*)&w2s[c+2][e0+4];
    *(float4*)&r3[0] = *(const float4*)&w2s[c+3][e0]; *(float4*)&r3[4] = *(const float4*)&w2s[c+3][e0+4];
#pragma unroll
    for (int j=0;j<8;j++){
      c0a[j] = fmaf(xa[0], r0[j], c0a[j]);
      c0a[j] = fmaf(xa[1], r1[j], c0a[j]);
      c0a[j] = fmaf(xa[2], r2[j], c0a[j]);
      c0a[j] = fmaf(xa[3], r3[j], c0a[j]);
      c1a[j] = fmaf(xb[0], r0[j], c1a[j]);
      c1a[j] = fmaf(xb[1], r1[j], c1a[j]);
      c1a[j] = fmaf(xb[2], r2[j], c1a[j]);
      c1a[j] = fmaf(xb[3], r3[j], c1a[j]);
    }
  }
#pragma unroll
  for (int j=0;j<8;j++){ float bv = B2v[e0+j]; c0a[j] += bv; c1a[j] += bv; }

  float s[8], q[8], mx[8], mn[8];
#pragma unroll
  for (int j=0;j<8;j++){
    s[j] = c0a[j]+c1a[j]; q[j] = c0a[j]*c0a[j] + c1a[j]*c1a[j];
    mx[j] = fmaxf(c0a[j], c1a[j]); mn[j] = fminf(c0a[j], c1a[j]);
  }
#pragma unroll
  for (int j=0;j<8;j++){
    s[j] += __shfl_down(s[j],32); s[j] += __shfl_down(s[j],16);
    q[j] += __shfl_down(q[j],32); q[j] += __shfl_down(q[j],16);
    mx[j] = fmaxf(mx[j], __shfl_xor(mx[j],16)); mx[j] = fmaxf(mx[j], __shfl_xor(mx[j],32));
    mn[j] = fminf(mn[j], __shfl_xor(mn[j],16)); mn[j] = fminf(mn[j], __shfl_xor(mn[j],32));
  }
  if (lane < 16){
#pragma unroll
    for (int j=0;j<8;j++){
      wsum[w][lane*8+j] = s[j]; wsq[w][lane*8+j] = q[j];
      wmx[w][lane*8+j] = mx[j]; wmn[w][lane*8+j] = mn[j];
    }
  }
  __syncthreads();
  if (tid < 128){
    float S = wsum[0][tid]+wsum[1][tid]+wsum[2][tid]+wsum[3][tid];
    float Q = wsq[0][tid]+wsq[1][tid]+wsq[2][tid]+wsq[3][tid];
    float MX = fmaxf(fmaxf(wmx[0][tid],wmx[1][tid]), fmaxf(wmx[2][tid],wmx[3][tid]));
    float MN = fminf(fminf(wmn[0][tid],wmn[1][tid]), fminf(wmn[2][tid],wmn[3][tid]));
    g_mmax[(size_t)g*128 + tid] = MX;
    g_mmin[(size_t)g*128 + tid] = MN;
    int bucket = g & 127;
    atomicAdd(&stats[(size_t)bucket*256 + tid], (double)S);
    atomicAdd(&stats[(size_t)bucket*256 + 128 + tid], (double)Q);
  }
}

// ---------------- K_stats ----------------
__global__ void k_stats(int stage, const float* __restrict__ gamma,
                        const float* __restrict__ beta, int aoff, int cout){
  int c = threadIdx.x;
  if (c >= cout) return;
  const double* stats = g_stats + (size_t)stage*128*256;
  double S=0.0, Q=0.0;
  for (int k=0;k<128;k++){ S += stats[(size_t)k*256 + c]; Q += stats[(size_t)k*256 + 128 + c]; }
  const double M = (double)MROWS;
  double mean = S / M;
  double var  = Q / M - mean*mean;
  double inv  = 1.0 / sqrt(var + 1e-5);
  double a    = (double)gamma[c] * inv;
  g_A[aoff+c]  = (float)a;
  g_Bv[aoff+c] = (float)((double)beta[c] - mean * a);
}

// ---------------- K_final ----------------
__global__ __launch_bounds__(256) void k_final(float* __restrict__ outp){
  int idx = blockIdx.x*256 + threadIdx.x;
  int d = idx & 127;
  float a = g_A[128+d], b = g_Bv[128+d];
  float y = (a >= 0.f) ? g_mmax[idx] : g_mmin[idx];
  float v = fmaf(y, a, b);
  outp[idx] = fmaxf(v, 0.f);
}

extern "C" void kernel_launch(void* const* d_in, const int* in_sizes, int n_in,
                              void* d_out, int out_size, void* d_ws, size_t ws_size,
                              hipStream_t stream) {
  (void)in_sizes; (void)n_in; (void)out_size; (void)d_ws; (void)ws_size;
  const float* xyz    = (const float*)d_in[0];
  const float* points = (const float*)d_in[1];
  const int*   start  = (const int*)d_in[2];
  const float* W0 = (const float*)d_in[3];  const float* b0 = (const float*)d_in[4];
  const float* g0 = (const float*)d_in[5];  const float* be0= (const float*)d_in[6];
  const float* W1 = (const float*)d_in[7];  const float* b1 = (const float*)d_in[8];
  const float* g1 = (const float*)d_in[9];  const float* be1= (const float*)d_in[10];
  const float* W2 = (const float*)d_in[11]; const float* b2 = (const float*)d_in[12];
  const float* g2 = (const float*)d_in[13]; const float* be2= (const float*)d_in[14];

  float* out_xyz = (float*)d_out;
  float* out_pts = (float*)d_out + (size_t)NBATCH*SG*3;

  k_zero <<<384, 256, 0, stream>>>();
  k_pre  <<<256, 256, 0, stream>>>(xyz);
  k_fps  <<<NBATCH, NT, 0, stream>>>(start, out_xyz);
  k_ball <<<4096, 256, 0, stream>>>();

  k_mlpA<<<NGRP, 256, 0, stream>>>(points, W0, b0);
  k_stats<<<1, 128, 0, stream>>>(0, g0, be0, 0, 64);
  k_mlpB<<<NGRP, 256, 0, stream>>>(W1, b1);
  k_stats<<<1, 128, 0, stream>>>(1, g1, be1, 64, 64);
  k_mlpC<<<NGRP, 256, 0, stream>>>(W2, b2);
  k_stats<<<1, 128, 0, stream>>>(2, g2, be2, 128, 128);
  k_final<<<8192, 256, 0, stream>>>(out_pts);
}